// Round 1
// baseline (2803.456 us; speedup 1.0000x reference)
//
#include <hip/hip_runtime.h>
#include <cfloat>

#define Hd 128
#define NTOT 65536
#define RREL 4
#define NRSEG (NTOT*RREL)
#define NEDGE 524288

__device__ __forceinline__ void atomicMaxF(float* addr, float v) {
  if (v >= 0.f) atomicMax((int*)addr, __float_as_int(v));
  else atomicMin((unsigned int*)addr, __float_as_uint(v));
}

// C[M,128] = (A (+A2)) [M,128] @ B[128,128] (+bias1)(+bias2); REMAP: final output row permutation
template<bool REMAP>
__global__ __launch_bounds__(256) void gemm128(
    const float* __restrict__ A, const float* __restrict__ A2,
    const float* __restrict__ B, const float* __restrict__ bias1,
    const float* __restrict__ bias2, float* __restrict__ C, int M)
{
  __shared__ float As[64][36];   // pad 36: 2-way max bank conflict on reads (free)
  __shared__ float Bs[32][128];
  const int tid = threadIdx.x;
  const int brow = blockIdx.x * 64;
  const int tx = tid & 7;        // col group: cols {tx*4 + j*32}
  const int ty = tid >> 3;       // row pair: rows 2ty, 2ty+1
  float acc[2][16];
#pragma unroll
  for (int i = 0; i < 2; ++i)
#pragma unroll
    for (int j = 0; j < 16; ++j) acc[i][j] = 0.f;

  for (int kc = 0; kc < 4; ++kc) {
#pragma unroll
    for (int t = 0; t < 2; ++t) {
      int slot = tid + t*256;            // 512 float4 slots: 64 rows x 8
      int r = slot >> 3, c4 = slot & 7;
      float4 av = *reinterpret_cast<const float4*>(A + (size_t)(brow + r)*Hd + kc*32 + c4*4);
      if (A2) {
        float4 a2 = *reinterpret_cast<const float4*>(A2 + (size_t)(brow + r)*Hd + kc*32 + c4*4);
        av.x += a2.x; av.y += a2.y; av.z += a2.z; av.w += a2.w;
      }
      *reinterpret_cast<float4*>(&As[r][c4*4]) = av;
    }
#pragma unroll
    for (int t = 0; t < 4; ++t) {
      int slot = tid + t*256;            // 1024 float4 slots: 32 rows x 32
      int r = slot >> 5, c4 = slot & 31;
      *reinterpret_cast<float4*>(&Bs[r][c4*4]) =
          *reinterpret_cast<const float4*>(B + (size_t)(kc*32 + r)*Hd + c4*4);
    }
    __syncthreads();
#pragma unroll
    for (int kk = 0; kk < 32; ++kk) {
      float a0 = As[2*ty][kk];
      float a1 = As[2*ty+1][kk];
#pragma unroll
      for (int j = 0; j < 4; ++j) {
        float4 bv = *reinterpret_cast<const float4*>(&Bs[kk][tx*4 + j*32]);
        acc[0][j*4+0] = fmaf(a0, bv.x, acc[0][j*4+0]);
        acc[0][j*4+1] = fmaf(a0, bv.y, acc[0][j*4+1]);
        acc[0][j*4+2] = fmaf(a0, bv.z, acc[0][j*4+2]);
        acc[0][j*4+3] = fmaf(a0, bv.w, acc[0][j*4+3]);
        acc[1][j*4+0] = fmaf(a1, bv.x, acc[1][j*4+0]);
        acc[1][j*4+1] = fmaf(a1, bv.y, acc[1][j*4+1]);
        acc[1][j*4+2] = fmaf(a1, bv.z, acc[1][j*4+2]);
        acc[1][j*4+3] = fmaf(a1, bv.w, acc[1][j*4+3]);
      }
    }
    __syncthreads();
  }
#pragma unroll
  for (int i = 0; i < 2; ++i) {
    int row = brow + 2*ty + i;
    size_t ob;
    if (REMAP) {
      int b = row >> 6, p = row & 63;
      ob = (p == 0) ? (size_t)b*Hd
                    : (size_t)(1024*Hd) + ((size_t)(b*63 + (p-1)))*Hd;
    } else {
      ob = (size_t)row * Hd;
    }
#pragma unroll
    for (int j = 0; j < 4; ++j) {
      int c = tx*4 + j*32;
      float4 v = make_float4(acc[i][j*4+0], acc[i][j*4+1], acc[i][j*4+2], acc[i][j*4+3]);
      if (bias1) {
        float4 bb = *reinterpret_cast<const float4*>(bias1 + c);
        v.x += bb.x; v.y += bb.y; v.z += bb.z; v.w += bb.w;
      }
      if (bias2) {
        float4 bb = *reinterpret_cast<const float4*>(bias2 + c);
        v.x += bb.x; v.y += bb.y; v.z += bb.z; v.w += bb.w;
      }
      *reinterpret_cast<float4*>(C + ob + c) = v;
    }
  }
}

__global__ void fill_i32(int* p, int v, int n) {
  int i = blockIdx.x*blockDim.x + threadIdx.x;
  if (i < n) p[i] = v;
}

__global__ void edge_count(const int* __restrict__ dst, const int* __restrict__ et, int* __restrict__ cnt) {
  int e = blockIdx.x*blockDim.x + threadIdx.x;
  if (e < NEDGE) atomicAdd(&cnt[dst[e]*RREL + et[e]], 1);
}

__global__ void inv_cnt_k(const int* __restrict__ cnt, float* __restrict__ invc) {
  int i = blockIdx.x*blockDim.x + threadIdx.x;
  if (i < NRSEG) invc[i] = 1.f / (float)max(cnt[i], 1);
}

__global__ void maskmul(const float* __restrict__ x, const float* __restrict__ m, float* __restrict__ o) {
  size_t i = ((size_t)blockIdx.x*blockDim.x + threadIdx.x)*4;
  float4 a = *reinterpret_cast<const float4*>(x + i);
  float4 b = *reinterpret_cast<const float4*>(m + i);
  a.x *= b.x; a.y *= b.y; a.z *= b.z; a.w *= b.w;
  *reinterpret_cast<float4*>(o + i) = a;
}

// qvec[r][h] = attW[r][h,:] . att_q[r];  kvec likewise
__global__ void qkvec_k(const float* __restrict__ attW, const float* __restrict__ att_q,
                        const float* __restrict__ att_k,
                        float* __restrict__ qvec, float* __restrict__ kvec) {
  int r = threadIdx.x >> 7, h = threadIdx.x & 127;
  const float* wrow = attW + ((size_t)r*Hd + h)*Hd;
  const float* qv = att_q + (size_t)r*Hd;
  const float* kv = att_k + (size_t)r*Hd;
  float sq_ = 0.f, sk_ = 0.f;
  for (int o = 0; o < Hd; ++o) { float w = wrow[o]; sq_ = fmaf(w, qv[o], sq_); sk_ = fmaf(w, kv[o], sk_); }
  qvec[r*Hd + h] = sq_;
  kvec[r*Hd + h] = sk_;
}

// per node: sq[r,n] = xm[n,:].qvec[r], sk[r,n] = xm[n,:].kvec[r]  (one wave per node)
__global__ void sqk_k(const float* __restrict__ xm, const float* __restrict__ qvec,
                      const float* __restrict__ kvec, float* __restrict__ sq, float* __restrict__ sk) {
  int w = blockIdx.x*4 + (threadIdx.x >> 6);
  if (w >= NTOT) return;
  int lane = threadIdx.x & 63;
  float2 v = *reinterpret_cast<const float2*>(xm + (size_t)w*Hd + lane*2);
  float pq[RREL], pk[RREL];
#pragma unroll
  for (int r = 0; r < RREL; ++r) {
    float2 q = *reinterpret_cast<const float2*>(qvec + r*Hd + lane*2);
    float2 k = *reinterpret_cast<const float2*>(kvec + r*Hd + lane*2);
    pq[r] = v.x*q.x + v.y*q.y;
    pk[r] = v.x*k.x + v.y*k.y;
  }
#pragma unroll
  for (int off = 32; off > 0; off >>= 1) {
#pragma unroll
    for (int r = 0; r < RREL; ++r) {
      pq[r] += __shfl_xor(pq[r], off);
      pk[r] += __shfl_xor(pk[r], off);
    }
  }
  if (lane == 0) {
#pragma unroll
    for (int r = 0; r < RREL; ++r) {
      sq[(size_t)r*NTOT + w] = pq[r];
      sk[(size_t)r*NTOT + w] = pk[r];
    }
  }
}

__global__ void layer_init(float* __restrict__ mx, float* __restrict__ den, float* __restrict__ bns) {
  int i = blockIdx.x*blockDim.x + threadIdx.x;
  if (i < NRSEG) { mx[i] = -FLT_MAX; den[i] = 0.f; }
  if (i < 256) bns[i] = 0.f;
}

__global__ void edge_logit(const int* __restrict__ src, const int* __restrict__ dst,
                           const int* __restrict__ et, const float* __restrict__ sq,
                           const float* __restrict__ sk, float* __restrict__ exb,
                           float* __restrict__ mx) {
  int e = blockIdx.x*blockDim.x + threadIdx.x;
  if (e >= NEDGE) return;
  int t = et[e];
  float lg = sq[(size_t)t*NTOT + dst[e]] + sk[(size_t)t*NTOT + src[e]];
  lg = lg >= 0.f ? lg : 0.2f*lg;
  exb[e] = lg;
  atomicMaxF(&mx[dst[e]*RREL + t], lg);
}

__global__ void edge_expden(const int* __restrict__ dst, const int* __restrict__ et,
                            float* __restrict__ exb, const float* __restrict__ mx,
                            float* __restrict__ den) {
  int e = blockIdx.x*blockDim.x + threadIdx.x;
  if (e >= NEDGE) return;
  int seg = dst[e]*RREL + et[e];
  float ex = __expf(exb[e] - mx[seg]);
  exb[e] = ex;
  unsafeAtomicAdd(&den[seg], ex);
}

// one wave per edge; MODE 0: w=1/cnt (conv mean), MODE 1: w=alpha (attention)
template<int MODE>
__global__ void scatter_rel(const float* __restrict__ tbuf, const int* __restrict__ src,
                            const int* __restrict__ dst, const int* __restrict__ et,
                            const float* __restrict__ invcnt, const float* __restrict__ exb,
                            const float* __restrict__ den, float* __restrict__ h, int rel) {
  int w = blockIdx.x*4 + (threadIdx.x >> 6);
  if (w >= NEDGE) return;
  if (et[w] != rel) return;
  int lane = threadIdx.x & 63;
  int s = src[w], d = dst[w];
  int seg = d*RREL + rel;
  float wgt = (MODE == 0) ? invcnt[seg] : exb[w] / fmaxf(den[seg], 1e-16f);
  float2 v = *reinterpret_cast<const float2*>(tbuf + (size_t)s*Hd + lane*2);
  unsafeAtomicAdd(h + (size_t)d*Hd + lane*2 + 0, wgt*v.x);
  unsafeAtomicAdd(h + (size_t)d*Hd + lane*2 + 1, wgt*v.y);
}

__global__ void bn_stats(const float* __restrict__ h, float* __restrict__ bns) {
  __shared__ float ls[2][128], ls2[2][128];
  int c = threadIdx.x & 127, half = threadIdx.x >> 7;
  int row0 = blockIdx.x*256 + half;
  float s = 0.f, s2 = 0.f;
  for (int i = 0; i < 128; ++i) {
    float v = h[(size_t)(row0 + i*2)*Hd + c];
    s += v; s2 = fmaf(v, v, s2);
  }
  ls[half][c] = s; ls2[half][c] = s2;
  __syncthreads();
  if (half == 0) {
    unsafeAtomicAdd(&bns[c], s + ls[1][c]);
    unsafeAtomicAdd(&bns[128 + c], s2 + ls2[1][c]);
  }
}

__global__ void bn_final(const float* __restrict__ bns, const float* __restrict__ g,
                         const float* __restrict__ b, float* __restrict__ scale,
                         float* __restrict__ shift) {
  int c = threadIdx.x;
  float mu = bns[c] * (1.f/NTOT);
  float var = bns[128 + c] * (1.f/NTOT) - mu*mu;
  float sc = g[c] / sqrtf(var + 1e-5f);
  scale[c] = sc;
  shift[c] = b[c] - mu*sc;
}

__global__ void bn_apply(const float* __restrict__ h, const float* __restrict__ scale,
                         const float* __restrict__ shift, float* __restrict__ x) {
  size_t i = ((size_t)blockIdx.x*blockDim.x + threadIdx.x)*4;
  int c = (int)(i & (Hd-1));
  float4 v = *reinterpret_cast<const float4*>(h + i);
  float4 sc = *reinterpret_cast<const float4*>(scale + c);
  float4 sh = *reinterpret_cast<const float4*>(shift + c);
  v.x = fmaf(v.x, sc.x, sh.x); v.y = fmaf(v.y, sc.y, sh.y);
  v.z = fmaf(v.z, sc.z, sh.z); v.w = fmaf(v.w, sc.w, sh.w);
  v.x = v.x >= 0.f ? v.x : 0.01f*v.x;
  v.y = v.y >= 0.f ? v.y : 0.01f*v.y;
  v.z = v.z >= 0.f ? v.z : 0.01f*v.z;
  v.w = v.w >= 0.f ? v.w : 0.01f*v.w;
  *reinterpret_cast<float4*>(x + i) = v;
}

extern "C" void kernel_launch(void* const* d_in, const int* in_sizes, int n_in,
                              void* d_out, int out_size, void* d_ws, size_t ws_size,
                              hipStream_t stream) {
  const float* x0       = (const float*)d_in[0];
  const float* x1       = (const float*)d_in[1];
  const float* W0       = (const float*)d_in[2];
  const float* b0       = (const float*)d_in[3];
  const float* W1       = (const float*)d_in[4];
  const float* b1       = (const float*)d_in[5];
  const float* mask     = (const float*)d_in[6];
  const float* conv_root= (const float*)d_in[7];
  const float* conv_rel = (const float*)d_in[8];
  const float* conv_b   = (const float*)d_in[9];
  const float* attW     = (const float*)d_in[10];
  const float* att_q    = (const float*)d_in[11];
  const float* att_k    = (const float*)d_in[12];
  const float* att_b    = (const float*)d_in[13];
  const float* bn_g     = (const float*)d_in[14];
  const float* bn_b     = (const float*)d_in[15];
  const float* fc_W     = (const float*)d_in[16];
  const float* fc_b     = (const float*)d_in[17];
  const int* edge_index = (const int*)d_in[18];
  const int* edge_type  = (const int*)d_in[19];
  const int* src = edge_index;
  const int* dst = edge_index + NEDGE;

  char* ws = (char*)d_ws;
  size_t off = 0;
  auto alloc = [&](size_t nf) { float* p = (float*)(ws + off); off += nf*sizeof(float); return p; };
  float* x_in  = alloc((size_t)NTOT*Hd);
  float* xbuf  = alloc((size_t)NTOT*Hd);
  float* xm    = alloc((size_t)NTOT*Hd);
  float* tbuf  = alloc((size_t)NTOT*Hd);
  float* hbuf  = alloc((size_t)NTOT*Hd);
  float* sq    = alloc((size_t)RREL*NTOT);
  float* sk    = alloc((size_t)RREL*NTOT);
  float* exbuf = alloc(NEDGE);
  float* mx    = alloc(NRSEG);
  float* den   = alloc(NRSEG);
  float* invcnt= alloc(NRSEG);
  int*   cnt   = (int*)alloc(NRSEG);
  float* qvec  = alloc(RREL*Hd);
  float* kvec  = alloc(RREL*Hd);
  float* bns   = alloc(256);
  float* bnscale = alloc(Hd);
  float* bnshift = alloc(Hd);
  (void)ws_size; (void)in_sizes; (void)n_in; (void)out_size;

  // static segment counts
  fill_i32<<<NRSEG/256, 256, 0, stream>>>(cnt, 0, NRSEG);
  edge_count<<<NEDGE/256, 256, 0, stream>>>(dst, edge_type, cnt);
  inv_cnt_k<<<NRSEG/256, 256, 0, stream>>>(cnt, invcnt);

  // x_in = [x0@W0+b0 ; x1@W1+b1]
  gemm128<false><<<512, 256, 0, stream>>>(x0, nullptr, W0, b0, nullptr, x_in, 32768);
  gemm128<false><<<512, 256, 0, stream>>>(x1, nullptr, W1, b1, nullptr, x_in + (size_t)32768*Hd, 32768);

  for (int l = 0; l < 2; ++l) {
    const float* cur = (l == 0) ? x_in : xbuf;
    maskmul<<<(NTOT*Hd/4)/256, 256, 0, stream>>>(cur, mask, xm);
    qkvec_k<<<1, 512, 0, stream>>>(attW + (size_t)l*16*Hd*Hd, att_q + (size_t)l*16*Hd,
                                   att_k + (size_t)l*16*Hd, qvec, kvec);
    sqk_k<<<NTOT/4, 256, 0, stream>>>(xm, qvec, kvec, sq, sk);
    layer_init<<<NRSEG/256, 256, 0, stream>>>(mx, den, bns);
    edge_logit<<<NEDGE/256, 256, 0, stream>>>(src, dst, edge_type, sq, sk, exbuf, mx);
    edge_expden<<<NEDGE/256, 256, 0, stream>>>(dst, edge_type, exbuf, mx, den);
    // h = xm @ conv_root[l] + conv_b[l] + att_b[l]
    gemm128<false><<<1024, 256, 0, stream>>>(xm, nullptr, conv_root + (size_t)l*Hd*Hd,
                                             conv_b + (size_t)l*Hd, att_b + (size_t)l*Hd, hbuf, NTOT);
    for (int r = 0; r < RREL; ++r) {
      gemm128<false><<<1024, 256, 0, stream>>>(xm, nullptr,
          conv_rel + ((size_t)l*RREL + r)*Hd*Hd, nullptr, nullptr, tbuf, NTOT);
      scatter_rel<0><<<NEDGE/4, 256, 0, stream>>>(tbuf, src, dst, edge_type, invcnt, exbuf, den, hbuf, r);
    }
    for (int r = 0; r < RREL; ++r) {
      gemm128<false><<<1024, 256, 0, stream>>>(xm, nullptr,
          attW + ((size_t)l*16 + r)*Hd*Hd, nullptr, nullptr, tbuf, NTOT);
      scatter_rel<1><<<NEDGE/4, 256, 0, stream>>>(tbuf, src, dst, edge_type, invcnt, exbuf, den, hbuf, r);
    }
    bn_stats<<<256, 256, 0, stream>>>(hbuf, bns);
    bn_final<<<1, 128, 0, stream>>>(bns, bn_g + (size_t)l*Hd, bn_b + (size_t)l*Hd, bnscale, bnshift);
    bn_apply<<<(NTOT*Hd/4)/256, 256, 0, stream>>>(hbuf, bnscale, bnshift, xbuf);
  }

  // out = (x + x_in) @ fc_W + fc_b, with output row remap
  gemm128<true><<<1024, 256, 0, stream>>>(xbuf, x_in, fc_W, fc_b, nullptr, (float*)d_out, NTOT);
}

// Round 2
// 1998.725 us; speedup vs baseline: 1.4026x; 1.4026x over previous
//
#include <hip/hip_runtime.h>
#include <cfloat>

#define Hd 128
#define NTOT 65536
#define RREL 4
#define NRSEG (NTOT*RREL)
#define NEDGE 524288
#define CH 8192
#define NCHUNK (NTOT/CH)

__device__ __forceinline__ void atomicMaxF(float* addr, float v) {
  if (v >= 0.f) atomicMax((int*)addr, __float_as_int(v));
  else atomicMin((unsigned int*)addr, __float_as_uint(v));
}

// ---------------- GEMM: C[64-row tile,128] = A[M,K(lda)] @ B[K,128] ----------------
// CMODE 0: write (+bias1)(+bias2), optional per-row scale (mask fold)
// CMODE 1: atomicAdd into C (split-K accumulate), no bias
// CMODE 2: remapped write (final output), A2 residual added at load, +bias1
template<int CMODE>
__global__ __launch_bounds__(256) void gemm64(
    const float* __restrict__ A, const float* __restrict__ A2,
    const float* __restrict__ rowscale,
    const float* __restrict__ B1, const float* __restrict__ B2, // B2: K rows >= 512
    const float* __restrict__ bias1, const float* __restrict__ bias2,
    float* __restrict__ C, int lda, int kIters)
{
  __shared__ float As[64][37];   // pad 37: 2-way max conflict on column reads
  __shared__ float Bs[32][128];
  const int tid = threadIdx.x;
  const int brow = blockIdx.x * 64;
  const int kStart = blockIdx.y * kIters * 32;
  const int tx = tid & 7;
  const int ty = tid >> 3;
  float acc[2][16];
#pragma unroll
  for (int i = 0; i < 2; ++i)
#pragma unroll
    for (int j = 0; j < 16; ++j) acc[i][j] = 0.f;

  for (int kc = 0; kc < kIters; ++kc) {
#pragma unroll
    for (int t = 0; t < 2; ++t) {
      int slot = tid + t*256;            // 512 slots: 64 rows x 8 float4
      int r = slot >> 3, c4 = slot & 7;
      const float* ap = A + (size_t)(brow + r)*lda + kStart + kc*32 + c4*4;
      float4 av = *reinterpret_cast<const float4*>(ap);
      if (A2) {
        const float* ap2 = A2 + (size_t)(brow + r)*lda + kStart + kc*32 + c4*4;
        float4 a2 = *reinterpret_cast<const float4*>(ap2);
        av.x += a2.x; av.y += a2.y; av.z += a2.z; av.w += a2.w;
      }
      if (rowscale) {
        float s = rowscale[brow + r];
        av.x *= s; av.y *= s; av.z *= s; av.w *= s;
      }
      *reinterpret_cast<float4*>(&As[r][c4*4]) = av;
    }
#pragma unroll
    for (int t = 0; t < 4; ++t) {
      int slot = tid + t*256;            // 1024 slots: 32 rows x 32 float4
      int r = slot >> 5, c4 = slot & 31;
      int kr = kStart + kc*32 + r;
      const float* brp = (B2 && kr >= 512) ? B2 + (size_t)(kr - 512)*Hd
                                           : B1 + (size_t)kr*Hd;
      *reinterpret_cast<float4*>(&Bs[r][c4*4]) =
          *reinterpret_cast<const float4*>(brp + c4*4);
    }
    __syncthreads();
#pragma unroll
    for (int kk = 0; kk < 32; ++kk) {
      float a0 = As[2*ty][kk];
      float a1 = As[2*ty+1][kk];
#pragma unroll
      for (int j = 0; j < 4; ++j) {
        float4 bv = *reinterpret_cast<const float4*>(&Bs[kk][tx*4 + j*32]);
        acc[0][j*4+0] = fmaf(a0, bv.x, acc[0][j*4+0]);
        acc[0][j*4+1] = fmaf(a0, bv.y, acc[0][j*4+1]);
        acc[0][j*4+2] = fmaf(a0, bv.z, acc[0][j*4+2]);
        acc[0][j*4+3] = fmaf(a0, bv.w, acc[0][j*4+3]);
        acc[1][j*4+0] = fmaf(a1, bv.x, acc[1][j*4+0]);
        acc[1][j*4+1] = fmaf(a1, bv.y, acc[1][j*4+1]);
        acc[1][j*4+2] = fmaf(a1, bv.z, acc[1][j*4+2]);
        acc[1][j*4+3] = fmaf(a1, bv.w, acc[1][j*4+3]);
      }
    }
    __syncthreads();
  }
#pragma unroll
  for (int i = 0; i < 2; ++i) {
    int row = brow + 2*ty + i;
    size_t ob;
    if (CMODE == 2) {
      int b = row >> 6, p = row & 63;
      ob = (p == 0) ? (size_t)b*Hd
                    : (size_t)(1024*Hd) + ((size_t)(b*63 + (p-1)))*Hd;
    } else {
      ob = (size_t)row * Hd;
    }
#pragma unroll
    for (int j = 0; j < 4; ++j) {
      int c = tx*4 + j*32;
      float4 v = make_float4(acc[i][j*4+0], acc[i][j*4+1], acc[i][j*4+2], acc[i][j*4+3]);
      if (CMODE == 1) {
        unsafeAtomicAdd(C + ob + c + 0, v.x);
        unsafeAtomicAdd(C + ob + c + 1, v.y);
        unsafeAtomicAdd(C + ob + c + 2, v.z);
        unsafeAtomicAdd(C + ob + c + 3, v.w);
      } else {
        if (bias1) {
          float4 bb = *reinterpret_cast<const float4*>(bias1 + c);
          v.x += bb.x; v.y += bb.y; v.z += bb.z; v.w += bb.w;
        }
        if (bias2) {
          float4 bb = *reinterpret_cast<const float4*>(bias2 + c);
          v.x += bb.x; v.y += bb.y; v.z += bb.z; v.w += bb.w;
        }
        *reinterpret_cast<float4*>(C + ob + c) = v;
      }
    }
  }
}

// ---------------- small utility kernels ----------------
__global__ void fill_i32(int* p, int v, int n) {
  int i = blockIdx.x*blockDim.x + threadIdx.x;
  if (i < n) p[i] = v;
}

__global__ void rowmask_k(const float* __restrict__ mask, float* __restrict__ rm) {
  int n = blockIdx.x*blockDim.x + threadIdx.x;
  if (n < NTOT) rm[n] = mask[(size_t)n*Hd];
}

__global__ void edge_count(const int* __restrict__ dst, const int* __restrict__ et, int* __restrict__ cnt) {
  int e = blockIdx.x*blockDim.x + threadIdx.x;
  if (e < NEDGE) atomicAdd(&cnt[dst[e]*RREL + et[e]], 1);
}

__global__ void inv_cnt_k(const int* __restrict__ cnt, float* __restrict__ invc) {
  int i = blockIdx.x*blockDim.x + threadIdx.x;
  if (i < NRSEG) invc[i] = 1.f / (float)max(cnt[i], 1);
}

// ---------------- CSR build: exclusive scan over 262144 counts ----------------
__global__ void scan1_k(const int* __restrict__ cnt, int* __restrict__ partial, int* __restrict__ bsum) {
  __shared__ int sh[256];
  int t = threadIdx.x;
  int i = blockIdx.x*256 + t;
  int v = cnt[i];
  sh[t] = v; __syncthreads();
  for (int off = 1; off < 256; off <<= 1) {
    int u = (t >= off) ? sh[t-off] : 0;
    __syncthreads();
    sh[t] += u;
    __syncthreads();
  }
  partial[i] = sh[t] - v;           // exclusive within block
  if (t == 255) bsum[blockIdx.x] = sh[255];
}

__global__ void scan2_k(int* __restrict__ bsum) {   // 1024 entries, in-place exclusive
  __shared__ int sh[256];
  int t = threadIdx.x;
  int v0 = bsum[t*4+0], v1 = bsum[t*4+1], v2 = bsum[t*4+2], v3 = bsum[t*4+3];
  int tot = v0+v1+v2+v3;
  sh[t] = tot; __syncthreads();
  for (int off = 1; off < 256; off <<= 1) {
    int u = (t >= off) ? sh[t-off] : 0;
    __syncthreads();
    sh[t] += u;
    __syncthreads();
  }
  int base = sh[t] - tot;
  bsum[t*4+0] = base;
  bsum[t*4+1] = base + v0;
  bsum[t*4+2] = base + v0+v1;
  bsum[t*4+3] = base + v0+v1+v2;
}

__global__ void scan3_k(const int* __restrict__ partial, const int* __restrict__ bsum, int* __restrict__ offsets) {
  int i = blockIdx.x*256 + threadIdx.x;
  offsets[i] = partial[i] + bsum[i >> 8];
  if (i == 0) offsets[NRSEG] = NEDGE;
}

__global__ void csr_fill(const int* __restrict__ src, const int* __restrict__ dst,
                         const int* __restrict__ et, const int* __restrict__ offsets,
                         int* __restrict__ fillctr, const float* __restrict__ rm,
                         int* __restrict__ src_sorted, float* __restrict__ wsrc_sorted,
                         int* __restrict__ epos) {
  int e = blockIdx.x*blockDim.x + threadIdx.x;
  if (e >= NEDGE) return;
  int seg = dst[e]*RREL + et[e];
  int pos = offsets[seg] + atomicAdd(&fillctr[seg], 1);
  int s = src[e];
  src_sorted[pos] = s;
  wsrc_sorted[pos] = rm[s];
  epos[e] = pos;
}

// ---------------- attention scalar path ----------------
__global__ void qkvec_k(const float* __restrict__ attW, const float* __restrict__ att_q,
                        const float* __restrict__ att_k,
                        float* __restrict__ qvec, float* __restrict__ kvec) {
  int r = threadIdx.x >> 7, h = threadIdx.x & 127;
  const float* wrow = attW + ((size_t)r*Hd + h)*Hd;
  const float* qv = att_q + (size_t)r*Hd;
  const float* kv = att_k + (size_t)r*Hd;
  float sq_ = 0.f, sk_ = 0.f;
  for (int o = 0; o < Hd; ++o) { float w = wrow[o]; sq_ = fmaf(w, qv[o], sq_); sk_ = fmaf(w, kv[o], sk_); }
  qvec[r*Hd + h] = sq_;
  kvec[r*Hd + h] = sk_;
}

__global__ void sqk_k(const float* __restrict__ x, const float* __restrict__ rm,
                      const float* __restrict__ qvec, const float* __restrict__ kvec,
                      float* __restrict__ sq, float* __restrict__ sk) {
  int w = blockIdx.x*4 + (threadIdx.x >> 6);
  if (w >= NTOT) return;
  int lane = threadIdx.x & 63;
  float2 v = *reinterpret_cast<const float2*>(x + (size_t)w*Hd + lane*2);
  float pq[RREL], pk[RREL];
#pragma unroll
  for (int r = 0; r < RREL; ++r) {
    float2 q = *reinterpret_cast<const float2*>(qvec + r*Hd + lane*2);
    float2 k = *reinterpret_cast<const float2*>(kvec + r*Hd + lane*2);
    pq[r] = v.x*q.x + v.y*q.y;
    pk[r] = v.x*k.x + v.y*k.y;
  }
#pragma unroll
  for (int off = 32; off > 0; off >>= 1) {
#pragma unroll
    for (int r = 0; r < RREL; ++r) {
      pq[r] += __shfl_xor(pq[r], off);
      pk[r] += __shfl_xor(pk[r], off);
    }
  }
  if (lane == 0) {
    float rmv = rm[w];
#pragma unroll
    for (int r = 0; r < RREL; ++r) {
      sq[(size_t)r*NTOT + w] = pq[r]*rmv;
      sk[(size_t)r*NTOT + w] = pk[r]*rmv;
    }
  }
}

__global__ void layer_init(float* __restrict__ mx, float* __restrict__ den, float* __restrict__ bns) {
  int i = blockIdx.x*blockDim.x + threadIdx.x;
  if (i < NRSEG) { mx[i] = -FLT_MAX; den[i] = 0.f; }
  if (i < 256) bns[i] = 0.f;
}

__global__ void edge_logit(const int* __restrict__ src, const int* __restrict__ dst,
                           const int* __restrict__ et, const float* __restrict__ sq,
                           const float* __restrict__ sk, float* __restrict__ exb,
                           float* __restrict__ mx) {
  int e = blockIdx.x*blockDim.x + threadIdx.x;
  if (e >= NEDGE) return;
  int t = et[e];
  float lg = sq[(size_t)t*NTOT + dst[e]] + sk[(size_t)t*NTOT + src[e]];
  lg = lg >= 0.f ? lg : 0.2f*lg;
  exb[e] = lg;
  atomicMaxF(&mx[dst[e]*RREL + t], lg);
}

__global__ void edge_expden(const int* __restrict__ dst, const int* __restrict__ et,
                            float* __restrict__ exb, const float* __restrict__ mx,
                            float* __restrict__ den) {
  int e = blockIdx.x*blockDim.x + threadIdx.x;
  if (e >= NEDGE) return;
  int seg = dst[e]*RREL + et[e];
  float ex = __expf(exb[e] - mx[seg]);
  exb[e] = ex;
  unsafeAtomicAdd(&den[seg], ex);
}

__global__ void alpha_sort(const int* __restrict__ dst, const int* __restrict__ et,
                           const int* __restrict__ epos, const float* __restrict__ exb,
                           const float* __restrict__ den, float* __restrict__ exs_sorted) {
  int e = blockIdx.x*blockDim.x + threadIdx.x;
  if (e >= NEDGE) return;
  int seg = dst[e]*RREL + et[e];
  exs_sorted[epos[e]] = exb[e] / fmaxf(den[seg], 1e-16f);
}

// ---------------- per-(node,rel) input-space gather: fills ych[CH][1024] ----------------
// row layout: [0:512) conv (r*128), [512:1024) att (512 + r*128)
__global__ __launch_bounds__(256) void gather_k(
    const float* __restrict__ x, const int* __restrict__ src_sorted,
    const float* __restrict__ wsrc_sorted, const float* __restrict__ exs_sorted,
    const int* __restrict__ offsets, const float* __restrict__ invcnt,
    float* __restrict__ ych, int cb)
{
  int w = blockIdx.x*4 + (threadIdx.x >> 6);
  int n = cb + w;
  int lane = threadIdx.x & 63;
  float* yrow = ych + (size_t)w*1024 + lane*2;
#pragma unroll
  for (int r = 0; r < RREL; ++r) {
    int seg = n*RREL + r;
    int e0 = offsets[seg], e1 = offsets[seg+1];
    float ic = invcnt[seg];
    float cx = 0.f, cy = 0.f, ax = 0.f, ay = 0.f;
    for (int e = e0; e < e1; ++e) {
      int s = src_sorted[e];
      float wsr = wsrc_sorted[e];
      float al = exs_sorted[e] * wsr;
      float2 v = *reinterpret_cast<const float2*>(x + (size_t)s*Hd + lane*2);
      cx = fmaf(wsr, v.x, cx); cy = fmaf(wsr, v.y, cy);
      ax = fmaf(al,  v.x, ax); ay = fmaf(al,  v.y, ay);
    }
    *reinterpret_cast<float2*>(yrow + r*128)       = make_float2(cx*ic, cy*ic);
    *reinterpret_cast<float2*>(yrow + 512 + r*128) = make_float2(ax, ay);
  }
}

// ---------------- batchnorm ----------------
__global__ void bn_stats(const float* __restrict__ h, float* __restrict__ bns) {
  __shared__ float ls[2][128], ls2[2][128];
  int c = threadIdx.x & 127, half = threadIdx.x >> 7;
  int row0 = blockIdx.x*256 + half;
  float s = 0.f, s2 = 0.f;
  for (int i = 0; i < 128; ++i) {
    float v = h[(size_t)(row0 + i*2)*Hd + c];
    s += v; s2 = fmaf(v, v, s2);
  }
  ls[half][c] = s; ls2[half][c] = s2;
  __syncthreads();
  if (half == 0) {
    unsafeAtomicAdd(&bns[c], s + ls[1][c]);
    unsafeAtomicAdd(&bns[128 + c], s2 + ls2[1][c]);
  }
}

__global__ void bn_final(const float* __restrict__ bns, const float* __restrict__ g,
                         const float* __restrict__ b, float* __restrict__ scale,
                         float* __restrict__ shift) {
  int c = threadIdx.x;
  float mu = bns[c] * (1.f/NTOT);
  float var = bns[128 + c] * (1.f/NTOT) - mu*mu;
  float sc = g[c] / sqrtf(var + 1e-5f);
  scale[c] = sc;
  shift[c] = b[c] - mu*sc;
}

__global__ void bn_apply(const float* __restrict__ h, const float* __restrict__ scale,
                         const float* __restrict__ shift, float* __restrict__ x) {
  size_t i = ((size_t)blockIdx.x*blockDim.x + threadIdx.x)*4;
  int c = (int)(i & (Hd-1));
  float4 v = *reinterpret_cast<const float4*>(h + i);
  float4 sc = *reinterpret_cast<const float4*>(scale + c);
  float4 sh = *reinterpret_cast<const float4*>(shift + c);
  v.x = fmaf(v.x, sc.x, sh.x); v.y = fmaf(v.y, sc.y, sh.y);
  v.z = fmaf(v.z, sc.z, sh.z); v.w = fmaf(v.w, sc.w, sh.w);
  v.x = v.x >= 0.f ? v.x : 0.01f*v.x;
  v.y = v.y >= 0.f ? v.y : 0.01f*v.y;
  v.z = v.z >= 0.f ? v.z : 0.01f*v.z;
  v.w = v.w >= 0.f ? v.w : 0.01f*v.w;
  *reinterpret_cast<float4*>(x + i) = v;
}

extern "C" void kernel_launch(void* const* d_in, const int* in_sizes, int n_in,
                              void* d_out, int out_size, void* d_ws, size_t ws_size,
                              hipStream_t stream) {
  const float* x0       = (const float*)d_in[0];
  const float* x1       = (const float*)d_in[1];
  const float* W0       = (const float*)d_in[2];
  const float* b0       = (const float*)d_in[3];
  const float* W1       = (const float*)d_in[4];
  const float* b1       = (const float*)d_in[5];
  const float* mask     = (const float*)d_in[6];
  const float* conv_root= (const float*)d_in[7];
  const float* conv_rel = (const float*)d_in[8];
  const float* conv_b   = (const float*)d_in[9];
  const float* attW     = (const float*)d_in[10];
  const float* att_q    = (const float*)d_in[11];
  const float* att_k    = (const float*)d_in[12];
  const float* att_b    = (const float*)d_in[13];
  const float* bn_g     = (const float*)d_in[14];
  const float* bn_b     = (const float*)d_in[15];
  const float* fc_W     = (const float*)d_in[16];
  const float* fc_b     = (const float*)d_in[17];
  const int* edge_index = (const int*)d_in[18];
  const int* edge_type  = (const int*)d_in[19];
  const int* src = edge_index;
  const int* dst = edge_index + NEDGE;
  (void)in_sizes; (void)n_in; (void)out_size; (void)ws_size;

  char* ws = (char*)d_ws;
  size_t off = 0;
  auto alloc = [&](size_t nf) { float* p = (float*)(ws + off); off += nf*sizeof(float); return p; };
  float* x_in   = alloc((size_t)NTOT*Hd);
  float* xbuf   = alloc((size_t)NTOT*Hd);
  float* hbuf   = alloc((size_t)NTOT*Hd);
  float* ych    = alloc((size_t)CH*1024);
  float* sq     = alloc((size_t)RREL*NTOT);
  float* sk     = alloc((size_t)RREL*NTOT);
  float* exb    = alloc(NEDGE);
  float* exs    = alloc(NEDGE);
  float* wsrc   = alloc(NEDGE);
  float* mx     = alloc(NRSEG);
  float* den    = alloc(NRSEG);
  float* invcnt = alloc(NRSEG);
  float* rm     = alloc(NTOT);
  int*   cnt      = (int*)alloc(NRSEG);
  int*   fillctr  = (int*)alloc(NRSEG);
  int*   partial  = (int*)alloc(NRSEG);
  int*   offsets  = (int*)alloc(NRSEG + 4);
  int*   bsum     = (int*)alloc(1024);
  int*   src_sorted = (int*)alloc(NEDGE);
  int*   epos       = (int*)alloc(NEDGE);
  float* qvec  = alloc(RREL*Hd);
  float* kvec  = alloc(RREL*Hd);
  float* bns   = alloc(256);
  float* bnscale = alloc(Hd);
  float* bnshift = alloc(Hd);

  // ---- static CSR over (dst, rel) segments ----
  rowmask_k<<<NTOT/256, 256, 0, stream>>>(mask, rm);
  fill_i32<<<NRSEG/256, 256, 0, stream>>>(cnt, 0, NRSEG);
  edge_count<<<NEDGE/256, 256, 0, stream>>>(dst, edge_type, cnt);
  inv_cnt_k<<<NRSEG/256, 256, 0, stream>>>(cnt, invcnt);
  scan1_k<<<NRSEG/256, 256, 0, stream>>>(cnt, partial, bsum);
  scan2_k<<<1, 256, 0, stream>>>(bsum);
  scan3_k<<<NRSEG/256, 256, 0, stream>>>(partial, bsum, offsets);
  fill_i32<<<NRSEG/256, 256, 0, stream>>>(fillctr, 0, NRSEG);
  csr_fill<<<NEDGE/256, 256, 0, stream>>>(src, dst, edge_type, offsets, fillctr, rm,
                                          src_sorted, wsrc, epos);

  // ---- x_in = [x0@W0+b0 ; x1@W1+b1] ----
  gemm64<0><<<dim3(512,1), 256, 0, stream>>>(x0, nullptr, nullptr, W0, nullptr,
                                             b0, nullptr, x_in, Hd, 4);
  gemm64<0><<<dim3(512,1), 256, 0, stream>>>(x1, nullptr, nullptr, W1, nullptr,
                                             b1, nullptr, x_in + (size_t)32768*Hd, Hd, 4);

  for (int l = 0; l < 2; ++l) {
    const float* cur = (l == 0) ? x_in : xbuf;
    // attention scalars
    qkvec_k<<<1, 512, 0, stream>>>(attW + (size_t)l*16*Hd*Hd, att_q + (size_t)l*16*Hd,
                                   att_k + (size_t)l*16*Hd, qvec, kvec);
    sqk_k<<<NTOT/4, 256, 0, stream>>>(cur, rm, qvec, kvec, sq, sk);
    layer_init<<<NRSEG/256, 256, 0, stream>>>(mx, den, bns);
    edge_logit<<<NEDGE/256, 256, 0, stream>>>(src, dst, edge_type, sq, sk, exb, mx);
    edge_expden<<<NEDGE/256, 256, 0, stream>>>(dst, edge_type, exb, mx, den);
    alpha_sort<<<NEDGE/256, 256, 0, stream>>>(dst, edge_type, epos, exb, den, exs);
    // root transform (+both biases) initializes hbuf
    gemm64<0><<<dim3(1024,1), 256, 0, stream>>>(cur, nullptr, rm,
        conv_root + (size_t)l*Hd*Hd, nullptr,
        conv_b + (size_t)l*Hd, att_b + (size_t)l*Hd, hbuf, Hd, 4);
    // chunked: gather per-(n,r) aggregates in input space, then K=1024 GEMM accumulate
    const float* Bc = conv_rel + (size_t)l*RREL*Hd*Hd;  // [512,128]
    const float* Ba = attW + (size_t)l*16*Hd*Hd;        // rows 512.. of stacked K
    for (int c = 0; c < NCHUNK; ++c) {
      int cb = c*CH;
      gather_k<<<CH/4, 256, 0, stream>>>(cur, src_sorted, wsrc, exs, offsets, invcnt, ych, cb);
      gemm64<1><<<dim3(CH/64, 4), 256, 0, stream>>>(ych, nullptr, nullptr, Bc, Ba,
          nullptr, nullptr, hbuf + (size_t)cb*Hd, 1024, 8);
    }
    bn_stats<<<256, 256, 0, stream>>>(hbuf, bns);
    bn_final<<<1, 128, 0, stream>>>(bns, bn_g + (size_t)l*Hd, bn_b + (size_t)l*Hd, bnscale, bnshift);
    bn_apply<<<(NTOT*Hd/4)/256, 256, 0, stream>>>(hbuf, bnscale, bnshift, xbuf);
  }

  // out = (x + x_in) @ fc_W + fc_b, remapped rows
  gemm64<2><<<dim3(1024,1), 256, 0, stream>>>(xbuf, x_in, nullptr, fc_W, nullptr,
                                              fc_b, nullptr, (float*)d_out, Hd, 4);
}

// Round 3
// 777.407 us; speedup vs baseline: 3.6062x; 2.5710x over previous
//
#include <hip/hip_runtime.h>
#include <cfloat>

#define Hd 128
#define NTOT 65536
#define RREL 4
#define NRSEG (NTOT*RREL)
#define NEDGE 524288
#define CH 32768

typedef unsigned short u16;
typedef unsigned int u32;
typedef short bf16x8 __attribute__((ext_vector_type(8)));
typedef float f32x4 __attribute__((ext_vector_type(4)));

__device__ __forceinline__ void atomicMaxF(float* addr, float v) {
  if (v >= 0.f) atomicMax((int*)addr, __float_as_int(v));
  else atomicMin((unsigned int*)addr, __float_as_uint(v));
}

__device__ __forceinline__ u16 f2bf(float f) {   // RNE
  u32 u = __float_as_uint(f);
  return (u16)((u + 0x7fffu + ((u >> 16) & 1u)) >> 16);
}
__device__ __forceinline__ u32 pack2(float lo, float hi) {
  return ((u32)f2bf(hi) << 16) | f2bf(lo);
}

// ================= MFMA GEMM: C[M,128] = A[M,K] @ Bt[128,K]^T =================
// Bt is n-major bf16 [128][ldb]. LDS tiles [128 rows][32 k] bf16, XOR-swizzled:
// logical byte q at physical p = q ^ (((q>>7)&3)<<4)  (involution, row bits untouched).
// Staged via global_load_lds (linear LDS dest = base + lane*16, pre-swizzled global src).
__device__ __forceinline__ void stage_tile(const u16* __restrict__ g, int ld,
                                           u16* lds, int wave, int lane) {
#pragma unroll
  for (int t = 0; t < 2; ++t) {
    int i = wave*2 + t;                       // issue 0..7, 16 rows each
    int row = i*16 + (lane >> 2);
    int col16 = (lane & 3) ^ ((lane >> 3) & 3);   // inverse-swizzled source chunk
    const u16* src = g + (size_t)row*ld + col16*8;
    __builtin_amdgcn_global_load_lds((const __attribute__((address_space(1))) void*)src,
                                     (__attribute__((address_space(3))) void*)(lds + i*512),
                                     16, 0, 0);
  }
}

// CMODE 0: plain write (+bias if non-null); 1: C += (block owns tile, no atomics);
// CMODE 2: remapped final-output write (+bias)
template<int CMODE>
__global__ __launch_bounds__(256) void mgemm(const u16* __restrict__ A, int lda,
                                             const u16* __restrict__ Bt, int ldb,
                                             const float* __restrict__ bias,
                                             float* __restrict__ C, int kTot)
{
  __shared__ u16 As[4096], Bs[4096];
  const int tid = threadIdx.x, wave = tid >> 6, lane = tid & 63;
  const int wm = wave >> 1, wn = wave & 1;
  const int brow = blockIdx.x * 128;
  const u16* Ab = A + (size_t)brow*lda;
  f32x4 acc[4][4];
#pragma unroll
  for (int i = 0; i < 4; ++i)
#pragma unroll
    for (int j = 0; j < 4; ++j) acc[i][j] = (f32x4){0.f, 0.f, 0.f, 0.f};

  const int ks = (lane >> 4) * 16;   // k-subgroup byte offset
  const int rl = lane & 15;
  for (int k0 = 0; k0 < kTot; k0 += 32) {
    stage_tile(Ab + k0, lda, As, wave, lane);
    stage_tile(Bt + k0, ldb, Bs, wave, lane);
    __syncthreads();
    bf16x8 af[4], bv[4];
    const char* Ac = (const char*)As;
    const char* Bc = (const char*)Bs;
#pragma unroll
    for (int i = 0; i < 4; ++i) {
      int r = wm*64 + i*16 + rl;
      int by = (r*64 + ks) ^ (((r >> 1) & 3) << 4);
      af[i] = *(const bf16x8*)(Ac + by);
    }
#pragma unroll
    for (int j = 0; j < 4; ++j) {
      int r = wn*64 + j*16 + rl;
      int by = (r*64 + ks) ^ (((r >> 1) & 3) << 4);
      bv[j] = *(const bf16x8*)(Bc + by);
    }
#pragma unroll
    for (int i = 0; i < 4; ++i)
#pragma unroll
      for (int j = 0; j < 4; ++j)
        acc[i][j] = __builtin_amdgcn_mfma_f32_16x16x32_bf16(af[i], bv[j], acc[i][j], 0, 0, 0);
    __syncthreads();
  }
  // epilogue: C/D frag layout col=lane&15, row=(lane>>4)*4+reg
  const int cl = lane & 15;
  const int rq = (lane >> 4) * 4;
#pragma unroll
  for (int i = 0; i < 4; ++i) {
#pragma unroll
    for (int q = 0; q < 4; ++q) {
      int row = brow + wm*64 + i*16 + rq + q;
      size_t ob;
      if (CMODE == 2) {
        int b = row >> 6, p = row & 63;
        ob = (p == 0) ? (size_t)b*Hd
                      : (size_t)(1024*Hd) + ((size_t)(b*63 + (p-1)))*Hd;
      } else {
        ob = (size_t)row * Hd;
      }
#pragma unroll
      for (int j = 0; j < 4; ++j) {
        int col = wn*64 + j*16 + cl;
        float v = acc[i][j][q];
        if (CMODE == 1) {
          C[ob + col] += v;
        } else {
          if (bias) v += bias[col];
          C[ob + col] = v;
        }
      }
    }
  }
}

// ---------------- weight transpose+convert: Bt[o][koff+k] = bf16(B[k][o]) ----------------
__global__ void wtrans(const float* __restrict__ B, u16* __restrict__ Bt,
                       int K, int ldb, int koff) {
  int idx = blockIdx.x*256 + threadIdx.x;
  if (idx >= K*128) return;
  int k = idx >> 7, o = idx & 127;
  Bt[(size_t)o*ldb + koff + k] = f2bf(B[idx]);
}

// ---------------- small utility kernels ----------------
__global__ void fill_i32(int* p, int v, int n) {
  int i = blockIdx.x*blockDim.x + threadIdx.x;
  if (i < n) p[i] = v;
}
__global__ void rowmask_k(const float* __restrict__ mask, float* __restrict__ rm) {
  int n = blockIdx.x*blockDim.x + threadIdx.x;
  if (n < NTOT) rm[n] = mask[(size_t)n*Hd];
}
__global__ void edge_count(const int* __restrict__ dst, const int* __restrict__ et, int* __restrict__ cnt) {
  int e = blockIdx.x*blockDim.x + threadIdx.x;
  if (e < NEDGE) atomicAdd(&cnt[dst[e]*RREL + et[e]], 1);
}
__global__ void inv_cnt_k(const int* __restrict__ cnt, float* __restrict__ invc) {
  int i = blockIdx.x*blockDim.x + threadIdx.x;
  if (i < NRSEG) invc[i] = 1.f / (float)max(cnt[i], 1);
}
__global__ void cvt_bf16(const float* __restrict__ src, u16* __restrict__ dst, int n4) {
  int i = blockIdx.x*256 + threadIdx.x;
  if (i >= n4) return;
  float4 v = *reinterpret_cast<const float4*>(src + (size_t)i*4);
  u32 o0 = pack2(v.x, v.y), o1 = pack2(v.z, v.w);
  *reinterpret_cast<uint2*>(dst + (size_t)i*4) = make_uint2(o0, o1);
}
__global__ void mkxmb(const float* __restrict__ x, const float* __restrict__ rm,
                      u16* __restrict__ xmb) {
  int i = blockIdx.x*256 + threadIdx.x;
  float s = rm[i >> 5];
  float4 v = *reinterpret_cast<const float4*>(x + (size_t)i*4);
  *reinterpret_cast<uint2*>(xmb + (size_t)i*4) =
      make_uint2(pack2(v.x*s, v.y*s), pack2(v.z*s, v.w*s));
}

// ---------------- CSR build ----------------
__global__ void scan1_k(const int* __restrict__ cnt, int* __restrict__ partial, int* __restrict__ bsum) {
  __shared__ int sh[256];
  int t = threadIdx.x;
  int i = blockIdx.x*256 + t;
  int v = cnt[i];
  sh[t] = v; __syncthreads();
  for (int off = 1; off < 256; off <<= 1) {
    int u = (t >= off) ? sh[t-off] : 0;
    __syncthreads();
    sh[t] += u;
    __syncthreads();
  }
  partial[i] = sh[t] - v;
  if (t == 255) bsum[blockIdx.x] = sh[255];
}
__global__ void scan2_k(int* __restrict__ bsum) {
  __shared__ int sh[256];
  int t = threadIdx.x;
  int v0 = bsum[t*4+0], v1 = bsum[t*4+1], v2 = bsum[t*4+2], v3 = bsum[t*4+3];
  int tot = v0+v1+v2+v3;
  sh[t] = tot; __syncthreads();
  for (int off = 1; off < 256; off <<= 1) {
    int u = (t >= off) ? sh[t-off] : 0;
    __syncthreads();
    sh[t] += u;
    __syncthreads();
  }
  int base = sh[t] - tot;
  bsum[t*4+0] = base;
  bsum[t*4+1] = base + v0;
  bsum[t*4+2] = base + v0+v1;
  bsum[t*4+3] = base + v0+v1+v2;
}
__global__ void scan3_k(const int* __restrict__ partial, const int* __restrict__ bsum, int* __restrict__ offsets) {
  int i = blockIdx.x*256 + threadIdx.x;
  offsets[i] = partial[i] + bsum[i >> 8];
  if (i == 0) offsets[NRSEG] = NEDGE;
}
__global__ void csr_fill(const int* __restrict__ src, const int* __restrict__ dst,
                         const int* __restrict__ et, const int* __restrict__ offsets,
                         int* __restrict__ fillctr,
                         int* __restrict__ src_sorted, int* __restrict__ epos) {
  int e = blockIdx.x*blockDim.x + threadIdx.x;
  if (e >= NEDGE) return;
  int seg = dst[e]*RREL + et[e];
  int pos = offsets[seg] + atomicAdd(&fillctr[seg], 1);
  src_sorted[pos] = src[e];
  epos[e] = pos;
}

// ---------------- attention scalar path ----------------
__global__ void qkvec_k(const float* __restrict__ attW, const float* __restrict__ att_q,
                        const float* __restrict__ att_k,
                        float* __restrict__ qvec, float* __restrict__ kvec) {
  int r = threadIdx.x >> 7, h = threadIdx.x & 127;
  const float* wrow = attW + ((size_t)r*Hd + h)*Hd;
  const float* qv = att_q + (size_t)r*Hd;
  const float* kv = att_k + (size_t)r*Hd;
  float sq_ = 0.f, sk_ = 0.f;
  for (int o = 0; o < Hd; ++o) { float w = wrow[o]; sq_ = fmaf(w, qv[o], sq_); sk_ = fmaf(w, kv[o], sk_); }
  qvec[r*Hd + h] = sq_;
  kvec[r*Hd + h] = sk_;
}

__global__ void sqk_k(const u16* __restrict__ xmb, const float* __restrict__ qvec,
                      const float* __restrict__ kvec, float* __restrict__ sq, float* __restrict__ sk) {
  int w = blockIdx.x*4 + (threadIdx.x >> 6);
  if (w >= NTOT) return;
  int lane = threadIdx.x & 63;
  u32 u = *reinterpret_cast<const u32*>(xmb + (size_t)w*Hd + lane*2);
  float vx = __uint_as_float(u << 16);
  float vy = __uint_as_float(u & 0xffff0000u);
  float pq[RREL], pk[RREL];
#pragma unroll
  for (int r = 0; r < RREL; ++r) {
    float2 q = *reinterpret_cast<const float2*>(qvec + r*Hd + lane*2);
    float2 k = *reinterpret_cast<const float2*>(kvec + r*Hd + lane*2);
    pq[r] = vx*q.x + vy*q.y;
    pk[r] = vx*k.x + vy*k.y;
  }
#pragma unroll
  for (int off = 32; off > 0; off >>= 1) {
#pragma unroll
    for (int r = 0; r < RREL; ++r) {
      pq[r] += __shfl_xor(pq[r], off);
      pk[r] += __shfl_xor(pk[r], off);
    }
  }
  if (lane == 0) {
#pragma unroll
    for (int r = 0; r < RREL; ++r) {
      sq[(size_t)r*NTOT + w] = pq[r];
      sk[(size_t)r*NTOT + w] = pk[r];
    }
  }
}

__global__ void layer_init(float* __restrict__ mx, float* __restrict__ den, float* __restrict__ bns) {
  int i = blockIdx.x*blockDim.x + threadIdx.x;
  if (i < NRSEG) { mx[i] = -FLT_MAX; den[i] = 0.f; }
  if (i < 256) bns[i] = 0.f;
}
__global__ void edge_logit(const int* __restrict__ src, const int* __restrict__ dst,
                           const int* __restrict__ et, const float* __restrict__ sq,
                           const float* __restrict__ sk, float* __restrict__ exb,
                           float* __restrict__ mx) {
  int e = blockIdx.x*blockDim.x + threadIdx.x;
  if (e >= NEDGE) return;
  int t = et[e];
  float lg = sq[(size_t)t*NTOT + dst[e]] + sk[(size_t)t*NTOT + src[e]];
  lg = lg >= 0.f ? lg : 0.2f*lg;
  exb[e] = lg;
  atomicMaxF(&mx[dst[e]*RREL + t], lg);
}
__global__ void edge_expden(const int* __restrict__ dst, const int* __restrict__ et,
                            float* __restrict__ exb, const float* __restrict__ mx,
                            float* __restrict__ den) {
  int e = blockIdx.x*blockDim.x + threadIdx.x;
  if (e >= NEDGE) return;
  int seg = dst[e]*RREL + et[e];
  float ex = __expf(exb[e] - mx[seg]);
  exb[e] = ex;
  unsafeAtomicAdd(&den[seg], ex);
}
__global__ void alpha_sort(const int* __restrict__ dst, const int* __restrict__ et,
                           const int* __restrict__ epos, const float* __restrict__ exb,
                           const float* __restrict__ den, float* __restrict__ exs_sorted) {
  int e = blockIdx.x*blockDim.x + threadIdx.x;
  if (e >= NEDGE) return;
  int seg = dst[e]*RREL + et[e];
  exs_sorted[epos[e]] = exb[e] / fmaxf(den[seg], 1e-16f);
}

// ------- gather: one wave per (node,rel); Y row = [conv(512) | att(512)] bf16 -------
__global__ __launch_bounds__(256) void gather_k(
    const u16* __restrict__ xmb, const int* __restrict__ src_sorted,
    const float* __restrict__ exs, const int* __restrict__ offsets,
    const float* __restrict__ invcnt, u16* __restrict__ ych, int cb)
{
  int wid = blockIdx.x*4 + (threadIdx.x >> 6);
  int w = wid >> 2, r = wid & 3;
  int n = cb + w;
  int lane = threadIdx.x & 63;
  int seg = n*RREL + r;
  int e0 = offsets[seg], e1 = offsets[seg+1];
  float cx = 0.f, cy = 0.f, ax = 0.f, ay = 0.f;
  for (int e = e0; e < e1; ++e) {
    int s = src_sorted[e];
    float al = exs[e];
    u32 u = *reinterpret_cast<const u32*>(xmb + (size_t)s*Hd + lane*2);
    float vx = __uint_as_float(u << 16);
    float vy = __uint_as_float(u & 0xffff0000u);
    cx += vx; cy += vy;
    ax = fmaf(al, vx, ax); ay = fmaf(al, vy, ay);
  }
  float ic = invcnt[seg];
  u32* yu = reinterpret_cast<u32*>(ych + (size_t)w*1024);
  yu[r*64 + lane]       = pack2(cx*ic, cy*ic);
  yu[256 + r*64 + lane] = pack2(ax, ay);
}

// ---------------- batchnorm ----------------
__global__ void bn_stats(const float* __restrict__ h, float* __restrict__ bns) {
  __shared__ float ls[2][128], ls2[2][128];
  int c = threadIdx.x & 127, half = threadIdx.x >> 7;
  int row0 = blockIdx.x*256 + half;
  float s = 0.f, s2 = 0.f;
  for (int i = 0; i < 128; ++i) {
    float v = h[(size_t)(row0 + i*2)*Hd + c];
    s += v; s2 = fmaf(v, v, s2);
  }
  ls[half][c] = s; ls2[half][c] = s2;
  __syncthreads();
  if (half == 0) {
    unsafeAtomicAdd(&bns[c], s + ls[1][c]);
    unsafeAtomicAdd(&bns[128 + c], s2 + ls2[1][c]);
  }
}
__global__ void bn_final(const float* __restrict__ bns, const float* __restrict__ g,
                         const float* __restrict__ b, float* __restrict__ scale,
                         float* __restrict__ shift) {
  int c = threadIdx.x;
  float mu = bns[c] * (1.f/NTOT);
  float var = bns[128 + c] * (1.f/NTOT) - mu*mu;
  float sc = g[c] / sqrtf(var + 1e-5f);
  scale[c] = sc;
  shift[c] = b[c] - mu*sc;
}

// LAST=0: x=leaky(bn(h)) written in-place to xout, xmb=bf16(rm*x)
// LAST=1: xmb=bf16(leaky(bn(h)) + x_in)   (no f32 x write)
template<int LAST>
__global__ void bn_apply(const float* __restrict__ h, const float* __restrict__ scale,
                         const float* __restrict__ shift, const float* __restrict__ rm,
                         const float* __restrict__ x_in, float* __restrict__ xout,
                         u16* __restrict__ xmb) {
  int i = blockIdx.x*256 + threadIdx.x;     // one float4
  size_t i4 = (size_t)i*4;
  int c = (int)(i4 & 127);
  float4 v = *reinterpret_cast<const float4*>(h + i4);
  float4 sc = *reinterpret_cast<const float4*>(scale + c);
  float4 sh = *reinterpret_cast<const float4*>(shift + c);
  v.x = fmaf(v.x, sc.x, sh.x); v.y = fmaf(v.y, sc.y, sh.y);
  v.z = fmaf(v.z, sc.z, sh.z); v.w = fmaf(v.w, sc.w, sh.w);
  v.x = v.x >= 0.f ? v.x : 0.01f*v.x;
  v.y = v.y >= 0.f ? v.y : 0.01f*v.y;
  v.z = v.z >= 0.f ? v.z : 0.01f*v.z;
  v.w = v.w >= 0.f ? v.w : 0.01f*v.w;
  float4 xb;
  if (LAST) {
    float4 rsd = *reinterpret_cast<const float4*>(x_in + i4);
    xb.x = v.x + rsd.x; xb.y = v.y + rsd.y; xb.z = v.z + rsd.z; xb.w = v.w + rsd.w;
  } else {
    *reinterpret_cast<float4*>(xout + i4) = v;
    float s = rm[i >> 5];
    xb.x = v.x*s; xb.y = v.y*s; xb.z = v.z*s; xb.w = v.w*s;
  }
  *reinterpret_cast<uint2*>(xmb + i4) = make_uint2(pack2(xb.x, xb.y), pack2(xb.z, xb.w));
}

extern "C" void kernel_launch(void* const* d_in, const int* in_sizes, int n_in,
                              void* d_out, int out_size, void* d_ws, size_t ws_size,
                              hipStream_t stream) {
  const float* x0       = (const float*)d_in[0];
  const float* x1       = (const float*)d_in[1];
  const float* W0       = (const float*)d_in[2];
  const float* b0       = (const float*)d_in[3];
  const float* W1       = (const float*)d_in[4];
  const float* b1       = (const float*)d_in[5];
  const float* mask     = (const float*)d_in[6];
  const float* conv_root= (const float*)d_in[7];
  const float* conv_rel = (const float*)d_in[8];
  const float* attW     = (const float*)d_in[10];
  const float* att_q    = (const float*)d_in[11];
  const float* att_k    = (const float*)d_in[12];
  const float* bn_g     = (const float*)d_in[14];
  const float* bn_b     = (const float*)d_in[15];
  const float* fc_W     = (const float*)d_in[16];
  const float* fc_b     = (const float*)d_in[17];
  const int* edge_index = (const int*)d_in[18];
  const int* edge_type  = (const int*)d_in[19];
  const int* src = edge_index;
  const int* dst = edge_index + NEDGE;
  (void)in_sizes; (void)n_in; (void)out_size; (void)ws_size;

  char* ws = (char*)d_ws;
  size_t off = 0;
  auto alloc = [&](size_t bytes) { void* p = ws + off; off = (off + bytes + 255) & ~(size_t)255; return p; };
  float* x_in  = (float*)alloc((size_t)NTOT*Hd*4);
  float* hbuf  = (float*)alloc((size_t)NTOT*Hd*4);
  u16*   xmb   = (u16*)  alloc((size_t)NTOT*Hd*2);
  u16*   ych   = (u16*)  alloc((size_t)CH*1024*2);
  float* sq    = (float*)alloc((size_t)RREL*NTOT*4);
  float* sk    = (float*)alloc((size_t)RREL*NTOT*4);
  float* exb   = (float*)alloc((size_t)NEDGE*4);
  float* exs   = (float*)alloc((size_t)NEDGE*4);
  float* mx    = (float*)alloc((size_t)NRSEG*4);
  float* den   = (float*)alloc((size_t)NRSEG*4);
  float* invcnt= (float*)alloc((size_t)NRSEG*4);
  float* rm    = (float*)alloc((size_t)NTOT*4);
  int* cnt        = (int*)alloc((size_t)NRSEG*4);
  int* fillctr    = (int*)alloc((size_t)NRSEG*4);
  int* partial    = (int*)alloc((size_t)NRSEG*4);
  int* offsets    = (int*)alloc((size_t)(NRSEG+4)*4);
  int* bsum       = (int*)alloc(4096);
  int* src_sorted = (int*)alloc((size_t)NEDGE*4);
  int* epos       = (int*)alloc((size_t)NEDGE*4);
  float* qvec   = (float*)alloc(512*4);
  float* kvec   = (float*)alloc(512*4);
  float* bns    = (float*)alloc(1024);
  float* bnscale= (float*)alloc(512);
  float* bnshift= (float*)alloc(512);
  u16* Btw  = (u16*)alloc((size_t)128*128*2);
  u16* Btca = (u16*)alloc((size_t)128*1024*2);

  // ---- static CSR over (dst, rel) segments ----
  rowmask_k<<<NTOT/256, 256, 0, stream>>>(mask, rm);
  fill_i32<<<NRSEG/256, 256, 0, stream>>>(cnt, 0, NRSEG);
  edge_count<<<NEDGE/256, 256, 0, stream>>>(dst, edge_type, cnt);
  inv_cnt_k<<<NRSEG/256, 256, 0, stream>>>(cnt, invcnt);
  scan1_k<<<NRSEG/256, 256, 0, stream>>>(cnt, partial, bsum);
  scan2_k<<<1, 256, 0, stream>>>(bsum);
  scan3_k<<<NRSEG/256, 256, 0, stream>>>(partial, bsum, offsets);
  fill_i32<<<NRSEG/256, 256, 0, stream>>>(fillctr, 0, NRSEG);
  csr_fill<<<NEDGE/256, 256, 0, stream>>>(src, dst, edge_type, offsets, fillctr,
                                          src_sorted, epos);

  // ---- x_in = [x0@W0+b0 ; x1@W1+b1]  (bf16 MFMA) ----
  cvt_bf16<<<(32768*Hd/4)/256, 256, 0, stream>>>(x0, xmb, 32768*Hd/4);
  cvt_bf16<<<(32768*Hd/4)/256, 256, 0, stream>>>(x1, xmb + (size_t)32768*Hd, 32768*Hd/4);
  wtrans<<<(128*128)/256, 256, 0, stream>>>(W0, Btw, 128, 128, 0);
  mgemm<0><<<256, 256, 0, stream>>>(xmb, Hd, Btw, 128, b0, x_in, 128);
  wtrans<<<(128*128)/256, 256, 0, stream>>>(W1, Btw, 128, 128, 0);
  mgemm<0><<<256, 256, 0, stream>>>(xmb + (size_t)32768*Hd, Hd, Btw, 128, b1,
                                    x_in + (size_t)32768*Hd, 128);
  mkxmb<<<(NTOT*Hd/4)/256, 256, 0, stream>>>(x_in, rm, xmb);

  for (int l = 0; l < 2; ++l) {
    const float* attW_l = attW + (size_t)l*16*Hd*Hd;
    // attention scalars (from masked bf16 features)
    qkvec_k<<<1, 512, 0, stream>>>(attW_l, att_q + (size_t)l*16*Hd, att_k + (size_t)l*16*Hd, qvec, kvec);
    sqk_k<<<NTOT/4, 256, 0, stream>>>(xmb, qvec, kvec, sq, sk);
    layer_init<<<NRSEG/256, 256, 0, stream>>>(mx, den, bns);
    edge_logit<<<NEDGE/256, 256, 0, stream>>>(src, dst, edge_type, sq, sk, exb, mx);
    edge_expden<<<NEDGE/256, 256, 0, stream>>>(dst, edge_type, exb, mx, den);
    alpha_sort<<<NEDGE/256, 256, 0, stream>>>(dst, edge_type, epos, exb, den, exs);
    // root transform initializes h (conv_b/att_b cancel exactly in BN)
    wtrans<<<(128*128)/256, 256, 0, stream>>>(conv_root + (size_t)l*Hd*Hd, Btw, 128, 128, 0);
    mgemm<0><<<512, 256, 0, stream>>>(xmb, Hd, Btw, 128, nullptr, hbuf, 128);
    // stacked conv+att weights, K=1024
    wtrans<<<(512*128)/256, 256, 0, stream>>>(conv_rel + (size_t)l*RREL*Hd*Hd, Btca, 512, 1024, 0);
    wtrans<<<(512*128)/256, 256, 0, stream>>>(attW_l, Btca, 512, 1024, 512);
    for (int c = 0; c < NTOT/CH; ++c) {
      gather_k<<<CH, 256, 0, stream>>>(xmb, src_sorted, exs, offsets, invcnt, ych, c*CH);
      mgemm<1><<<CH/128, 256, 0, stream>>>(ych, 1024, Btca, 1024, nullptr,
                                           hbuf + (size_t)c*CH*Hd, 1024);
    }
    bn_stats<<<256, 256, 0, stream>>>(hbuf, bns);
    bn_final<<<1, 128, 0, stream>>>(bns, bn_g + (size_t)l*Hd, bn_b + (size_t)l*Hd, bnscale, bnshift);
    if (l == 0)
      bn_apply<0><<<(NTOT*Hd/4)/256, 256, 0, stream>>>(hbuf, bnscale, bnshift, rm, x_in, hbuf, xmb);
    else
      bn_apply<1><<<(NTOT*Hd/4)/256, 256, 0, stream>>>(hbuf, bnscale, bnshift, rm, x_in, nullptr, xmb);
  }

  // out = (x + x_in) @ fc_W + fc_b, remapped rows
  wtrans<<<(128*128)/256, 256, 0, stream>>>(fc_W, Btw, 128, 128, 0);
  mgemm<2><<<512, 256, 0, stream>>>(xmb, Hd, Btw, 128, fc_b, (float*)d_out, 128);
}

// Round 4
// 773.201 us; speedup vs baseline: 3.6258x; 1.0054x over previous
//
#include <hip/hip_runtime.h>
#include <cfloat>

#define Hd 128
#define NTOT 65536
#define RREL 4
#define NRSEG (NTOT*RREL)
#define NEDGE 524288

typedef unsigned short u16;
typedef unsigned int u32;
typedef short bf16x8 __attribute__((ext_vector_type(8)));
typedef float f32x4 __attribute__((ext_vector_type(4)));

__device__ __forceinline__ void atomicMaxF(float* addr, float v) {
  if (v >= 0.f) atomicMax((int*)addr, __float_as_int(v));
  else atomicMin((unsigned int*)addr, __float_as_uint(v));
}

__device__ __forceinline__ u16 f2bf(float f) {   // RNE
  u32 u = __float_as_uint(f);
  return (u16)((u + 0x7fffu + ((u >> 16) & 1u)) >> 16);
}
__device__ __forceinline__ u32 pack2(float lo, float hi) {
  return ((u32)f2bf(hi) << 16) | f2bf(lo);
}

// swizzled byte offset within a [128 rows][256 B] LDS tile (involution on bits 7:4)
__device__ __forceinline__ int swzb(int row, int o) {
  return (row*256 + o) ^ ((row & 15) << 4);
}

// ======== mgemm (unchanged from round 3): C[M,128] = A[M,K] @ Bt[128,K]^T ========
__device__ __forceinline__ void stage_tile(const u16* __restrict__ g, int ld,
                                           u16* lds, int wave, int lane) {
#pragma unroll
  for (int t = 0; t < 2; ++t) {
    int i = wave*2 + t;
    int row = i*16 + (lane >> 2);
    int col16 = (lane & 3) ^ ((lane >> 3) & 3);
    const u16* src = g + (size_t)row*ld + col16*8;
    __builtin_amdgcn_global_load_lds((const __attribute__((address_space(1))) void*)src,
                                     (__attribute__((address_space(3))) void*)(lds + i*512),
                                     16, 0, 0);
  }
}

// CMODE 0: plain write (+bias); 2: remapped final-output write (+bias), A2 residual n/a (A pre-summed)
template<int CMODE>
__global__ __launch_bounds__(256) void mgemm(const u16* __restrict__ A, int lda,
                                             const u16* __restrict__ Bt, int ldb,
                                             const float* __restrict__ bias,
                                             float* __restrict__ C, int kTot)
{
  __shared__ u16 As[4096], Bs[4096];
  const int tid = threadIdx.x, wave = tid >> 6, lane = tid & 63;
  const int wm = wave >> 1, wn = wave & 1;
  const int brow = blockIdx.x * 128;
  const u16* Ab = A + (size_t)brow*lda;
  f32x4 acc[4][4];
#pragma unroll
  for (int i = 0; i < 4; ++i)
#pragma unroll
    for (int j = 0; j < 4; ++j) acc[i][j] = (f32x4){0.f, 0.f, 0.f, 0.f};

  const int ks = (lane >> 4) * 16;
  const int rl = lane & 15;
  for (int k0 = 0; k0 < kTot; k0 += 32) {
    stage_tile(Ab + k0, lda, As, wave, lane);
    stage_tile(Bt + k0, ldb, Bs, wave, lane);
    __syncthreads();
    bf16x8 af[4], bv[4];
    const char* Ac = (const char*)As;
    const char* Bc = (const char*)Bs;
#pragma unroll
    for (int i = 0; i < 4; ++i) {
      int r = wm*64 + i*16 + rl;
      int by = (r*64 + ks) ^ (((r >> 1) & 3) << 4);
      af[i] = *(const bf16x8*)(Ac + by);
    }
#pragma unroll
    for (int j = 0; j < 4; ++j) {
      int r = wn*64 + j*16 + rl;
      int by = (r*64 + ks) ^ (((r >> 1) & 3) << 4);
      bv[j] = *(const bf16x8*)(Bc + by);
    }
#pragma unroll
    for (int i = 0; i < 4; ++i)
#pragma unroll
      for (int j = 0; j < 4; ++j)
        acc[i][j] = __builtin_amdgcn_mfma_f32_16x16x32_bf16(af[i], bv[j], acc[i][j], 0, 0, 0);
    __syncthreads();
  }
  const int cl = lane & 15;
  const int rq = (lane >> 4) * 4;
#pragma unroll
  for (int i = 0; i < 4; ++i) {
#pragma unroll
    for (int q = 0; q < 4; ++q) {
      int row = brow + wm*64 + i*16 + rq + q;
      size_t ob;
      if (CMODE == 2) {
        int b = row >> 6, p = row & 63;
        ob = (p == 0) ? (size_t)b*Hd
                      : (size_t)(1024*Hd) + ((size_t)(b*63 + (p-1)))*Hd;
      } else {
        ob = (size_t)row * Hd;
      }
#pragma unroll
      for (int j = 0; j < 4; ++j) {
        int col = wn*64 + j*16 + cl;
        float v = acc[i][j][q];
        if (bias) v += bias[col];
        C[ob + col] = v;
      }
    }
  }
}

// ======== fused gather + K=1152 GEMM + BN-stats ========
// Btg: bf16 [128 out][1152], chunks: 0..3 conv_rel r, 4..7 attW r, 8 conv_root
__device__ __forceinline__ void stage128(const u16* __restrict__ gbase, int ld,
                                         u16* lds, int wave, int lane) {
#pragma unroll
  for (int t = 0; t < 4; ++t) {
    int ti = wave*4 + t;
    int row = ti*4 + (lane >> 4);
    int lchunk = (lane & 15) ^ (row & 15);
    const u16* src = gbase + (size_t)row*ld + lchunk*8;
    __builtin_amdgcn_global_load_lds((const __attribute__((address_space(1))) void*)src,
                                     (__attribute__((address_space(3))) void*)(lds + ti*512),
                                     16, 0, 0);
  }
}

__device__ __forceinline__ void mfma128(const u16* Yt, const u16* Bt, f32x4 (&acc)[4][2],
                                        int wm, int wn, int lane) {
  const int rl = lane & 15;
  const int ko = (lane >> 4) * 16;
  const char* Yc_ = (const char*)Yt;
  const char* Bc_ = (const char*)Bt;
#pragma unroll
  for (int ks = 0; ks < 4; ++ks) {
    int o = ks*64 + ko;
    bf16x8 af[4], bv[2];
#pragma unroll
    for (int i = 0; i < 4; ++i)
      af[i] = *(const bf16x8*)(Yc_ + swzb(wm*64 + i*16 + rl, o));
#pragma unroll
    for (int j = 0; j < 2; ++j)
      bv[j] = *(const bf16x8*)(Bc_ + swzb(wn*32 + j*16 + rl, o));
#pragma unroll
    for (int i = 0; i < 4; ++i)
#pragma unroll
      for (int j = 0; j < 2; ++j)
        acc[i][j] = __builtin_amdgcn_mfma_f32_16x16x32_bf16(af[i], bv[j], acc[i][j], 0, 0, 0);
  }
}

__global__ __launch_bounds__(512) void fused_gemm(
    const u16* __restrict__ xmb, const int* __restrict__ src_sorted,
    const float* __restrict__ exs, const int* __restrict__ offsets,
    const float* __restrict__ invcnt, const u16* __restrict__ Btg,
    float* __restrict__ hbuf, float* __restrict__ bns)
{
  __shared__ u16 Yc[16384];
  __shared__ u16 Ya[16384];
  __shared__ u16 B0[16384];
  __shared__ u16 B1[16384];
  const int tid = threadIdx.x, wave = tid >> 6, lane = tid & 63;
  const int wm = wave >> 2, wn = wave & 3;
  const int brow = blockIdx.x * 128;
  f32x4 acc[4][2];
#pragma unroll
  for (int i = 0; i < 4; ++i)
#pragma unroll
    for (int j = 0; j < 2; ++j) acc[i][j] = (f32x4){0.f, 0.f, 0.f, 0.f};

  for (int r = 0; r < RREL; ++r) {
    if (r) __syncthreads();             // protect Y/B from previous iteration's readers
    stage128(Btg + r*128, 1152, B0, wave, lane);        // in flight during gather
    stage128(Btg + (4+r)*128, 1152, B1, wave, lane);
    // ---- gather: 16 local nodes per wave, 4 concurrent edge chains ----
#pragma unroll 1
    for (int g = 0; g < 4; ++g) {
      int ln0 = wave*16 + g*4;
      int e[4], E[4];
      float cx[4], cy[4], ax[4], ay[4];
#pragma unroll
      for (int m = 0; m < 4; ++m) {
        int seg = (brow + ln0 + m)*RREL + r;
        e[m] = offsets[seg]; E[m] = offsets[seg+1];
        cx[m] = cy[m] = ax[m] = ay[m] = 0.f;
      }
      bool run = (e[0] < E[0]) | (e[1] < E[1]) | (e[2] < E[2]) | (e[3] < E[3]);
      while (run) {
        u32 u[4]; float al[4]; bool a[4];
#pragma unroll
        for (int m = 0; m < 4; ++m) {
          a[m] = e[m] < E[m];
          if (a[m]) {
            int s = src_sorted[e[m]];
            al[m] = exs[e[m]];
            u[m] = *(const u32*)(xmb + (size_t)s*Hd + lane*2);
          }
        }
        run = false;
#pragma unroll
        for (int m = 0; m < 4; ++m) {
          if (a[m]) {
            float vx = __uint_as_float(u[m] << 16);
            float vy = __uint_as_float(u[m] & 0xffff0000u);
            cx[m] += vx; cy[m] += vy;
            ax[m] = fmaf(al[m], vx, ax[m]);
            ay[m] = fmaf(al[m], vy, ay[m]);
            e[m]++;
            run |= (e[m] < E[m]);
          }
        }
      }
#pragma unroll
      for (int m = 0; m < 4; ++m) {
        int ln = ln0 + m;
        float ic = invcnt[(brow + ln)*RREL + r];
        *(u32*)((char*)Yc + swzb(ln, lane*4)) = pack2(cx[m]*ic, cy[m]*ic);
        *(u32*)((char*)Ya + swzb(ln, lane*4)) = pack2(ax[m], ay[m]);
      }
    }
    __syncthreads();                    // Y writes + B stages complete
    mfma128(Yc, B0, acc, wm, wn, lane);
    mfma128(Ya, B1, acc, wm, wn, lane);
  }
  // ---- root chunk: Y = xmb tile (linear dest, inverse-swizzled source) ----
  __syncthreads();
  stage128(xmb + (size_t)brow*Hd, Hd, Yc, wave, lane);
  stage128(Btg + 8*128, 1152, B0, wave, lane);
  __syncthreads();
  mfma128(Yc, B0, acc, wm, wn, lane);

  // ---- epilogue: write hbuf + BN partial sums ----
  const int cl = lane & 15, rq = (lane >> 4) * 4;
#pragma unroll
  for (int j = 0; j < 2; ++j) {
    float s = 0.f, s2 = 0.f;
#pragma unroll
    for (int i = 0; i < 4; ++i) {
#pragma unroll
      for (int q = 0; q < 4; ++q) {
        float v = acc[i][j][q];
        int row = brow + wm*64 + i*16 + rq + q;
        hbuf[(size_t)row*Hd + wn*32 + j*16 + cl] = v;
        s += v; s2 = fmaf(v, v, s2);
      }
    }
    s  += __shfl_xor(s, 16);  s  += __shfl_xor(s, 32);
    s2 += __shfl_xor(s2, 16); s2 += __shfl_xor(s2, 32);
    if (lane < 16) {
      int col = wn*32 + j*16 + cl;
      unsafeAtomicAdd(&bns[col], s);
      unsafeAtomicAdd(&bns[128 + col], s2);
    }
  }
}

// ---------------- weight transpose+convert: Bt[o][koff+k] = bf16(B[k][o]) ----------------
__global__ void wtrans(const float* __restrict__ B, u16* __restrict__ Bt,
                       int K, int ldb, int koff) {
  int idx = blockIdx.x*256 + threadIdx.x;
  if (idx >= K*128) return;
  int k = idx >> 7, o = idx & 127;
  Bt[(size_t)o*ldb + koff + k] = f2bf(B[idx]);
}

// ---------------- small utility kernels ----------------
__global__ void fill_i32(int* p, int v, int n) {
  int i = blockIdx.x*blockDim.x + threadIdx.x;
  if (i < n) p[i] = v;
}
__global__ void rowmask_k(const float* __restrict__ mask, float* __restrict__ rm) {
  int n = blockIdx.x*blockDim.x + threadIdx.x;
  if (n < NTOT) rm[n] = mask[(size_t)n*Hd];
}
__global__ void edge_count(const int* __restrict__ dst, const int* __restrict__ et, int* __restrict__ cnt) {
  int e = blockIdx.x*blockDim.x + threadIdx.x;
  if (e < NEDGE) atomicAdd(&cnt[dst[e]*RREL + et[e]], 1);
}
__global__ void inv_cnt_k(const int* __restrict__ cnt, float* __restrict__ invc) {
  int i = blockIdx.x*blockDim.x + threadIdx.x;
  if (i < NRSEG) invc[i] = 1.f / (float)max(cnt[i], 1);
}
__global__ void cvt_bf16(const float* __restrict__ src, u16* __restrict__ dst, int n4) {
  int i = blockIdx.x*256 + threadIdx.x;
  if (i >= n4) return;
  float4 v = *reinterpret_cast<const float4*>(src + (size_t)i*4);
  *reinterpret_cast<uint2*>(dst + (size_t)i*4) = make_uint2(pack2(v.x, v.y), pack2(v.z, v.w));
}
__global__ void mkxmb(const float* __restrict__ x, const float* __restrict__ rm,
                      u16* __restrict__ xmb) {
  int i = blockIdx.x*256 + threadIdx.x;
  float s = rm[i >> 5];
  float4 v = *reinterpret_cast<const float4*>(x + (size_t)i*4);
  *reinterpret_cast<uint2*>(xmb + (size_t)i*4) =
      make_uint2(pack2(v.x*s, v.y*s), pack2(v.z*s, v.w*s));
}

// ---------------- CSR build ----------------
__global__ void scan1_k(const int* __restrict__ cnt, int* __restrict__ partial, int* __restrict__ bsum) {
  __shared__ int sh[256];
  int t = threadIdx.x;
  int i = blockIdx.x*256 + t;
  int v = cnt[i];
  sh[t] = v; __syncthreads();
  for (int off = 1; off < 256; off <<= 1) {
    int u = (t >= off) ? sh[t-off] : 0;
    __syncthreads();
    sh[t] += u;
    __syncthreads();
  }
  partial[i] = sh[t] - v;
  if (t == 255) bsum[blockIdx.x] = sh[255];
}
__global__ void scan2_k(int* __restrict__ bsum) {
  __shared__ int sh[256];
  int t = threadIdx.x;
  int v0 = bsum[t*4+0], v1 = bsum[t*4+1], v2 = bsum[t*4+2], v3 = bsum[t*4+3];
  int tot = v0+v1+v2+v3;
  sh[t] = tot; __syncthreads();
  for (int off = 1; off < 256; off <<= 1) {
    int u = (t >= off) ? sh[t-off] : 0;
    __syncthreads();
    sh[t] += u;
    __syncthreads();
  }
  int base = sh[t] - tot;
  bsum[t*4+0] = base;
  bsum[t*4+1] = base + v0;
  bsum[t*4+2] = base + v0+v1;
  bsum[t*4+3] = base + v0+v1+v2;
}
__global__ void scan3_k(const int* __restrict__ partial, const int* __restrict__ bsum, int* __restrict__ offsets) {
  int i = blockIdx.x*256 + threadIdx.x;
  offsets[i] = partial[i] + bsum[i >> 8];
  if (i == 0) offsets[NRSEG] = NEDGE;
}
__global__ void csr_fill(const int* __restrict__ src, const int* __restrict__ dst,
                         const int* __restrict__ et, const int* __restrict__ offsets,
                         int* __restrict__ fillctr,
                         int* __restrict__ src_sorted, int* __restrict__ epos) {
  int e = blockIdx.x*blockDim.x + threadIdx.x;
  if (e >= NEDGE) return;
  int seg = dst[e]*RREL + et[e];
  int pos = offsets[seg] + atomicAdd(&fillctr[seg], 1);
  src_sorted[pos] = src[e];
  epos[e] = pos;
}

// ---------------- attention scalar path ----------------
__global__ void qkvec_k(const float* __restrict__ attW, const float* __restrict__ att_q,
                        const float* __restrict__ att_k,
                        float* __restrict__ qvec, float* __restrict__ kvec) {
  int r = threadIdx.x >> 7, h = threadIdx.x & 127;
  const float* wrow = attW + ((size_t)r*Hd + h)*Hd;
  const float* qv = att_q + (size_t)r*Hd;
  const float* kv = att_k + (size_t)r*Hd;
  float sq_ = 0.f, sk_ = 0.f;
  for (int o = 0; o < Hd; ++o) { float w = wrow[o]; sq_ = fmaf(w, qv[o], sq_); sk_ = fmaf(w, kv[o], sk_); }
  qvec[r*Hd + h] = sq_;
  kvec[r*Hd + h] = sk_;
}

__global__ void sqk_k(const u16* __restrict__ xmb, const float* __restrict__ qvec,
                      const float* __restrict__ kvec, float* __restrict__ sq, float* __restrict__ sk) {
  int w = blockIdx.x*4 + (threadIdx.x >> 6);
  if (w >= NTOT) return;
  int lane = threadIdx.x & 63;
  u32 u = *reinterpret_cast<const u32*>(xmb + (size_t)w*Hd + lane*2);
  float vx = __uint_as_float(u << 16);
  float vy = __uint_as_float(u & 0xffff0000u);
  float pq[RREL], pk[RREL];
#pragma unroll
  for (int r = 0; r < RREL; ++r) {
    float2 q = *reinterpret_cast<const float2*>(qvec + r*Hd + lane*2);
    float2 k = *reinterpret_cast<const float2*>(kvec + r*Hd + lane*2);
    pq[r] = vx*q.x + vy*q.y;
    pk[r] = vx*k.x + vy*k.y;
  }
#pragma unroll
  for (int off = 32; off > 0; off >>= 1) {
#pragma unroll
    for (int r = 0; r < RREL; ++r) {
      pq[r] += __shfl_xor(pq[r], off);
      pk[r] += __shfl_xor(pk[r], off);
    }
  }
  if (lane == 0) {
#pragma unroll
    for (int r = 0; r < RREL; ++r) {
      sq[(size_t)r*NTOT + w] = pq[r];
      sk[(size_t)r*NTOT + w] = pk[r];
    }
  }
}

__global__ void layer_init(float* __restrict__ mx, float* __restrict__ den, float* __restrict__ bns) {
  int i = blockIdx.x*blockDim.x + threadIdx.x;
  if (i < NRSEG) { mx[i] = -FLT_MAX; den[i] = 0.f; }
  if (i < 256) bns[i] = 0.f;
}
__global__ void edge_logit(const int* __restrict__ src, const int* __restrict__ dst,
                           const int* __restrict__ et, const float* __restrict__ sq,
                           const float* __restrict__ sk, float* __restrict__ exb,
                           float* __restrict__ mx) {
  int e = blockIdx.x*blockDim.x + threadIdx.x;
  if (e >= NEDGE) return;
  int t = et[e];
  float lg = sq[(size_t)t*NTOT + dst[e]] + sk[(size_t)t*NTOT + src[e]];
  lg = lg >= 0.f ? lg : 0.2f*lg;
  exb[e] = lg;
  atomicMaxF(&mx[dst[e]*RREL + t], lg);
}
__global__ void edge_expden(const int* __restrict__ dst, const int* __restrict__ et,
                            float* __restrict__ exb, const float* __restrict__ mx,
                            float* __restrict__ den) {
  int e = blockIdx.x*blockDim.x + threadIdx.x;
  if (e >= NEDGE) return;
  int seg = dst[e]*RREL + et[e];
  float ex = __expf(exb[e] - mx[seg]);
  exb[e] = ex;
  unsafeAtomicAdd(&den[seg], ex);
}
__global__ void alpha_sort(const int* __restrict__ dst, const int* __restrict__ et,
                           const int* __restrict__ epos, const float* __restrict__ exb,
                           const float* __restrict__ den, float* __restrict__ exs_sorted) {
  int e = blockIdx.x*blockDim.x + threadIdx.x;
  if (e >= NEDGE) return;
  int seg = dst[e]*RREL + et[e];
  exs_sorted[epos[e]] = exb[e] / fmaxf(den[seg], 1e-16f);
}

// ---------------- batchnorm finalize/apply ----------------
__global__ void bn_final(const float* __restrict__ bns, const float* __restrict__ g,
                         const float* __restrict__ b, float* __restrict__ scale,
                         float* __restrict__ shift) {
  int c = threadIdx.x;
  float mu = bns[c] * (1.f/NTOT);
  float var = bns[128 + c] * (1.f/NTOT) - mu*mu;
  float sc = g[c] / sqrtf(var + 1e-5f);
  scale[c] = sc;
  shift[c] = b[c] - mu*sc;
}

// LAST=0: xmb = bf16(rm * leaky(bn(h)))   LAST=1: xmb = bf16(leaky(bn(h)) + x_in)
template<int LAST>
__global__ void bn_apply(const float* __restrict__ h, const float* __restrict__ scale,
                         const float* __restrict__ shift, const float* __restrict__ rm,
                         const float* __restrict__ x_in, u16* __restrict__ xmb) {
  int i = blockIdx.x*256 + threadIdx.x;
  size_t i4 = (size_t)i*4;
  int c = (int)(i4 & 127);
  float4 v = *reinterpret_cast<const float4*>(h + i4);
  float4 sc = *reinterpret_cast<const float4*>(scale + c);
  float4 sh = *reinterpret_cast<const float4*>(shift + c);
  v.x = fmaf(v.x, sc.x, sh.x); v.y = fmaf(v.y, sc.y, sh.y);
  v.z = fmaf(v.z, sc.z, sh.z); v.w = fmaf(v.w, sc.w, sh.w);
  v.x = v.x >= 0.f ? v.x : 0.01f*v.x;
  v.y = v.y >= 0.f ? v.y : 0.01f*v.y;
  v.z = v.z >= 0.f ? v.z : 0.01f*v.z;
  v.w = v.w >= 0.f ? v.w : 0.01f*v.w;
  float4 xb;
  if (LAST) {
    float4 rsd = *reinterpret_cast<const float4*>(x_in + i4);
    xb.x = v.x + rsd.x; xb.y = v.y + rsd.y; xb.z = v.z + rsd.z; xb.w = v.w + rsd.w;
  } else {
    float s = rm[i >> 5];
    xb.x = v.x*s; xb.y = v.y*s; xb.z = v.z*s; xb.w = v.w*s;
  }
  *reinterpret_cast<uint2*>(xmb + i4) = make_uint2(pack2(xb.x, xb.y), pack2(xb.z, xb.w));
}

extern "C" void kernel_launch(void* const* d_in, const int* in_sizes, int n_in,
                              void* d_out, int out_size, void* d_ws, size_t ws_size,
                              hipStream_t stream) {
  const float* x0       = (const float*)d_in[0];
  const float* x1       = (const float*)d_in[1];
  const float* W0       = (const float*)d_in[2];
  const float* b0       = (const float*)d_in[3];
  const float* W1       = (const float*)d_in[4];
  const float* b1       = (const float*)d_in[5];
  const float* mask     = (const float*)d_in[6];
  const float* conv_root= (const float*)d_in[7];
  const float* conv_rel = (const float*)d_in[8];
  const float* attW     = (const float*)d_in[10];
  const float* att_q    = (const float*)d_in[11];
  const float* att_k    = (const float*)d_in[12];
  const float* bn_g     = (const float*)d_in[14];
  const float* bn_b     = (const float*)d_in[15];
  const float* fc_W     = (const float*)d_in[16];
  const float* fc_b     = (const float*)d_in[17];
  const int* edge_index = (const int*)d_in[18];
  const int* edge_type  = (const int*)d_in[19];
  const int* src = edge_index;
  const int* dst = edge_index + NEDGE;
  (void)in_sizes; (void)n_in; (void)out_size; (void)ws_size;

  char* ws = (char*)d_ws;
  size_t off = 0;
  auto alloc = [&](size_t bytes) { void* p = ws + off; off = (off + bytes + 255) & ~(size_t)255; return p; };
  float* x_in  = (float*)alloc((size_t)NTOT*Hd*4);
  float* hbuf  = (float*)alloc((size_t)NTOT*Hd*4);
  u16*   xmb   = (u16*)  alloc((size_t)NTOT*Hd*2);
  float* sq    = (float*)alloc((size_t)RREL*NTOT*4);
  float* sk    = (float*)alloc((size_t)RREL*NTOT*4);
  float* exb   = (float*)alloc((size_t)NEDGE*4);
  float* exs   = (float*)alloc((size_t)NEDGE*4);
  float* mx    = (float*)alloc((size_t)NRSEG*4);
  float* den   = (float*)alloc((size_t)NRSEG*4);
  float* invcnt= (float*)alloc((size_t)NRSEG*4);
  float* rm    = (float*)alloc((size_t)NTOT*4);
  int* cnt        = (int*)alloc((size_t)NRSEG*4);
  int* fillctr    = (int*)alloc((size_t)NRSEG*4);
  int* partial    = (int*)alloc((size_t)NRSEG*4);
  int* offsets    = (int*)alloc((size_t)(NRSEG+4)*4);
  int* bsum       = (int*)alloc(4096);
  int* src_sorted = (int*)alloc((size_t)NEDGE*4);
  int* epos       = (int*)alloc((size_t)NEDGE*4);
  float* qvec   = (float*)alloc(512*4);
  float* kvec   = (float*)alloc(512*4);
  float* bns    = (float*)alloc(1024);
  float* bnscale= (float*)alloc(512);
  float* bnshift= (float*)alloc(512);
  u16* Btw  = (u16*)alloc((size_t)128*128*2);
  u16* Btg0 = (u16*)alloc((size_t)128*1152*2);
  u16* Btg1 = (u16*)alloc((size_t)128*1152*2);
  u16* BtgL[2] = {Btg0, Btg1};

  // ---- static CSR over (dst, rel) segments ----
  rowmask_k<<<NTOT/256, 256, 0, stream>>>(mask, rm);
  fill_i32<<<NRSEG/256, 256, 0, stream>>>(cnt, 0, NRSEG);
  edge_count<<<NEDGE/256, 256, 0, stream>>>(dst, edge_type, cnt);
  inv_cnt_k<<<NRSEG/256, 256, 0, stream>>>(cnt, invcnt);
  scan1_k<<<NRSEG/256, 256, 0, stream>>>(cnt, partial, bsum);
  scan2_k<<<1, 256, 0, stream>>>(bsum);
  scan3_k<<<NRSEG/256, 256, 0, stream>>>(partial, bsum, offsets);
  fill_i32<<<NRSEG/256, 256, 0, stream>>>(fillctr, 0, NRSEG);
  csr_fill<<<NEDGE/256, 256, 0, stream>>>(src, dst, edge_type, offsets, fillctr,
                                          src_sorted, epos);

  // ---- per-layer stacked weights: [conv_rel r | attW r | conv_root], bf16 [128][1152] ----
  for (int l = 0; l < 2; ++l) {
    wtrans<<<(512*128)/256, 256, 0, stream>>>(conv_rel + (size_t)l*RREL*Hd*Hd, BtgL[l], 512, 1152, 0);
    wtrans<<<(512*128)/256, 256, 0, stream>>>(attW + (size_t)l*16*Hd*Hd, BtgL[l], 512, 1152, 512);
    wtrans<<<(128*128)/256, 256, 0, stream>>>(conv_root + (size_t)l*Hd*Hd, BtgL[l], 128, 1152, 1024);
  }

  // ---- x_in = [x0@W0+b0 ; x1@W1+b1]  (bf16 MFMA) ----
  cvt_bf16<<<(32768*Hd/4)/256, 256, 0, stream>>>(x0, xmb, 32768*Hd/4);
  cvt_bf16<<<(32768*Hd/4)/256, 256, 0, stream>>>(x1, xmb + (size_t)32768*Hd, 32768*Hd/4);
  wtrans<<<(128*128)/256, 256, 0, stream>>>(W0, Btw, 128, 128, 0);
  mgemm<0><<<256, 256, 0, stream>>>(xmb, Hd, Btw, 128, b0, x_in, 128);
  wtrans<<<(128*128)/256, 256, 0, stream>>>(W1, Btw, 128, 128, 0);
  mgemm<0><<<256, 256, 0, stream>>>(xmb + (size_t)32768*Hd, Hd, Btw, 128, b1,
                                    x_in + (size_t)32768*Hd, 128);
  mkxmb<<<(NTOT*Hd/4)/256, 256, 0, stream>>>(x_in, rm, xmb);

  for (int l = 0; l < 2; ++l) {
    const float* attW_l = attW + (size_t)l*16*Hd*Hd;
    qkvec_k<<<1, 512, 0, stream>>>(attW_l, att_q + (size_t)l*16*Hd, att_k + (size_t)l*16*Hd, qvec, kvec);
    sqk_k<<<NTOT/4, 256, 0, stream>>>(xmb, qvec, kvec, sq, sk);
    layer_init<<<NRSEG/256, 256, 0, stream>>>(mx, den, bns);
    edge_logit<<<NEDGE/256, 256, 0, stream>>>(src, dst, edge_type, sq, sk, exb, mx);
    edge_expden<<<NEDGE/256, 256, 0, stream>>>(dst, edge_type, exb, mx, den);
    alpha_sort<<<NEDGE/256, 256, 0, stream>>>(dst, edge_type, epos, exb, den, exs);
    // fused: gather + (conv|att|root) GEMM + BN partial stats  (conv_b/att_b cancel in BN)
    fused_gemm<<<NTOT/128, 512, 0, stream>>>(xmb, src_sorted, exs, offsets, invcnt,
                                             BtgL[l], hbuf, bns);
    bn_final<<<1, 128, 0, stream>>>(bns, bn_g + (size_t)l*Hd, bn_b + (size_t)l*Hd, bnscale, bnshift);
    if (l == 0)
      bn_apply<0><<<(NTOT*Hd/4)/256, 256, 0, stream>>>(hbuf, bnscale, bnshift, rm, x_in, xmb);
    else
      bn_apply<1><<<(NTOT*Hd/4)/256, 256, 0, stream>>>(hbuf, bnscale, bnshift, rm, x_in, xmb);
  }

  // out = (x + x_in) @ fc_W + fc_b, remapped rows
  wtrans<<<(128*128)/256, 256, 0, stream>>>(fc_W, Btw, 128, 128, 0);
  mgemm<2><<<512, 256, 0, stream>>>(xmb, Hd, Btw, 128, fc_b, (float*)d_out, 128);
}

// Round 5
// 737.934 us; speedup vs baseline: 3.7991x; 1.0478x over previous
//
#include <hip/hip_runtime.h>
#include <cfloat>

#define Hd 128
#define NTOT 65536
#define RREL 4
#define NRSEG (NTOT*RREL)
#define NEDGE 524288

typedef unsigned short u16;
typedef unsigned int u32;
typedef short bf16x8 __attribute__((ext_vector_type(8)));
typedef float f32x4 __attribute__((ext_vector_type(4)));

__device__ __forceinline__ u16 f2bf(float f) {   // RNE
  u32 u = __float_as_uint(f);
  return (u16)((u + 0x7fffu + ((u >> 16) & 1u)) >> 16);
}
__device__ __forceinline__ u32 pack2(float lo, float hi) {
  return ((u32)f2bf(hi) << 16) | f2bf(lo);
}

// swizzled byte offset within a [128 rows][256 B] LDS tile (involution on bits 7:4)
__device__ __forceinline__ int swzb(int row, int o) {
  return (row*256 + o) ^ ((row & 15) << 4);
}

// ======== mgemm: C[M,128] = A[M,K] @ Bt[128,K]^T ========
__device__ __forceinline__ void stage_tile(const u16* __restrict__ g, int ld,
                                           u16* lds, int wave, int lane) {
#pragma unroll
  for (int t = 0; t < 2; ++t) {
    int i = wave*2 + t;
    int row = i*16 + (lane >> 2);
    int col16 = (lane & 3) ^ ((lane >> 3) & 3);
    const u16* src = g + (size_t)row*ld + col16*8;
    __builtin_amdgcn_global_load_lds((const __attribute__((address_space(1))) void*)src,
                                     (__attribute__((address_space(3))) void*)(lds + i*512),
                                     16, 0, 0);
  }
}

// CMODE 0: plain write (+bias); 2: remapped final-output write (+bias)
template<int CMODE>
__global__ __launch_bounds__(256) void mgemm(const u16* __restrict__ A, int lda,
                                             const u16* __restrict__ Bt, int ldb,
                                             const float* __restrict__ bias,
                                             float* __restrict__ C, int kTot)
{
  __shared__ u16 As[4096], Bs[4096];
  const int tid = threadIdx.x, wave = tid >> 6, lane = tid & 63;
  const int wm = wave >> 1, wn = wave & 1;
  const int brow = blockIdx.x * 128;
  const u16* Ab = A + (size_t)brow*lda;
  f32x4 acc[4][4];
#pragma unroll
  for (int i = 0; i < 4; ++i)
#pragma unroll
    for (int j = 0; j < 4; ++j) acc[i][j] = (f32x4){0.f, 0.f, 0.f, 0.f};

  const int ks = (lane >> 4) * 16;
  const int rl = lane & 15;
  for (int k0 = 0; k0 < kTot; k0 += 32) {
    stage_tile(Ab + k0, lda, As, wave, lane);
    stage_tile(Bt + k0, ldb, Bs, wave, lane);
    __syncthreads();
    bf16x8 af[4], bv[4];
    const char* Ac = (const char*)As;
    const char* Bc = (const char*)Bs;
#pragma unroll
    for (int i = 0; i < 4; ++i) {
      int r = wm*64 + i*16 + rl;
      int by = (r*64 + ks) ^ (((r >> 1) & 3) << 4);
      af[i] = *(const bf16x8*)(Ac + by);
    }
#pragma unroll
    for (int j = 0; j < 4; ++j) {
      int r = wn*64 + j*16 + rl;
      int by = (r*64 + ks) ^ (((r >> 1) & 3) << 4);
      bv[j] = *(const bf16x8*)(Bc + by);
    }
#pragma unroll
    for (int i = 0; i < 4; ++i)
#pragma unroll
      for (int j = 0; j < 4; ++j)
        acc[i][j] = __builtin_amdgcn_mfma_f32_16x16x32_bf16(af[i], bv[j], acc[i][j], 0, 0, 0);
    __syncthreads();
  }
  const int cl = lane & 15;
  const int rq = (lane >> 4) * 4;
#pragma unroll
  for (int i = 0; i < 4; ++i) {
#pragma unroll
    for (int q = 0; q < 4; ++q) {
      int row = brow + wm*64 + i*16 + rq + q;
      size_t ob;
      if (CMODE == 2) {
        int b = row >> 6, p = row & 63;
        ob = (p == 0) ? (size_t)b*Hd
                      : (size_t)(1024*Hd) + ((size_t)(b*63 + (p-1)))*Hd;
      } else {
        ob = (size_t)row * Hd;
      }
#pragma unroll
      for (int j = 0; j < 4; ++j) {
        int col = wn*64 + j*16 + cl;
        float v = acc[i][j][q];
        if (bias) v += bias[col];
        C[ob + col] = v;
      }
    }
  }
}

// ======== fused gather + K=1152 GEMM + BN-stats (64 KB LDS, 2 blocks/CU) ========
// Btg: bf16 [128 out][1152], chunks: 0..3 conv_rel r, 4..7 attW r, 8 conv_root
__device__ __forceinline__ void stage128(const u16* __restrict__ gbase, int ld,
                                         u16* lds, int wave, int lane) {
#pragma unroll
  for (int t = 0; t < 4; ++t) {
    int ti = wave*4 + t;
    int row = ti*4 + (lane >> 4);
    int lchunk = (lane & 15) ^ (row & 15);
    const u16* src = gbase + (size_t)row*ld + lchunk*8;
    __builtin_amdgcn_global_load_lds((const __attribute__((address_space(1))) void*)src,
                                     (__attribute__((address_space(3))) void*)(lds + ti*512),
                                     16, 0, 0);
  }
}

__device__ __forceinline__ void mfma128(const u16* Yt, const u16* Bt, f32x4 (&acc)[4][2],
                                        int wm, int wn, int lane) {
  const int rl = lane & 15;
  const int ko = (lane >> 4) * 16;
  const char* Yc_ = (const char*)Yt;
  const char* Bc_ = (const char*)Bt;
#pragma unroll
  for (int ks = 0; ks < 4; ++ks) {
    int o = ks*64 + ko;
    bf16x8 af[4], bv[2];
#pragma unroll
    for (int i = 0; i < 4; ++i)
      af[i] = *(const bf16x8*)(Yc_ + swzb(wm*64 + i*16 + rl, o));
#pragma unroll
    for (int j = 0; j < 2; ++j)
      bv[j] = *(const bf16x8*)(Bc_ + swzb(wn*32 + j*16 + rl, o));
#pragma unroll
    for (int i = 0; i < 4; ++i)
#pragma unroll
      for (int j = 0; j < 2; ++j)
        acc[i][j] = __builtin_amdgcn_mfma_f32_16x16x32_bf16(af[i], bv[j], acc[i][j], 0, 0, 0);
  }
}

__global__ __launch_bounds__(512, 4) void fused_gemm(
    const u16* __restrict__ xmb, const int* __restrict__ src_sorted,
    const float* __restrict__ exs, const int* __restrict__ offsets,
    const float* __restrict__ invcnt, const float* __restrict__ den,
    const u16* __restrict__ Btg, float* __restrict__ hbuf, float* __restrict__ bns)
{
  __shared__ u16 Yt[16384];   // 32 KB: Y tile (conv, then att, then root rows)
  __shared__ u16 Bw[16384];   // 32 KB: weight tile
  const int tid = threadIdx.x, wave = tid >> 6, lane = tid & 63;
  const int wm = wave >> 2, wn = wave & 3;
  const int brow = blockIdx.x * 128;
  f32x4 acc[4][2];
#pragma unroll
  for (int i = 0; i < 4; ++i)
#pragma unroll
    for (int j = 0; j < 2; ++j) acc[i][j] = (f32x4){0.f, 0.f, 0.f, 0.f};

  float axv[16], ayv[16];     // att sums held across conv mfma (static-indexed)

  for (int r = 0; r < RREL; ++r) {
    __syncthreads();                        // Yt/Bw free (prev att-mfma done)
    stage128(Btg + r*128, 1152, Bw, wave, lane);   // conv weights, in flight during gather
#pragma unroll
    for (int g = 0; g < 4; ++g) {
      int ln0 = wave*16 + g*4;
      int e[4], E[4];
      float cx[4], cy[4], ax[4], ay[4];
#pragma unroll
      for (int m = 0; m < 4; ++m) {
        int seg = (brow + ln0 + m)*RREL + r;
        e[m] = offsets[seg]; E[m] = offsets[seg+1];
        cx[m] = cy[m] = ax[m] = ay[m] = 0.f;
      }
      bool run = (e[0] < E[0]) | (e[1] < E[1]) | (e[2] < E[2]) | (e[3] < E[3]);
      while (run) {
        u32 u[4]; float al[4]; bool a[4];
#pragma unroll
        for (int m = 0; m < 4; ++m) {
          a[m] = e[m] < E[m];
          if (a[m]) {
            int s = src_sorted[e[m]];
            al[m] = exs[e[m]];
            u[m] = *(const u32*)(xmb + (size_t)s*Hd + lane*2);
          }
        }
        run = false;
#pragma unroll
        for (int m = 0; m < 4; ++m) {
          if (a[m]) {
            float vx = __uint_as_float(u[m] << 16);
            float vy = __uint_as_float(u[m] & 0xffff0000u);
            cx[m] += vx; cy[m] += vy;
            ax[m] = fmaf(al[m], vx, ax[m]);
            ay[m] = fmaf(al[m], vy, ay[m]);
            e[m]++;
            run |= (e[m] < E[m]);
          }
        }
      }
#pragma unroll
      for (int m = 0; m < 4; ++m) {
        int ln = ln0 + m;
        int seg = (brow + ln)*RREL + r;
        float ic = invcnt[seg];
        float idn = 1.f / fmaxf(den[seg], 1e-16f);
        *(u32*)((char*)Yt + swzb(ln, lane*4)) = pack2(cx[m]*ic, cy[m]*ic);
        axv[g*4+m] = ax[m]*idn;
        ayv[g*4+m] = ay[m]*idn;
      }
    }
    __syncthreads();                        // Y conv written + B0 staged
    mfma128(Yt, Bw, acc, wm, wn, lane);     // conv contribution
    __syncthreads();                        // conv reads done; Yt/Bw reusable
    stage128(Btg + (4+r)*128, 1152, Bw, wave, lane);   // att weights
#pragma unroll
    for (int g = 0; g < 4; ++g)
#pragma unroll
      for (int m = 0; m < 4; ++m) {
        int ln = wave*16 + g*4 + m;
        *(u32*)((char*)Yt + swzb(ln, lane*4)) = pack2(axv[g*4+m], ayv[g*4+m]);
      }
    __syncthreads();                        // Y att written + B1 staged
    mfma128(Yt, Bw, acc, wm, wn, lane);     // att contribution
  }
  // ---- root chunk: Y = xmb tile ----
  __syncthreads();
  stage128(xmb + (size_t)brow*Hd, Hd, Yt, wave, lane);
  stage128(Btg + 8*128, 1152, Bw, wave, lane);
  __syncthreads();
  mfma128(Yt, Bw, acc, wm, wn, lane);

  // ---- epilogue: write hbuf + BN partial sums ----
  const int cl = lane & 15, rq = (lane >> 4) * 4;
#pragma unroll
  for (int j = 0; j < 2; ++j) {
    float s = 0.f, s2 = 0.f;
#pragma unroll
    for (int i = 0; i < 4; ++i) {
#pragma unroll
      for (int q = 0; q < 4; ++q) {
        float v = acc[i][j][q];
        int row = brow + wm*64 + i*16 + rq + q;
        hbuf[(size_t)row*Hd + wn*32 + j*16 + cl] = v;
        s += v; s2 = fmaf(v, v, s2);
      }
    }
    s  += __shfl_xor(s, 16);  s  += __shfl_xor(s, 32);
    s2 += __shfl_xor(s2, 16); s2 += __shfl_xor(s2, 32);
    if (lane < 16) {
      int col = wn*32 + j*16 + cl;
      unsafeAtomicAdd(&bns[col], s);
      unsafeAtomicAdd(&bns[128 + col], s2);
    }
  }
}

// ---------------- weight transpose+convert: Bt[o][koff+k] = bf16(B[k][o]) ----------------
__global__ void wtrans(const float* __restrict__ B, u16* __restrict__ Bt,
                       int K, int ldb, int koff) {
  int idx = blockIdx.x*256 + threadIdx.x;
  if (idx >= K*128) return;
  int k = idx >> 7, o = idx & 127;
  Bt[(size_t)o*ldb + koff + k] = f2bf(B[idx]);
}

// ---------------- small utility kernels ----------------
__global__ void fill_i32(int* p, int v, int n) {
  int i = blockIdx.x*blockDim.x + threadIdx.x;
  if (i < n) p[i] = v;
}
__global__ void rowmask_k(const float* __restrict__ mask, float* __restrict__ rm) {
  int n = blockIdx.x*blockDim.x + threadIdx.x;
  if (n < NTOT) rm[n] = mask[(size_t)n*Hd];
}
__global__ void edge_count(const int* __restrict__ dst, const int* __restrict__ et, int* __restrict__ cnt) {
  int e = blockIdx.x*blockDim.x + threadIdx.x;
  if (e < NEDGE) atomicAdd(&cnt[dst[e]*RREL + et[e]], 1);
}
__global__ void inv_cnt_k(const int* __restrict__ cnt, float* __restrict__ invc) {
  int i = blockIdx.x*blockDim.x + threadIdx.x;
  if (i < NRSEG) invc[i] = 1.f / (float)max(cnt[i], 1);
}
__global__ void cvt_bf16(const float* __restrict__ src, u16* __restrict__ dst, int n4) {
  int i = blockIdx.x*256 + threadIdx.x;
  if (i >= n4) return;
  float4 v = *reinterpret_cast<const float4*>(src + (size_t)i*4);
  *reinterpret_cast<uint2*>(dst + (size_t)i*4) = make_uint2(pack2(v.x, v.y), pack2(v.z, v.w));
}
__global__ void mkxmb(const float* __restrict__ x, const float* __restrict__ rm,
                      u16* __restrict__ xmb) {
  int i = blockIdx.x*256 + threadIdx.x;
  float s = rm[i >> 5];
  float4 v = *reinterpret_cast<const float4*>(x + (size_t)i*4);
  *reinterpret_cast<uint2*>(xmb + (size_t)i*4) =
      make_uint2(pack2(v.x*s, v.y*s), pack2(v.z*s, v.w*s));
}

// ---------------- CSR build ----------------
__global__ void scan1_k(const int* __restrict__ cnt, int* __restrict__ partial, int* __restrict__ bsum) {
  __shared__ int sh[256];
  int t = threadIdx.x;
  int i = blockIdx.x*256 + t;
  int v = cnt[i];
  sh[t] = v; __syncthreads();
  for (int off = 1; off < 256; off <<= 1) {
    int u = (t >= off) ? sh[t-off] : 0;
    __syncthreads();
    sh[t] += u;
    __syncthreads();
  }
  partial[i] = sh[t] - v;
  if (t == 255) bsum[blockIdx.x] = sh[255];
}
__global__ void scan2_k(int* __restrict__ bsum) {
  __shared__ int sh[256];
  int t = threadIdx.x;
  int v0 = bsum[t*4+0], v1 = bsum[t*4+1], v2 = bsum[t*4+2], v3 = bsum[t*4+3];
  int tot = v0+v1+v2+v3;
  sh[t] = tot; __syncthreads();
  for (int off = 1; off < 256; off <<= 1) {
    int u = (t >= off) ? sh[t-off] : 0;
    __syncthreads();
    sh[t] += u;
    __syncthreads();
  }
  int base = sh[t] - tot;
  bsum[t*4+0] = base;
  bsum[t*4+1] = base + v0;
  bsum[t*4+2] = base + v0+v1;
  bsum[t*4+3] = base + v0+v1+v2;
}
__global__ void scan3_k(const int* __restrict__ partial, const int* __restrict__ bsum, int* __restrict__ offsets) {
  int i = blockIdx.x*256 + threadIdx.x;
  offsets[i] = partial[i] + bsum[i >> 8];
  if (i == 0) offsets[NRSEG] = NEDGE;
}
__global__ void csr_fill(const int* __restrict__ src, const int* __restrict__ dst,
                         const int* __restrict__ et, const int* __restrict__ offsets,
                         int* __restrict__ fillctr,
                         int* __restrict__ src_sorted, int* __restrict__ epos) {
  int e = blockIdx.x*blockDim.x + threadIdx.x;
  if (e >= NEDGE) return;
  int seg = dst[e]*RREL + et[e];
  int pos = offsets[seg] + atomicAdd(&fillctr[seg], 1);
  src_sorted[pos] = src[e];
  epos[e] = pos;
}

// ---------------- attention scalar path ----------------
__global__ void qkvec_k(const float* __restrict__ attW, const float* __restrict__ att_q,
                        const float* __restrict__ att_k,
                        float* __restrict__ qvec, float* __restrict__ kvec) {
  int r = threadIdx.x >> 7, h = threadIdx.x & 127;
  const float* wrow = attW + ((size_t)r*Hd + h)*Hd;
  const float* qv = att_q + (size_t)r*Hd;
  const float* kv = att_k + (size_t)r*Hd;
  float sq_ = 0.f, sk_ = 0.f;
  for (int o = 0; o < Hd; ++o) { float w = wrow[o]; sq_ = fmaf(w, qv[o], sq_); sk_ = fmaf(w, kv[o], sk_); }
  qvec[r*Hd + h] = sq_;
  kvec[r*Hd + h] = sk_;
}

__global__ void sqk_k(const u16* __restrict__ xmb, const float* __restrict__ qvec,
                      const float* __restrict__ kvec, float* __restrict__ sq, float* __restrict__ sk) {
  int w = blockIdx.x*4 + (threadIdx.x >> 6);
  if (w >= NTOT) return;
  int lane = threadIdx.x & 63;
  u32 u = *reinterpret_cast<const u32*>(xmb + (size_t)w*Hd + lane*2);
  float vx = __uint_as_float(u << 16);
  float vy = __uint_as_float(u & 0xffff0000u);
  float pq[RREL], pk[RREL];
#pragma unroll
  for (int r = 0; r < RREL; ++r) {
    float2 q = *reinterpret_cast<const float2*>(qvec + r*Hd + lane*2);
    float2 k = *reinterpret_cast<const float2*>(kvec + r*Hd + lane*2);
    pq[r] = vx*q.x + vy*q.y;
    pk[r] = vx*k.x + vy*k.y;
  }
#pragma unroll
  for (int off = 32; off > 0; off >>= 1) {
#pragma unroll
    for (int r = 0; r < RREL; ++r) {
      pq[r] += __shfl_xor(pq[r], off);
      pk[r] += __shfl_xor(pk[r], off);
    }
  }
  if (lane == 0) {
#pragma unroll
    for (int r = 0; r < RREL; ++r) {
      sq[(size_t)r*NTOT + w] = pq[r];
      sk[(size_t)r*NTOT + w] = pk[r];
    }
  }
}

__global__ void layer_init(float* __restrict__ den, float* __restrict__ bns) {
  int i = blockIdx.x*blockDim.x + threadIdx.x;
  if (i < NRSEG) den[i] = 0.f;
  if (i < 256) bns[i] = 0.f;
}

// one pass: ex = exp(leaky(logit)) (no max-subtract; logits bounded), sorted write + den
__global__ void edge_ex(const int* __restrict__ src, const int* __restrict__ dst,
                        const int* __restrict__ et, const float* __restrict__ sq,
                        const float* __restrict__ sk, const int* __restrict__ epos,
                        float* __restrict__ exs, float* __restrict__ den) {
  int e = blockIdx.x*blockDim.x + threadIdx.x;
  if (e >= NEDGE) return;
  int t = et[e];
  float lg = sq[(size_t)t*NTOT + dst[e]] + sk[(size_t)t*NTOT + src[e]];
  lg = lg >= 0.f ? lg : 0.2f*lg;
  float ex = __expf(lg);
  exs[epos[e]] = ex;
  unsafeAtomicAdd(&den[dst[e]*RREL + t], ex);
}

// ---------------- batchnorm finalize/apply ----------------
__global__ void bn_final(const float* __restrict__ bns, const float* __restrict__ g,
                         const float* __restrict__ b, float* __restrict__ scale,
                         float* __restrict__ shift) {
  int c = threadIdx.x;
  float mu = bns[c] * (1.f/NTOT);
  float var = bns[128 + c] * (1.f/NTOT) - mu*mu;
  float sc = g[c] / sqrtf(var + 1e-5f);
  scale[c] = sc;
  shift[c] = b[c] - mu*sc;
}

// LAST=0: xmb = bf16(rm * leaky(bn(h)))   LAST=1: xmb = bf16(leaky(bn(h)) + x_in)
template<int LAST>
__global__ void bn_apply(const float* __restrict__ h, const float* __restrict__ scale,
                         const float* __restrict__ shift, const float* __restrict__ rm,
                         const float* __restrict__ x_in, u16* __restrict__ xmb) {
  int i = blockIdx.x*256 + threadIdx.x;
  size_t i4 = (size_t)i*4;
  int c = (int)(i4 & 127);
  float4 v = *reinterpret_cast<const float4*>(h + i4);
  float4 sc = *reinterpret_cast<const float4*>(scale + c);
  float4 sh = *reinterpret_cast<const float4*>(shift + c);
  v.x = fmaf(v.x, sc.x, sh.x); v.y = fmaf(v.y, sc.y, sh.y);
  v.z = fmaf(v.z, sc.z, sh.z); v.w = fmaf(v.w, sc.w, sh.w);
  v.x = v.x >= 0.f ? v.x : 0.01f*v.x;
  v.y = v.y >= 0.f ? v.y : 0.01f*v.y;
  v.z = v.z >= 0.f ? v.z : 0.01f*v.z;
  v.w = v.w >= 0.f ? v.w : 0.01f*v.w;
  float4 xb;
  if (LAST) {
    float4 rsd = *reinterpret_cast<const float4*>(x_in + i4);
    xb.x = v.x + rsd.x; xb.y = v.y + rsd.y; xb.z = v.z + rsd.z; xb.w = v.w + rsd.w;
  } else {
    float s = rm[i >> 5];
    xb.x = v.x*s; xb.y = v.y*s; xb.z = v.z*s; xb.w = v.w*s;
  }
  *reinterpret_cast<uint2*>(xmb + i4) = make_uint2(pack2(xb.x, xb.y), pack2(xb.z, xb.w));
}

extern "C" void kernel_launch(void* const* d_in, const int* in_sizes, int n_in,
                              void* d_out, int out_size, void* d_ws, size_t ws_size,
                              hipStream_t stream) {
  const float* x0       = (const float*)d_in[0];
  const float* x1       = (const float*)d_in[1];
  const float* W0       = (const float*)d_in[2];
  const float* b0       = (const float*)d_in[3];
  const float* W1       = (const float*)d_in[4];
  const float* b1       = (const float*)d_in[5];
  const float* mask     = (const float*)d_in[6];
  const float* conv_root= (const float*)d_in[7];
  const float* conv_rel = (const float*)d_in[8];
  const float* attW     = (const float*)d_in[10];
  const float* att_q    = (const float*)d_in[11];
  const float* att_k    = (const float*)d_in[12];
  const float* bn_g     = (const float*)d_in[14];
  const float* bn_b     = (const float*)d_in[15];
  const float* fc_W     = (const float*)d_in[16];
  const float* fc_b     = (const float*)d_in[17];
  const int* edge_index = (const int*)d_in[18];
  const int* edge_type  = (const int*)d_in[19];
  const int* src = edge_index;
  const int* dst = edge_index + NEDGE;
  (void)in_sizes; (void)n_in; (void)out_size; (void)ws_size;

  char* ws = (char*)d_ws;
  size_t off = 0;
  auto alloc = [&](size_t bytes) { void* p = ws + off; off = (off + bytes + 255) & ~(size_t)255; return p; };
  float* x_in  = (float*)alloc((size_t)NTOT*Hd*4);
  float* hbuf  = (float*)alloc((size_t)NTOT*Hd*4);
  u16*   xmb   = (u16*)  alloc((size_t)NTOT*Hd*2);
  float* sq    = (float*)alloc((size_t)RREL*NTOT*4);
  float* sk    = (float*)alloc((size_t)RREL*NTOT*4);
  float* exs   = (float*)alloc((size_t)NEDGE*4);
  float* den   = (float*)alloc((size_t)NRSEG*4);
  float* invcnt= (float*)alloc((size_t)NRSEG*4);
  float* rm    = (float*)alloc((size_t)NTOT*4);
  int* cnt        = (int*)alloc((size_t)NRSEG*4);
  int* fillctr    = (int*)alloc((size_t)NRSEG*4);
  int* partial    = (int*)alloc((size_t)NRSEG*4);
  int* offsets    = (int*)alloc((size_t)(NRSEG+4)*4);
  int* bsum       = (int*)alloc(4096);
  int* src_sorted = (int*)alloc((size_t)NEDGE*4);
  int* epos       = (int*)alloc((size_t)NEDGE*4);
  float* qvec   = (float*)alloc(512*4);
  float* kvec   = (float*)alloc(512*4);
  float* bns    = (float*)alloc(1024);
  float* bnscale= (float*)alloc(512);
  float* bnshift= (float*)alloc(512);
  u16* Btw  = (u16*)alloc((size_t)128*128*2);
  u16* Btg0 = (u16*)alloc((size_t)128*1152*2);
  u16* Btg1 = (u16*)alloc((size_t)128*1152*2);
  u16* BtgL[2] = {Btg0, Btg1};

  // ---- static CSR over (dst, rel) segments ----
  rowmask_k<<<NTOT/256, 256, 0, stream>>>(mask, rm);
  fill_i32<<<NRSEG/256, 256, 0, stream>>>(cnt, 0, NRSEG);
  edge_count<<<NEDGE/256, 256, 0, stream>>>(dst, edge_type, cnt);
  inv_cnt_k<<<NRSEG/256, 256, 0, stream>>>(cnt, invcnt);
  scan1_k<<<NRSEG/256, 256, 0, stream>>>(cnt, partial, bsum);
  scan2_k<<<1, 256, 0, stream>>>(bsum);
  scan3_k<<<NRSEG/256, 256, 0, stream>>>(partial, bsum, offsets);
  fill_i32<<<NRSEG/256, 256, 0, stream>>>(fillctr, 0, NRSEG);
  csr_fill<<<NEDGE/256, 256, 0, stream>>>(src, dst, edge_type, offsets, fillctr,
                                          src_sorted, epos);

  // ---- per-layer stacked weights: [conv_rel r | attW r | conv_root], bf16 [128][1152] ----
  for (int l = 0; l < 2; ++l) {
    wtrans<<<(512*128)/256, 256, 0, stream>>>(conv_rel + (size_t)l*RREL*Hd*Hd, BtgL[l], 512, 1152, 0);
    wtrans<<<(512*128)/256, 256, 0, stream>>>(attW + (size_t)l*16*Hd*Hd, BtgL[l], 512, 1152, 512);
    wtrans<<<(128*128)/256, 256, 0, stream>>>(conv_root + (size_t)l*Hd*Hd, BtgL[l], 128, 1152, 1024);
  }

  // ---- x_in = [x0@W0+b0 ; x1@W1+b1]  (bf16 MFMA) ----
  cvt_bf16<<<(32768*Hd/4)/256, 256, 0, stream>>>(x0, xmb, 32768*Hd/4);
  cvt_bf16<<<(32768*Hd/4)/256, 256, 0, stream>>>(x1, xmb + (size_t)32768*Hd, 32768*Hd/4);
  wtrans<<<(128*128)/256, 256, 0, stream>>>(W0, Btw, 128, 128, 0);
  mgemm<0><<<256, 256, 0, stream>>>(xmb, Hd, Btw, 128, b0, x_in, 128);
  wtrans<<<(128*128)/256, 256, 0, stream>>>(W1, Btw, 128, 128, 0);
  mgemm<0><<<256, 256, 0, stream>>>(xmb + (size_t)32768*Hd, Hd, Btw, 128, b1,
                                    x_in + (size_t)32768*Hd, 128);
  mkxmb<<<(NTOT*Hd/4)/256, 256, 0, stream>>>(x_in, rm, xmb);

  for (int l = 0; l < 2; ++l) {
    const float* attW_l = attW + (size_t)l*16*Hd*Hd;
    qkvec_k<<<1, 512, 0, stream>>>(attW_l, att_q + (size_t)l*16*Hd, att_k + (size_t)l*16*Hd, qvec, kvec);
    sqk_k<<<NTOT/4, 256, 0, stream>>>(xmb, qvec, kvec, sq, sk);
    layer_init<<<NRSEG/256, 256, 0, stream>>>(den, bns);
    edge_ex<<<NEDGE/256, 256, 0, stream>>>(src, dst, edge_type, sq, sk, epos, exs, den);
    // fused: gather + (conv|att|root) GEMM + BN partial stats (conv_b/att_b cancel in BN)
    fused_gemm<<<NTOT/128, 512, 0, stream>>>(xmb, src_sorted, exs, offsets, invcnt, den,
                                             BtgL[l], hbuf, bns);
    bn_final<<<1, 128, 0, stream>>>(bns, bn_g + (size_t)l*Hd, bn_b + (size_t)l*Hd, bnscale, bnshift);
    if (l == 0)
      bn_apply<0><<<(NTOT*Hd/4)/256, 256, 0, stream>>>(hbuf, bnscale, bnshift, rm, x_in, xmb);
    else
      bn_apply<1><<<(NTOT*Hd/4)/256, 256, 0, stream>>>(hbuf, bnscale, bnshift, rm, x_in, xmb);
  }

  // out = (x + x_in) @ fc_W + fc_b, remapped rows
  wtrans<<<(128*128)/256, 256, 0, stream>>>(fc_W, Btw, 128, 128, 0);
  mgemm<2><<<512, 256, 0, stream>>>(xmb, Hd, Btw, 128, fc_b, (float*)d_out, 128);
}

// Round 6
// 716.130 us; speedup vs baseline: 3.9147x; 1.0304x over previous
//
#include <hip/hip_runtime.h>
#include <cfloat>

#define Hd 128
#define NTOT 65536
#define RREL 4
#define NRSEG (NTOT*RREL)
#define NEDGE 524288

typedef unsigned short u16;
typedef unsigned int u32;
typedef short bf16x8 __attribute__((ext_vector_type(8)));
typedef float f32x4 __attribute__((ext_vector_type(4)));

__device__ __forceinline__ u16 f2bf(float f) {   // RNE
  u32 u = __float_as_uint(f);
  return (u16)((u + 0x7fffu + ((u >> 16) & 1u)) >> 16);
}
__device__ __forceinline__ u32 pack2(float lo, float hi) {
  return ((u32)f2bf(hi) << 16) | f2bf(lo);
}

// swizzled byte offset within a [128 rows][256 B] LDS tile (involution on bits 7:4)
__device__ __forceinline__ int swzb(int row, int o) {
  return (row*256 + o) ^ ((row & 15) << 4);
}

// ======== mgemm: C[M,128] = A[M,K] @ Bt[128,K]^T ========
__device__ __forceinline__ void stage_tile(const u16* __restrict__ g, int ld,
                                           u16* lds, int wave, int lane) {
#pragma unroll
  for (int t = 0; t < 2; ++t) {
    int i = wave*2 + t;
    int row = i*16 + (lane >> 2);
    int col16 = (lane & 3) ^ ((lane >> 3) & 3);
    const u16* src = g + (size_t)row*ld + col16*8;
    __builtin_amdgcn_global_load_lds((const __attribute__((address_space(1))) void*)src,
                                     (__attribute__((address_space(3))) void*)(lds + i*512),
                                     16, 0, 0);
  }
}

// CMODE 0: plain write (+bias); 2: remapped final-output write (+bias)
template<int CMODE>
__global__ __launch_bounds__(256) void mgemm(const u16* __restrict__ A, int lda,
                                             const u16* __restrict__ Bt, int ldb,
                                             const float* __restrict__ bias,
                                             float* __restrict__ C, int kTot)
{
  __shared__ u16 As[4096], Bs[4096];
  const int tid = threadIdx.x, wave = tid >> 6, lane = tid & 63;
  const int wm = wave >> 1, wn = wave & 1;
  const int brow = blockIdx.x * 128;
  const u16* Ab = A + (size_t)brow*lda;
  f32x4 acc[4][4];
#pragma unroll
  for (int i = 0; i < 4; ++i)
#pragma unroll
    for (int j = 0; j < 4; ++j) acc[i][j] = (f32x4){0.f, 0.f, 0.f, 0.f};

  const int ks = (lane >> 4) * 16;
  const int rl = lane & 15;
  for (int k0 = 0; k0 < kTot; k0 += 32) {
    stage_tile(Ab + k0, lda, As, wave, lane);
    stage_tile(Bt + k0, ldb, Bs, wave, lane);
    __syncthreads();
    bf16x8 af[4], bv[4];
    const char* Ac = (const char*)As;
    const char* Bc = (const char*)Bs;
#pragma unroll
    for (int i = 0; i < 4; ++i) {
      int r = wm*64 + i*16 + rl;
      int by = (r*64 + ks) ^ (((r >> 1) & 3) << 4);
      af[i] = *(const bf16x8*)(Ac + by);
    }
#pragma unroll
    for (int j = 0; j < 4; ++j) {
      int r = wn*64 + j*16 + rl;
      int by = (r*64 + ks) ^ (((r >> 1) & 3) << 4);
      bv[j] = *(const bf16x8*)(Bc + by);
    }
#pragma unroll
    for (int i = 0; i < 4; ++i)
#pragma unroll
      for (int j = 0; j < 4; ++j)
        acc[i][j] = __builtin_amdgcn_mfma_f32_16x16x32_bf16(af[i], bv[j], acc[i][j], 0, 0, 0);
    __syncthreads();
  }
  const int cl = lane & 15;
  const int rq = (lane >> 4) * 4;
#pragma unroll
  for (int i = 0; i < 4; ++i) {
#pragma unroll
    for (int q = 0; q < 4; ++q) {
      int row = brow + wm*64 + i*16 + rq + q;
      size_t ob;
      if (CMODE == 2) {
        int b = row >> 6, p = row & 63;
        ob = (p == 0) ? (size_t)b*Hd
                      : (size_t)(1024*Hd) + ((size_t)(b*63 + (p-1)))*Hd;
      } else {
        ob = (size_t)row * Hd;
      }
#pragma unroll
      for (int j = 0; j < 4; ++j) {
        int col = wn*64 + j*16 + cl;
        float v = acc[i][j][q];
        if (bias) v += bias[col];
        C[ob + col] = v;
      }
    }
  }
}

// ======== fused gather + K=1152 GEMM + BN-stats (64 KB LDS, 2 blocks/CU) ========
// Btg: bf16 [128 out][1152], chunks: 0..3 conv_rel r, 4..7 attW r, 8 conv_root
__device__ __forceinline__ void stage128(const u16* __restrict__ gbase, int ld,
                                         u16* lds, int wave, int lane) {
#pragma unroll
  for (int t = 0; t < 4; ++t) {
    int ti = wave*4 + t;
    int row = ti*4 + (lane >> 4);
    int lchunk = (lane & 15) ^ (row & 15);
    const u16* src = gbase + (size_t)row*ld + lchunk*8;
    __builtin_amdgcn_global_load_lds((const __attribute__((address_space(1))) void*)src,
                                     (__attribute__((address_space(3))) void*)(lds + ti*512),
                                     16, 0, 0);
  }
}

__device__ __forceinline__ void mfma128(const u16* Yt, const u16* Bt, f32x4 (&acc)[4][2],
                                        int wm, int wn, int lane) {
  const int rl = lane & 15;
  const int ko = (lane >> 4) * 16;
  const char* Yc_ = (const char*)Yt;
  const char* Bc_ = (const char*)Bt;
#pragma unroll
  for (int ks = 0; ks < 4; ++ks) {
    int o = ks*64 + ko;
    bf16x8 af[4], bv[2];
#pragma unroll
    for (int i = 0; i < 4; ++i)
      af[i] = *(const bf16x8*)(Yc_ + swzb(wm*64 + i*16 + rl, o));
#pragma unroll
    for (int j = 0; j < 2; ++j)
      bv[j] = *(const bf16x8*)(Bc_ + swzb(wn*32 + j*16 + rl, o));
#pragma unroll
    for (int i = 0; i < 4; ++i)
#pragma unroll
      for (int j = 0; j < 2; ++j)
        acc[i][j] = __builtin_amdgcn_mfma_f32_16x16x32_bf16(af[i], bv[j], acc[i][j], 0, 0, 0);
  }
}

__global__ __launch_bounds__(512, 2) void fused_gemm(
    const u16* __restrict__ xmb, const int* __restrict__ src_sorted,
    const float* __restrict__ exs, const int* __restrict__ offsets,
    const float* __restrict__ invcnt, const float* __restrict__ den,
    const u16* __restrict__ Btg, float* __restrict__ hbuf, float* __restrict__ bns)
{
  __shared__ u16 Yt[16384];   // 32 KB: Y tile (conv, then att, then root rows)
  __shared__ u16 Bw[16384];   // 32 KB: weight tile
  const int tid = threadIdx.x, wave = tid >> 6, lane = tid & 63;
  const int wm = wave >> 2, wn = wave & 3;
  const int brow = blockIdx.x * 128;
  f32x4 acc[4][2];
#pragma unroll
  for (int i = 0; i < 4; ++i)
#pragma unroll
    for (int j = 0; j < 2; ++j) acc[i][j] = (f32x4){0.f, 0.f, 0.f, 0.f};

  u32 axp[16];                // att sums, packed bf16 pair (static-indexed)

  for (int r = 0; r < RREL; ++r) {
    __syncthreads();                        // Yt/Bw free (prev att-mfma done)
    stage128(Btg + r*128, 1152, Bw, wave, lane);   // conv weights, in flight during gather
#pragma unroll
    for (int g = 0; g < 4; ++g) {
      int ln0 = wave*16 + g*4;
      int e[4], E[4];
      float cx[4], cy[4], ax[4], ay[4];
#pragma unroll
      for (int m = 0; m < 4; ++m) {
        int seg = (brow + ln0 + m)*RREL + r;
        e[m] = offsets[seg]; E[m] = offsets[seg+1];
        cx[m] = cy[m] = ax[m] = ay[m] = 0.f;
      }
      bool run = (e[0] < E[0]) | (e[1] < E[1]) | (e[2] < E[2]) | (e[3] < E[3]);
      while (run) {
        u32 u[4]; float al[4]; bool a[4];
#pragma unroll
        for (int m = 0; m < 4; ++m) {
          a[m] = e[m] < E[m];
          if (a[m]) {
            int s = src_sorted[e[m]];
            al[m] = exs[e[m]];
            u[m] = *(const u32*)(xmb + (size_t)s*Hd + lane*2);
          }
        }
        run = false;
#pragma unroll
        for (int m = 0; m < 4; ++m) {
          if (a[m]) {
            float vx = __uint_as_float(u[m] << 16);
            float vy = __uint_as_float(u[m] & 0xffff0000u);
            cx[m] += vx; cy[m] += vy;
            ax[m] = fmaf(al[m], vx, ax[m]);
            ay[m] = fmaf(al[m], vy, ay[m]);
            e[m]++;
            run |= (e[m] < E[m]);
          }
        }
      }
#pragma unroll
      for (int m = 0; m < 4; ++m) {
        int ln = ln0 + m;
        int seg = (brow + ln)*RREL + r;
        float ic = invcnt[seg];
        float idn = 1.f / fmaxf(den[seg], 1e-16f);
        *(u32*)((char*)Yt + swzb(ln, lane*4)) = pack2(cx[m]*ic, cy[m]*ic);
        axp[g*4+m] = pack2(ax[m]*idn, ay[m]*idn);
      }
    }
    __syncthreads();                        // Y conv written + B0 staged
    mfma128(Yt, Bw, acc, wm, wn, lane);     // conv contribution
    __syncthreads();                        // conv reads done; Yt/Bw reusable
    stage128(Btg + (4+r)*128, 1152, Bw, wave, lane);   // att weights
#pragma unroll
    for (int g = 0; g < 4; ++g)
#pragma unroll
      for (int m = 0; m < 4; ++m) {
        int ln = wave*16 + g*4 + m;
        *(u32*)((char*)Yt + swzb(ln, lane*4)) = axp[g*4+m];
      }
    __syncthreads();                        // Y att written + B1 staged
    mfma128(Yt, Bw, acc, wm, wn, lane);     // att contribution
  }
  // ---- root chunk: Y = xmb tile ----
  __syncthreads();
  stage128(xmb + (size_t)brow*Hd, Hd, Yt, wave, lane);
  stage128(Btg + 8*128, 1152, Bw, wave, lane);
  __syncthreads();
  mfma128(Yt, Bw, acc, wm, wn, lane);

  // ---- epilogue: write hbuf + BN partial sums ----
  const int cl = lane & 15, rq = (lane >> 4) * 4;
#pragma unroll
  for (int j = 0; j < 2; ++j) {
    float s = 0.f, s2 = 0.f;
#pragma unroll
    for (int i = 0; i < 4; ++i) {
#pragma unroll
      for (int q = 0; q < 4; ++q) {
        float v = acc[i][j][q];
        int row = brow + wm*64 + i*16 + rq + q;
        hbuf[(size_t)row*Hd + wn*32 + j*16 + cl] = v;
        s += v; s2 = fmaf(v, v, s2);
      }
    }
    s  += __shfl_xor(s, 16);  s  += __shfl_xor(s, 32);
    s2 += __shfl_xor(s2, 16); s2 += __shfl_xor(s2, 32);
    if (lane < 16) {
      int col = wn*32 + j*16 + cl;
      unsafeAtomicAdd(&bns[col], s);
      unsafeAtomicAdd(&bns[128 + col], s2);
    }
  }
}

// ---------------- weight transpose+convert: Bt[o][koff+k] = bf16(B[k][o]) ----------------
__global__ void wtrans(const float* __restrict__ B, u16* __restrict__ Bt,
                       int K, int ldb, int koff) {
  int idx = blockIdx.x*256 + threadIdx.x;
  if (idx >= K*128) return;
  int k = idx >> 7, o = idx & 127;
  Bt[(size_t)o*ldb + koff + k] = f2bf(B[idx]);
}

// ---------------- small utility kernels ----------------
__global__ void fill_i32(int* p, int v, int n) {
  int i = blockIdx.x*blockDim.x + threadIdx.x;
  if (i < n) p[i] = v;
}
__global__ void rowmask_k(const float* __restrict__ mask, float* __restrict__ rm) {
  int n = blockIdx.x*blockDim.x + threadIdx.x;
  if (n < NTOT) rm[n] = mask[(size_t)n*Hd];
}
__global__ void edge_count(const int* __restrict__ dst, const int* __restrict__ et, int* __restrict__ cnt) {
  int e = blockIdx.x*blockDim.x + threadIdx.x;
  if (e < NEDGE) atomicAdd(&cnt[dst[e]*RREL + et[e]], 1);
}
__global__ void inv_cnt_k(const int* __restrict__ cnt, float* __restrict__ invc) {
  int i = blockIdx.x*blockDim.x + threadIdx.x;
  if (i < NRSEG) invc[i] = 1.f / (float)max(cnt[i], 1);
}
__global__ void cvt_bf16(const float* __restrict__ src, u16* __restrict__ dst, int n4) {
  int i = blockIdx.x*256 + threadIdx.x;
  if (i >= n4) return;
  float4 v = *reinterpret_cast<const float4*>(src + (size_t)i*4);
  *reinterpret_cast<uint2*>(dst + (size_t)i*4) = make_uint2(pack2(v.x, v.y), pack2(v.z, v.w));
}
__global__ void mkxmb(const float* __restrict__ x, const float* __restrict__ rm,
                      u16* __restrict__ xmb) {
  int i = blockIdx.x*256 + threadIdx.x;
  float s = rm[i >> 5];
  float4 v = *reinterpret_cast<const float4*>(x + (size_t)i*4);
  *reinterpret_cast<uint2*>(xmb + (size_t)i*4) =
      make_uint2(pack2(v.x*s, v.y*s), pack2(v.z*s, v.w*s));
}

// ---------------- CSR build ----------------
__global__ void scan1_k(const int* __restrict__ cnt, int* __restrict__ partial, int* __restrict__ bsum) {
  __shared__ int sh[256];
  int t = threadIdx.x;
  int i = blockIdx.x*256 + t;
  int v = cnt[i];
  sh[t] = v; __syncthreads();
  for (int off = 1; off < 256; off <<= 1) {
    int u = (t >= off) ? sh[t-off] : 0;
    __syncthreads();
    sh[t] += u;
    __syncthreads();
  }
  partial[i] = sh[t] - v;
  if (t == 255) bsum[blockIdx.x] = sh[255];
}
__global__ void scan2_k(int* __restrict__ bsum) {
  __shared__ int sh[256];
  int t = threadIdx.x;
  int v0 = bsum[t*4+0], v1 = bsum[t*4+1], v2 = bsum[t*4+2], v3 = bsum[t*4+3];
  int tot = v0+v1+v2+v3;
  sh[t] = tot; __syncthreads();
  for (int off = 1; off < 256; off <<= 1) {
    int u = (t >= off) ? sh[t-off] : 0;
    __syncthreads();
    sh[t] += u;
    __syncthreads();
  }
  int base = sh[t] - tot;
  bsum[t*4+0] = base;
  bsum[t*4+1] = base + v0;
  bsum[t*4+2] = base + v0+v1;
  bsum[t*4+3] = base + v0+v1+v2;
}
__global__ void scan3_k(const int* __restrict__ partial, const int* __restrict__ bsum, int* __restrict__ offsets) {
  int i = blockIdx.x*256 + threadIdx.x;
  offsets[i] = partial[i] + bsum[i >> 8];
  if (i == 0) offsets[NRSEG] = NEDGE;
}
__global__ void csr_fill(const int* __restrict__ src, const int* __restrict__ dst,
                         const int* __restrict__ et, const int* __restrict__ offsets,
                         int* __restrict__ fillctr,
                         int* __restrict__ src_sorted, int* __restrict__ epos) {
  int e = blockIdx.x*blockDim.x + threadIdx.x;
  if (e >= NEDGE) return;
  int seg = dst[e]*RREL + et[e];
  int pos = offsets[seg] + atomicAdd(&fillctr[seg], 1);
  src_sorted[pos] = src[e];
  epos[e] = pos;
}

// ---------------- attention scalar path ----------------
__global__ void qkvec_k(const float* __restrict__ attW, const float* __restrict__ att_q,
                        const float* __restrict__ att_k,
                        float* __restrict__ qvec, float* __restrict__ kvec) {
  int r = threadIdx.x >> 7, h = threadIdx.x & 127;
  const float* wrow = attW + ((size_t)r*Hd + h)*Hd;
  const float* qv = att_q + (size_t)r*Hd;
  const float* kv = att_k + (size_t)r*Hd;
  float sq_ = 0.f, sk_ = 0.f;
  for (int o = 0; o < Hd; ++o) { float w = wrow[o]; sq_ = fmaf(w, qv[o], sq_); sk_ = fmaf(w, kv[o], sk_); }
  qvec[r*Hd + h] = sq_;
  kvec[r*Hd + h] = sk_;
}

__global__ void sqk_k(const u16* __restrict__ xmb, const float* __restrict__ qvec,
                      const float* __restrict__ kvec, float* __restrict__ sq, float* __restrict__ sk) {
  int w = blockIdx.x*4 + (threadIdx.x >> 6);
  if (w >= NTOT) return;
  int lane = threadIdx.x & 63;
  u32 u = *reinterpret_cast<const u32*>(xmb + (size_t)w*Hd + lane*2);
  float vx = __uint_as_float(u << 16);
  float vy = __uint_as_float(u & 0xffff0000u);
  float pq[RREL], pk[RREL];
#pragma unroll
  for (int r = 0; r < RREL; ++r) {
    float2 q = *reinterpret_cast<const float2*>(qvec + r*Hd + lane*2);
    float2 k = *reinterpret_cast<const float2*>(kvec + r*Hd + lane*2);
    pq[r] = vx*q.x + vy*q.y;
    pk[r] = vx*k.x + vy*k.y;
  }
#pragma unroll
  for (int off = 32; off > 0; off >>= 1) {
#pragma unroll
    for (int r = 0; r < RREL; ++r) {
      pq[r] += __shfl_xor(pq[r], off);
      pk[r] += __shfl_xor(pk[r], off);
    }
  }
  if (lane == 0) {
#pragma unroll
    for (int r = 0; r < RREL; ++r) {
      sq[(size_t)r*NTOT + w] = pq[r];
      sk[(size_t)r*NTOT + w] = pk[r];
    }
  }
}

__global__ void layer_init(float* __restrict__ den, float* __restrict__ bns) {
  int i = blockIdx.x*blockDim.x + threadIdx.x;
  if (i < NRSEG) den[i] = 0.f;
  if (i < 256) bns[i] = 0.f;
}

// one pass: ex = exp(leaky(logit)) (no max-subtract; logits bounded), sorted write + den
__global__ void edge_ex(const int* __restrict__ src, const int* __restrict__ dst,
                        const int* __restrict__ et, const float* __restrict__ sq,
                        const float* __restrict__ sk, const int* __restrict__ epos,
                        float* __restrict__ exs, float* __restrict__ den) {
  int e = blockIdx.x*blockDim.x + threadIdx.x;
  if (e >= NEDGE) return;
  int t = et[e];
  float lg = sq[(size_t)t*NTOT + dst[e]] + sk[(size_t)t*NTOT + src[e]];
  lg = lg >= 0.f ? lg : 0.2f*lg;
  float ex = __expf(lg);
  exs[epos[e]] = ex;
  unsafeAtomicAdd(&den[dst[e]*RREL + t], ex);
}

// ---------------- batchnorm finalize/apply ----------------
__global__ void bn_final(const float* __restrict__ bns, const float* __restrict__ g,
                         const float* __restrict__ b, float* __restrict__ scale,
                         float* __restrict__ shift) {
  int c = threadIdx.x;
  float mu = bns[c] * (1.f/NTOT);
  float var = bns[128 + c] * (1.f/NTOT) - mu*mu;
  float sc = g[c] / sqrtf(var + 1e-5f);
  scale[c] = sc;
  shift[c] = b[c] - mu*sc;
}

// LAST=0: xmb = bf16(rm * leaky(bn(h)))   LAST=1: xmb = bf16(leaky(bn(h)) + x_in)
template<int LAST>
__global__ void bn_apply(const float* __restrict__ h, const float* __restrict__ scale,
                         const float* __restrict__ shift, const float* __restrict__ rm,
                         const float* __restrict__ x_in, u16* __restrict__ xmb) {
  int i = blockIdx.x*256 + threadIdx.x;
  size_t i4 = (size_t)i*4;
  int c = (int)(i4 & 127);
  float4 v = *reinterpret_cast<const float4*>(h + i4);
  float4 sc = *reinterpret_cast<const float4*>(scale + c);
  float4 sh = *reinterpret_cast<const float4*>(shift + c);
  v.x = fmaf(v.x, sc.x, sh.x); v.y = fmaf(v.y, sc.y, sh.y);
  v.z = fmaf(v.z, sc.z, sh.z); v.w = fmaf(v.w, sc.w, sh.w);
  v.x = v.x >= 0.f ? v.x : 0.01f*v.x;
  v.y = v.y >= 0.f ? v.y : 0.01f*v.y;
  v.z = v.z >= 0.f ? v.z : 0.01f*v.z;
  v.w = v.w >= 0.f ? v.w : 0.01f*v.w;
  float4 xb;
  if (LAST) {
    float4 rsd = *reinterpret_cast<const float4*>(x_in + i4);
    xb.x = v.x + rsd.x; xb.y = v.y + rsd.y; xb.z = v.z + rsd.z; xb.w = v.w + rsd.w;
  } else {
    float s = rm[i >> 5];
    xb.x = v.x*s; xb.y = v.y*s; xb.z = v.z*s; xb.w = v.w*s;
  }
  *reinterpret_cast<uint2*>(xmb + i4) = make_uint2(pack2(xb.x, xb.y), pack2(xb.z, xb.w));
}

extern "C" void kernel_launch(void* const* d_in, const int* in_sizes, int n_in,
                              void* d_out, int out_size, void* d_ws, size_t ws_size,
                              hipStream_t stream) {
  const float* x0       = (const float*)d_in[0];
  const float* x1       = (const float*)d_in[1];
  const float* W0       = (const float*)d_in[2];
  const float* b0       = (const float*)d_in[3];
  const float* W1       = (const float*)d_in[4];
  const float* b1       = (const float*)d_in[5];
  const float* mask     = (const float*)d_in[6];
  const float* conv_root= (const float*)d_in[7];
  const float* conv_rel = (const float*)d_in[8];
  const float* attW     = (const float*)d_in[10];
  const float* att_q    = (const float*)d_in[11];
  const float* att_k    = (const float*)d_in[12];
  const float* bn_g     = (const float*)d_in[14];
  const float* bn_b     = (const float*)d_in[15];
  const float* fc_W     = (const float*)d_in[16];
  const float* fc_b     = (const float*)d_in[17];
  const int* edge_index = (const int*)d_in[18];
  const int* edge_type  = (const int*)d_in[19];
  const int* src = edge_index;
  const int* dst = edge_index + NEDGE;
  (void)in_sizes; (void)n_in; (void)out_size; (void)ws_size;

  char* ws = (char*)d_ws;
  size_t off = 0;
  auto alloc = [&](size_t bytes) { void* p = ws + off; off = (off + bytes + 255) & ~(size_t)255; return p; };
  float* x_in  = (float*)alloc((size_t)NTOT*Hd*4);
  float* hbuf  = (float*)alloc((size_t)NTOT*Hd*4);
  u16*   xmb   = (u16*)  alloc((size_t)NTOT*Hd*2);
  float* sq    = (float*)alloc((size_t)RREL*NTOT*4);
  float* sk    = (float*)alloc((size_t)RREL*NTOT*4);
  float* exs   = (float*)alloc((size_t)NEDGE*4);
  float* den   = (float*)alloc((size_t)NRSEG*4);
  float* invcnt= (float*)alloc((size_t)NRSEG*4);
  float* rm    = (float*)alloc((size_t)NTOT*4);
  int* cnt        = (int*)alloc((size_t)NRSEG*4);
  int* fillctr    = (int*)alloc((size_t)NRSEG*4);
  int* partial    = (int*)alloc((size_t)NRSEG*4);
  int* offsets    = (int*)alloc((size_t)(NRSEG+4)*4);
  int* bsum       = (int*)alloc(4096);
  int* src_sorted = (int*)alloc((size_t)NEDGE*4);
  int* epos       = (int*)alloc((size_t)NEDGE*4);
  float* qvec   = (float*)alloc(512*4);
  float* kvec   = (float*)alloc(512*4);
  float* bns    = (float*)alloc(1024);
  float* bnscale= (float*)alloc(512);
  float* bnshift= (float*)alloc(512);
  u16* Btw  = (u16*)alloc((size_t)128*128*2);
  u16* Btg0 = (u16*)alloc((size_t)128*1152*2);
  u16* Btg1 = (u16*)alloc((size_t)128*1152*2);
  u16* BtgL[2] = {Btg0, Btg1};

  // ---- static CSR over (dst, rel) segments ----
  rowmask_k<<<NTOT/256, 256, 0, stream>>>(mask, rm);
  fill_i32<<<NRSEG/256, 256, 0, stream>>>(cnt, 0, NRSEG);
  edge_count<<<NEDGE/256, 256, 0, stream>>>(dst, edge_type, cnt);
  inv_cnt_k<<<NRSEG/256, 256, 0, stream>>>(cnt, invcnt);
  scan1_k<<<NRSEG/256, 256, 0, stream>>>(cnt, partial, bsum);
  scan2_k<<<1, 256, 0, stream>>>(bsum);
  scan3_k<<<NRSEG/256, 256, 0, stream>>>(partial, bsum, offsets);
  fill_i32<<<NRSEG/256, 256, 0, stream>>>(fillctr, 0, NRSEG);
  csr_fill<<<NEDGE/256, 256, 0, stream>>>(src, dst, edge_type, offsets, fillctr,
                                          src_sorted, epos);

  // ---- per-layer stacked weights: [conv_rel r | attW r | conv_root], bf16 [128][1152] ----
  for (int l = 0; l < 2; ++l) {
    wtrans<<<(512*128)/256, 256, 0, stream>>>(conv_rel + (size_t)l*RREL*Hd*Hd, BtgL[l], 512, 1152, 0);
    wtrans<<<(512*128)/256, 256, 0, stream>>>(attW + (size_t)l*16*Hd*Hd, BtgL[l], 512, 1152, 512);
    wtrans<<<(128*128)/256, 256, 0, stream>>>(conv_root + (size_t)l*Hd*Hd, BtgL[l], 128, 1152, 1024);
  }

  // ---- x_in = [x0@W0+b0 ; x1@W1+b1]  (bf16 MFMA) ----
  cvt_bf16<<<(32768*Hd/4)/256, 256, 0, stream>>>(x0, xmb, 32768*Hd/4);
  cvt_bf16<<<(32768*Hd/4)/256, 256, 0, stream>>>(x1, xmb + (size_t)32768*Hd, 32768*Hd/4);
  wtrans<<<(128*128)/256, 256, 0, stream>>>(W0, Btw, 128, 128, 0);
  mgemm<0><<<256, 256, 0, stream>>>(xmb, Hd, Btw, 128, b0, x_in, 128);
  wtrans<<<(128*128)/256, 256, 0, stream>>>(W1, Btw, 128, 128, 0);
  mgemm<0><<<256, 256, 0, stream>>>(xmb + (size_t)32768*Hd, Hd, Btw, 128, b1,
                                    x_in + (size_t)32768*Hd, 128);
  mkxmb<<<(NTOT*Hd/4)/256, 256, 0, stream>>>(x_in, rm, xmb);

  for (int l = 0; l < 2; ++l) {
    const float* attW_l = attW + (size_t)l*16*Hd*Hd;
    qkvec_k<<<1, 512, 0, stream>>>(attW_l, att_q + (size_t)l*16*Hd, att_k + (size_t)l*16*Hd, qvec, kvec);
    sqk_k<<<NTOT/4, 256, 0, stream>>>(xmb, qvec, kvec, sq, sk);
    layer_init<<<NRSEG/256, 256, 0, stream>>>(den, bns);
    edge_ex<<<NEDGE/256, 256, 0, stream>>>(src, dst, edge_type, sq, sk, epos, exs, den);
    // fused: gather + (conv|att|root) GEMM + BN partial stats (conv_b/att_b cancel in BN)
    fused_gemm<<<NTOT/128, 512, 0, stream>>>(xmb, src_sorted, exs, offsets, invcnt, den,
                                             BtgL[l], hbuf, bns);
    bn_final<<<1, 128, 0, stream>>>(bns, bn_g + (size_t)l*Hd, bn_b + (size_t)l*Hd, bnscale, bnshift);
    if (l == 0)
      bn_apply<0><<<(NTOT*Hd/4)/256, 256, 0, stream>>>(hbuf, bnscale, bnshift, rm, x_in, xmb);
    else
      bn_apply<1><<<(NTOT*Hd/4)/256, 256, 0, stream>>>(hbuf, bnscale, bnshift, rm, x_in, xmb);
  }

  // out = (x + x_in) @ fc_W + fc_b, remapped rows
  wtrans<<<(128*128)/256, 256, 0, stream>>>(fc_W, Btw, 128, 128, 0);
  mgemm<2><<<512, 256, 0, stream>>>(xmb, Hd, Btw, 128, fc_b, (float*)d_out, 128);
}

// Round 7
// 604.626 us; speedup vs baseline: 4.6367x; 1.1844x over previous
//
#include <hip/hip_runtime.h>
#include <cfloat>

#define Hd 128
#define NTOT 65536
#define RREL 4
#define NRSEG (NTOT*RREL)
#define NEDGE 524288

typedef unsigned short u16;
typedef unsigned int u32;
typedef short bf16x8 __attribute__((ext_vector_type(8)));
typedef float f32x4 __attribute__((ext_vector_type(4)));

__device__ __forceinline__ u16 f2bf(float f) {   // RNE
  u32 u = __float_as_uint(f);
  return (u16)((u + 0x7fffu + ((u >> 16) & 1u)) >> 16);
}
__device__ __forceinline__ u32 pack2(float lo, float hi) {
  return ((u32)f2bf(hi) << 16) | f2bf(lo);
}

// swizzled byte offset within a [128 rows][256 B] LDS tile (involution on bits 7:4)
__device__ __forceinline__ int swzb(int row, int o) {
  return (row*256 + o) ^ ((row & 15) << 4);
}

// ======== mgemm: C[M,128] = A[M,K] @ Bt[128,K]^T ========
__device__ __forceinline__ void stage_tile(const u16* __restrict__ g, int ld,
                                           u16* lds, int wave, int lane) {
#pragma unroll
  for (int t = 0; t < 2; ++t) {
    int i = wave*2 + t;
    int row = i*16 + (lane >> 2);
    int col16 = (lane & 3) ^ ((lane >> 3) & 3);
    const u16* src = g + (size_t)row*ld + col16*8;
    __builtin_amdgcn_global_load_lds((const __attribute__((address_space(1))) void*)src,
                                     (__attribute__((address_space(3))) void*)(lds + i*512),
                                     16, 0, 0);
  }
}

// CMODE 0: plain write (+bias); 2: remapped final-output write (+bias);
// CMODE 3: dual half-M (blocks >= gridDim/2 use A+32768 rows, Bt+128*128, bias2, C+32768 rows)
template<int CMODE>
__global__ __launch_bounds__(256) void mgemm(const u16* __restrict__ A, int lda,
                                             const u16* __restrict__ Bt, int ldb,
                                             const float* __restrict__ bias,
                                             const float* __restrict__ bias2,
                                             float* __restrict__ C, int kTot)
{
  __shared__ u16 As[4096], Bs[4096];
  const int tid = threadIdx.x, wave = tid >> 6, lane = tid & 63;
  const int wm = wave >> 1, wn = wave & 1;
  int bx = blockIdx.x;
  if (CMODE == 3) {
    if (bx >= (int)gridDim.x/2) {
      bx -= gridDim.x/2;
      A += (size_t)32768*lda; Bt += 128*128; bias = bias2; C += (size_t)32768*Hd;
    }
  }
  const int brow = bx * 128;
  const u16* Ab = A + (size_t)brow*lda;
  f32x4 acc[4][4];
#pragma unroll
  for (int i = 0; i < 4; ++i)
#pragma unroll
    for (int j = 0; j < 4; ++j) acc[i][j] = (f32x4){0.f, 0.f, 0.f, 0.f};

  const int ks = (lane >> 4) * 16;
  const int rl = lane & 15;
  for (int k0 = 0; k0 < kTot; k0 += 32) {
    stage_tile(Ab + k0, lda, As, wave, lane);
    stage_tile(Bt + k0, ldb, Bs, wave, lane);
    __syncthreads();
    bf16x8 af[4], bv[4];
    const char* Ac = (const char*)As;
    const char* Bc = (const char*)Bs;
#pragma unroll
    for (int i = 0; i < 4; ++i) {
      int r = wm*64 + i*16 + rl;
      int by = (r*64 + ks) ^ (((r >> 1) & 3) << 4);
      af[i] = *(const bf16x8*)(Ac + by);
    }
#pragma unroll
    for (int j = 0; j < 4; ++j) {
      int r = wn*64 + j*16 + rl;
      int by = (r*64 + ks) ^ (((r >> 1) & 3) << 4);
      bv[j] = *(const bf16x8*)(Bc + by);
    }
#pragma unroll
    for (int i = 0; i < 4; ++i)
#pragma unroll
      for (int j = 0; j < 4; ++j)
        acc[i][j] = __builtin_amdgcn_mfma_f32_16x16x32_bf16(af[i], bv[j], acc[i][j], 0, 0, 0);
    __syncthreads();
  }
  const int cl = lane & 15;
  const int rq = (lane >> 4) * 4;
#pragma unroll
  for (int i = 0; i < 4; ++i) {
#pragma unroll
    for (int q = 0; q < 4; ++q) {
      int row = brow + wm*64 + i*16 + rq + q;
      size_t ob;
      if (CMODE == 2) {
        int b = row >> 6, p = row & 63;
        ob = (p == 0) ? (size_t)b*Hd
                      : (size_t)(1024*Hd) + ((size_t)(b*63 + (p-1)))*Hd;
      } else {
        ob = (size_t)row * Hd;
      }
#pragma unroll
      for (int j = 0; j < 4; ++j) {
        int col = wn*64 + j*16 + cl;
        float v = acc[i][j][q];
        if (bias) v += bias[col];
        C[ob + col] = v;
      }
    }
  }
}

// ======== fused gather + K=1152 GEMM + BN-stats ========
// Btg: bf16 [128 out][1152], chunks: 0..3 conv_rel r, 4..7 attW r, 8 conv_root
__device__ __forceinline__ void stage128(const u16* __restrict__ gbase, int ld,
                                         u16* lds, int wave, int lane) {
#pragma unroll
  for (int t = 0; t < 4; ++t) {
    int ti = wave*4 + t;
    int row = ti*4 + (lane >> 4);
    int lchunk = (lane & 15) ^ (row & 15);
    const u16* src = gbase + (size_t)row*ld + lchunk*8;
    __builtin_amdgcn_global_load_lds((const __attribute__((address_space(1))) void*)src,
                                     (__attribute__((address_space(3))) void*)(lds + ti*512),
                                     16, 0, 0);
  }
}

__device__ __forceinline__ void mfma128(const u16* Yt, const u16* Bt, f32x4 (&acc)[4][2],
                                        int wm, int wn, int lane) {
  const int rl = lane & 15;
  const int ko = (lane >> 4) * 16;
  const char* Yc_ = (const char*)Yt;
  const char* Bc_ = (const char*)Bt;
#pragma unroll
  for (int ks = 0; ks < 4; ++ks) {
    int o = ks*64 + ko;
    bf16x8 af[4], bv[2];
#pragma unroll
    for (int i = 0; i < 4; ++i)
      af[i] = *(const bf16x8*)(Yc_ + swzb(wm*64 + i*16 + rl, o));
#pragma unroll
    for (int j = 0; j < 2; ++j)
      bv[j] = *(const bf16x8*)(Bc_ + swzb(wn*32 + j*16 + rl, o));
#pragma unroll
    for (int i = 0; i < 4; ++i)
#pragma unroll
      for (int j = 0; j < 2; ++j)
        acc[i][j] = __builtin_amdgcn_mfma_f32_16x16x32_bf16(af[i], bv[j], acc[i][j], 0, 0, 0);
  }
}

__global__ __launch_bounds__(512) void fused_gemm(
    const u16* __restrict__ xmb, const int* __restrict__ src_sorted,
    const float* __restrict__ exs, const int* __restrict__ offsets,
    const float* __restrict__ invcnt, const float* __restrict__ den,
    const u16* __restrict__ Btg, float* __restrict__ hbuf, float* __restrict__ bns)
{
  __shared__ u16 Yt[16384];   // 32 KB: Y tile (conv, then att, then root rows)
  __shared__ u16 Bw[16384];   // 32 KB: weight tile
  const int tid = threadIdx.x, wave = tid >> 6, lane = tid & 63;
  const int wm = wave >> 2, wn = wave & 3;
  const int brow = blockIdx.x * 128;
  f32x4 acc[4][2];
#pragma unroll
  for (int i = 0; i < 4; ++i)
#pragma unroll
    for (int j = 0; j < 2; ++j) acc[i][j] = (f32x4){0.f, 0.f, 0.f, 0.f};

  u32 axp[16];                // att sums, packed bf16 pair (static-indexed)

  for (int r = 0; r < RREL; ++r) {
    __syncthreads();                        // Yt/Bw free (prev att-mfma done)
    stage128(Btg + r*128, 1152, Bw, wave, lane);   // conv weights, in flight during gather
#pragma unroll
    for (int g = 0; g < 4; ++g) {
      int ln0 = wave*16 + g*4;
      int e0[4], ct[4];
#pragma unroll
      for (int m = 0; m < 4; ++m) {
        int seg = (brow + ln0 + m)*RREL + r;
        e0[m] = offsets[seg];
        ct[m] = offsets[seg+1] - e0[m];
      }
      // head: indices + alphas for up to 4 edges per chain, all issued in parallel
      int   si[4][4];
      float ew[4][4];
#pragma unroll
      for (int m = 0; m < 4; ++m)
#pragma unroll
        for (int k = 0; k < 4; ++k) {
          si[m][k] = src_sorted[e0[m] + k];   // padded buffer; discarded if k>=ct
          ew[m][k] = exs[e0[m] + k];
        }
      float cx[4], cy[4], ax[4], ay[4];
#pragma unroll
      for (int m = 0; m < 4; ++m) { cx[m] = cy[m] = ax[m] = ay[m] = 0.f; }
#pragma unroll
      for (int m = 0; m < 4; ++m) {
#pragma unroll
        for (int k = 0; k < 4; ++k) {
          int sx = (k < ct[m]) ? si[m][k] : 0;      // clamp to L1-hot row
          u32 u = *(const u32*)(xmb + (size_t)sx*Hd + lane*2);
          float pr = (k < ct[m]) ? 1.f : 0.f;
          float al = pr * ew[m][k];
          float vx = __uint_as_float(u << 16);
          float vy = __uint_as_float(u & 0xffff0000u);
          cx[m] = fmaf(pr, vx, cx[m]);
          cy[m] = fmaf(pr, vy, cy[m]);
          ax[m] = fmaf(al, vx, ax[m]);
          ay[m] = fmaf(al, vy, ay[m]);
        }
        // rare tail (cnt > 4): sequential
        for (int e = e0[m] + 4; e < e0[m] + ct[m]; ++e) {
          int s = src_sorted[e];
          float al = exs[e];
          u32 u = *(const u32*)(xmb + (size_t)s*Hd + lane*2);
          float vx = __uint_as_float(u << 16);
          float vy = __uint_as_float(u & 0xffff0000u);
          cx[m] += vx; cy[m] += vy;
          ax[m] = fmaf(al, vx, ax[m]);
          ay[m] = fmaf(al, vy, ay[m]);
        }
      }
#pragma unroll
      for (int m = 0; m < 4; ++m) {
        int ln = ln0 + m;
        int seg = (brow + ln)*RREL + r;
        float ic = invcnt[seg];
        float idn = 1.f / fmaxf(den[seg], 1e-16f);
        *(u32*)((char*)Yt + swzb(ln, lane*4)) = pack2(cx[m]*ic, cy[m]*ic);
        axp[g*4+m] = pack2(ax[m]*idn, ay[m]*idn);
      }
    }
    __syncthreads();                        // Y conv written + B0 staged
    mfma128(Yt, Bw, acc, wm, wn, lane);     // conv contribution
    __syncthreads();                        // conv reads done; Yt/Bw reusable
    stage128(Btg + (4+r)*128, 1152, Bw, wave, lane);   // att weights
#pragma unroll
    for (int g = 0; g < 4; ++g)
#pragma unroll
      for (int m = 0; m < 4; ++m) {
        int ln = wave*16 + g*4 + m;
        *(u32*)((char*)Yt + swzb(ln, lane*4)) = axp[g*4+m];
      }
    __syncthreads();                        // Y att written + B1 staged
    mfma128(Yt, Bw, acc, wm, wn, lane);     // att contribution
  }
  // ---- root chunk: Y = xmb tile ----
  __syncthreads();
  stage128(xmb + (size_t)brow*Hd, Hd, Yt, wave, lane);
  stage128(Btg + 8*128, 1152, Bw, wave, lane);
  __syncthreads();
  mfma128(Yt, Bw, acc, wm, wn, lane);

  // ---- epilogue: write hbuf + BN partial sums ----
  const int cl = lane & 15, rq = (lane >> 4) * 4;
#pragma unroll
  for (int j = 0; j < 2; ++j) {
    float s = 0.f, s2 = 0.f;
#pragma unroll
    for (int i = 0; i < 4; ++i) {
#pragma unroll
      for (int q = 0; q < 4; ++q) {
        float v = acc[i][j][q];
        int row = brow + wm*64 + i*16 + rq + q;
        hbuf[(size_t)row*Hd + wn*32 + j*16 + cl] = v;
        s += v; s2 = fmaf(v, v, s2);
      }
    }
    s  += __shfl_xor(s, 16);  s  += __shfl_xor(s, 32);
    s2 += __shfl_xor(s2, 16); s2 += __shfl_xor(s2, 32);
    if (lane < 16) {
      int col = wn*32 + j*16 + cl;
      unsafeAtomicAdd(&bns[col], s);
      unsafeAtomicAdd(&bns[128 + col], s2);
    }
  }
}

// ---------------- weight transpose+convert: Bt[o][koff+k] = bf16(B[k][o]) ----------------
__global__ void wtrans(const float* __restrict__ B, u16* __restrict__ Bt,
                       int K, int ldb, int koff) {
  int idx = blockIdx.x*256 + threadIdx.x;
  if (idx >= K*128) return;
  int k = idx >> 7, o = idx & 127;
  Bt[(size_t)o*ldb + koff + k] = f2bf(B[idx]);
}

// ---------------- small utility kernels ----------------
__global__ void fill_i32(int* p, int v, int n) {
  int i = blockIdx.x*blockDim.x + threadIdx.x;
  if (i < n) p[i] = v;
}
__global__ void rowmask_k(const float* __restrict__ mask, float* __restrict__ rm) {
  int n = blockIdx.x*blockDim.x + threadIdx.x;
  if (n < NTOT) rm[n] = mask[(size_t)n*Hd];
}
__global__ void edge_count(const int* __restrict__ dst, const int* __restrict__ et, int* __restrict__ cnt) {
  int e = blockIdx.x*blockDim.x + threadIdx.x;
  if (e < NEDGE) atomicAdd(&cnt[dst[e]*RREL + et[e]], 1);
}
__global__ void inv_cnt_k(const int* __restrict__ cnt, float* __restrict__ invc) {
  int i = blockIdx.x*blockDim.x + threadIdx.x;
  if (i < NRSEG) invc[i] = 1.f / (float)max(cnt[i], 1);
}
// both node types in one dispatch
__global__ void cvt_bf16_2(const float* __restrict__ s0, const float* __restrict__ s1,
                           u16* __restrict__ dst) {
  int i = blockIdx.x*256 + threadIdx.x;
  const int half = 32768*Hd/4;
  const float* s = (i < half) ? s0 : s1;
  int ii = (i < half) ? i : i - half;
  float4 v = *reinterpret_cast<const float4*>(s + (size_t)ii*4);
  *reinterpret_cast<uint2*>(dst + (size_t)i*4) = make_uint2(pack2(v.x, v.y), pack2(v.z, v.w));
}
__global__ void mkxmb(const float* __restrict__ x, const float* __restrict__ rm,
                      u16* __restrict__ xmb) {
  int i = blockIdx.x*256 + threadIdx.x;
  float s = rm[i >> 5];
  float4 v = *reinterpret_cast<const float4*>(x + (size_t)i*4);
  *reinterpret_cast<uint2*>(xmb + (size_t)i*4) =
      make_uint2(pack2(v.x*s, v.y*s), pack2(v.z*s, v.w*s));
}

// ---------------- CSR build ----------------
__global__ void scan1_k(const int* __restrict__ cnt, int* __restrict__ partial, int* __restrict__ bsum) {
  __shared__ int sh[256];
  int t = threadIdx.x;
  int i = blockIdx.x*256 + t;
  int v = cnt[i];
  sh[t] = v; __syncthreads();
  for (int off = 1; off < 256; off <<= 1) {
    int u = (t >= off) ? sh[t-off] : 0;
    __syncthreads();
    sh[t] += u;
    __syncthreads();
  }
  partial[i] = sh[t] - v;
  if (t == 255) bsum[blockIdx.x] = sh[255];
}
__global__ void scan2_k(int* __restrict__ bsum) {
  __shared__ int sh[256];
  int t = threadIdx.x;
  int v0 = bsum[t*4+0], v1 = bsum[t*4+1], v2 = bsum[t*4+2], v3 = bsum[t*4+3];
  int tot = v0+v1+v2+v3;
  sh[t] = tot; __syncthreads();
  for (int off = 1; off < 256; off <<= 1) {
    int u = (t >= off) ? sh[t-off] : 0;
    __syncthreads();
    sh[t] += u;
    __syncthreads();
  }
  int base = sh[t] - tot;
  bsum[t*4+0] = base;
  bsum[t*4+1] = base + v0;
  bsum[t*4+2] = base + v0+v1;
  bsum[t*4+3] = base + v0+v1+v2;
}
__global__ void scan3_k(const int* __restrict__ partial, const int* __restrict__ bsum, int* __restrict__ offsets) {
  int i = blockIdx.x*256 + threadIdx.x;
  offsets[i] = partial[i] + bsum[i >> 8];
  if (i == 0) offsets[NRSEG] = NEDGE;
}
__global__ void csr_fill(const int* __restrict__ src, const int* __restrict__ dst,
                         const int* __restrict__ et, const int* __restrict__ offsets,
                         int* __restrict__ fillctr,
                         int* __restrict__ src_sorted, int* __restrict__ epos) {
  int e = blockIdx.x*blockDim.x + threadIdx.x;
  if (e >= NEDGE) return;
  int seg = dst[e]*RREL + et[e];
  int pos = offsets[seg] + atomicAdd(&fillctr[seg], 1);
  src_sorted[pos] = src[e];
  epos[e] = pos;
}

// ---------------- attention scalar path ----------------
__global__ void qkvec_k(const float* __restrict__ attW, const float* __restrict__ att_q,
                        const float* __restrict__ att_k,
                        float* __restrict__ qvec, float* __restrict__ kvec) {
  int r = threadIdx.x >> 7, h = threadIdx.x & 127;
  const float* wrow = attW + ((size_t)r*Hd + h)*Hd;
  const float* qv = att_q + (size_t)r*Hd;
  const float* kv = att_k + (size_t)r*Hd;
  float sq_ = 0.f, sk_ = 0.f;
  for (int o = 0; o < Hd; ++o) { float w = wrow[o]; sq_ = fmaf(w, qv[o], sq_); sk_ = fmaf(w, kv[o], sk_); }
  qvec[r*Hd + h] = sq_;
  kvec[r*Hd + h] = sk_;
}

__global__ void sqk_k(const u16* __restrict__ xmb, const float* __restrict__ qvec,
                      const float* __restrict__ kvec, float* __restrict__ sq, float* __restrict__ sk) {
  int w = blockIdx.x*4 + (threadIdx.x >> 6);
  if (w >= NTOT) return;
  int lane = threadIdx.x & 63;
  u32 u = *reinterpret_cast<const u32*>(xmb + (size_t)w*Hd + lane*2);
  float vx = __uint_as_float(u << 16);
  float vy = __uint_as_float(u & 0xffff0000u);
  float pq[RREL], pk[RREL];
#pragma unroll
  for (int r = 0; r < RREL; ++r) {
    float2 q = *reinterpret_cast<const float2*>(qvec + r*Hd + lane*2);
    float2 k = *reinterpret_cast<const float2*>(kvec + r*Hd + lane*2);
    pq[r] = vx*q.x + vy*q.y;
    pk[r] = vx*k.x + vy*k.y;
  }
#pragma unroll
  for (int off = 32; off > 0; off >>= 1) {
#pragma unroll
    for (int r = 0; r < RREL; ++r) {
      pq[r] += __shfl_xor(pq[r], off);
      pk[r] += __shfl_xor(pk[r], off);
    }
  }
  if (lane == 0) {
#pragma unroll
    for (int r = 0; r < RREL; ++r) {
      sq[(size_t)r*NTOT + w] = pq[r];
      sk[(size_t)r*NTOT + w] = pk[r];
    }
  }
}

__global__ void layer_init(float* __restrict__ den, float* __restrict__ bns) {
  int i = blockIdx.x*blockDim.x + threadIdx.x;
  if (i < NRSEG) den[i] = 0.f;
  if (i < 256) bns[i] = 0.f;
}

// one pass: ex = exp(leaky(logit)) (no max-subtract; logits bounded), sorted write + den
__global__ void edge_ex(const int* __restrict__ src, const int* __restrict__ dst,
                        const int* __restrict__ et, const float* __restrict__ sq,
                        const float* __restrict__ sk, const int* __restrict__ epos,
                        float* __restrict__ exs, float* __restrict__ den) {
  int e = blockIdx.x*blockDim.x + threadIdx.x;
  if (e >= NEDGE) return;
  int t = et[e];
  float lg = sq[(size_t)t*NTOT + dst[e]] + sk[(size_t)t*NTOT + src[e]];
  lg = lg >= 0.f ? lg : 0.2f*lg;
  float ex = __expf(lg);
  exs[epos[e]] = ex;
  unsafeAtomicAdd(&den[dst[e]*RREL + t], ex);
}

// ---------------- batchnorm finalize/apply ----------------
__global__ void bn_final(const float* __restrict__ bns, const float* __restrict__ g,
                         const float* __restrict__ b, float* __restrict__ scale,
                         float* __restrict__ shift) {
  int c = threadIdx.x;
  float mu = bns[c] * (1.f/NTOT);
  float var = bns[128 + c] * (1.f/NTOT) - mu*mu;
  float sc = g[c] / sqrtf(var + 1e-5f);
  scale[c] = sc;
  shift[c] = b[c] - mu*sc;
}

// LAST=0: xmb = bf16(rm * leaky(bn(h)))   LAST=1: xmb = bf16(leaky(bn(h)) + x_in)
template<int LAST>
__global__ void bn_apply(const float* __restrict__ h, const float* __restrict__ scale,
                         const float* __restrict__ shift, const float* __restrict__ rm,
                         const float* __restrict__ x_in, u16* __restrict__ xmb) {
  int i = blockIdx.x*256 + threadIdx.x;
  size_t i4 = (size_t)i*4;
  int c = (int)(i4 & 127);
  float4 v = *reinterpret_cast<const float4*>(h + i4);
  float4 sc = *reinterpret_cast<const float4*>(scale + c);
  float4 sh = *reinterpret_cast<const float4*>(shift + c);
  v.x = fmaf(v.x, sc.x, sh.x); v.y = fmaf(v.y, sc.y, sh.y);
  v.z = fmaf(v.z, sc.z, sh.z); v.w = fmaf(v.w, sc.w, sh.w);
  v.x = v.x >= 0.f ? v.x : 0.01f*v.x;
  v.y = v.y >= 0.f ? v.y : 0.01f*v.y;
  v.z = v.z >= 0.f ? v.z : 0.01f*v.z;
  v.w = v.w >= 0.f ? v.w : 0.01f*v.w;
  float4 xb;
  if (LAST) {
    float4 rsd = *reinterpret_cast<const float4*>(x_in + i4);
    xb.x = v.x + rsd.x; xb.y = v.y + rsd.y; xb.z = v.z + rsd.z; xb.w = v.w + rsd.w;
  } else {
    float s = rm[i >> 5];
    xb.x = v.x*s; xb.y = v.y*s; xb.z = v.z*s; xb.w = v.w*s;
  }
  *reinterpret_cast<uint2*>(xmb + i4) = make_uint2(pack2(xb.x, xb.y), pack2(xb.z, xb.w));
}

extern "C" void kernel_launch(void* const* d_in, const int* in_sizes, int n_in,
                              void* d_out, int out_size, void* d_ws, size_t ws_size,
                              hipStream_t stream) {
  const float* x0       = (const float*)d_in[0];
  const float* x1       = (const float*)d_in[1];
  const float* W0       = (const float*)d_in[2];
  const float* b0       = (const float*)d_in[3];
  const float* W1       = (const float*)d_in[4];
  const float* b1       = (const float*)d_in[5];
  const float* mask     = (const float*)d_in[6];
  const float* conv_root= (const float*)d_in[7];
  const float* conv_rel = (const float*)d_in[8];
  const float* attW     = (const float*)d_in[10];
  const float* att_q    = (const float*)d_in[11];
  const float* att_k    = (const float*)d_in[12];
  const float* bn_g     = (const float*)d_in[14];
  const float* bn_b     = (const float*)d_in[15];
  const float* fc_W     = (const float*)d_in[16];
  const float* fc_b     = (const float*)d_in[17];
  const int* edge_index = (const int*)d_in[18];
  const int* edge_type  = (const int*)d_in[19];
  const int* src = edge_index;
  const int* dst = edge_index + NEDGE;
  (void)in_sizes; (void)n_in; (void)out_size; (void)ws_size;

  char* ws = (char*)d_ws;
  size_t off = 0;
  auto alloc = [&](size_t bytes) { void* p = ws + off; off = (off + bytes + 255) & ~(size_t)255; return p; };
  float* x_in  = (float*)alloc((size_t)NTOT*Hd*4);
  float* hbuf  = (float*)alloc((size_t)NTOT*Hd*4);
  u16*   xmb   = (u16*)  alloc((size_t)NTOT*Hd*2);
  float* sq    = (float*)alloc((size_t)RREL*NTOT*4);
  float* sk    = (float*)alloc((size_t)RREL*NTOT*4);
  float* exs   = (float*)alloc((size_t)(NEDGE+16)*4);   // +16 pad for head over-read
  float* den   = (float*)alloc((size_t)NRSEG*4);
  float* invcnt= (float*)alloc((size_t)NRSEG*4);
  float* rm    = (float*)alloc((size_t)NTOT*4);
  int* cnt        = (int*)alloc((size_t)NRSEG*4);
  int* fillctr    = (int*)alloc((size_t)NRSEG*4);
  int* partial    = (int*)alloc((size_t)NRSEG*4);
  int* offsets    = (int*)alloc((size_t)(NRSEG+4)*4);
  int* bsum       = (int*)alloc(4096);
  int* src_sorted = (int*)alloc((size_t)(NEDGE+16)*4);  // +16 pad
  int* epos       = (int*)alloc((size_t)NEDGE*4);
  float* qvec   = (float*)alloc(512*4);
  float* kvec   = (float*)alloc(512*4);
  float* bns    = (float*)alloc(1024);
  float* bnscale= (float*)alloc(512);
  float* bnshift= (float*)alloc(512);
  u16* Btw  = (u16*)alloc((size_t)2*128*128*2);   // W0^T | W1^T (then reused for fc)
  u16* Btg0 = (u16*)alloc((size_t)128*1152*2);
  u16* Btg1 = (u16*)alloc((size_t)128*1152*2);
  u16* BtgL[2] = {Btg0, Btg1};

  // ---- static CSR over (dst, rel) segments ----
  rowmask_k<<<NTOT/256, 256, 0, stream>>>(mask, rm);
  fill_i32<<<NRSEG/256, 256, 0, stream>>>(cnt, 0, NRSEG);
  edge_count<<<NEDGE/256, 256, 0, stream>>>(dst, edge_type, cnt);
  inv_cnt_k<<<NRSEG/256, 256, 0, stream>>>(cnt, invcnt);
  scan1_k<<<NRSEG/256, 256, 0, stream>>>(cnt, partial, bsum);
  scan2_k<<<1, 256, 0, stream>>>(bsum);
  scan3_k<<<NRSEG/256, 256, 0, stream>>>(partial, bsum, offsets);
  fill_i32<<<NRSEG/256, 256, 0, stream>>>(fillctr, 0, NRSEG);
  csr_fill<<<NEDGE/256, 256, 0, stream>>>(src, dst, edge_type, offsets, fillctr,
                                          src_sorted, epos);

  // ---- per-layer stacked weights: [conv_rel r | attW r | conv_root], bf16 [128][1152] ----
  for (int l = 0; l < 2; ++l) {
    wtrans<<<(512*128)/256, 256, 0, stream>>>(conv_rel + (size_t)l*RREL*Hd*Hd, BtgL[l], 512, 1152, 0);
    wtrans<<<(512*128)/256, 256, 0, stream>>>(attW + (size_t)l*16*Hd*Hd, BtgL[l], 512, 1152, 512);
    wtrans<<<(128*128)/256, 256, 0, stream>>>(conv_root + (size_t)l*Hd*Hd, BtgL[l], 128, 1152, 1024);
  }

  // ---- x_in = [x0@W0+b0 ; x1@W1+b1]  (bf16 MFMA, single dual dispatch) ----
  cvt_bf16_2<<<(NTOT*Hd/4)/256, 256, 0, stream>>>(x0, x1, xmb);
  wtrans<<<(128*128)/256, 256, 0, stream>>>(W0, Btw, 128, 128, 0);
  wtrans<<<(128*128)/256, 256, 0, stream>>>(W1, Btw + 128*128, 128, 128, 0);
  mgemm<3><<<512, 256, 0, stream>>>(xmb, Hd, Btw, 128, b0, b1, x_in, 128);
  mkxmb<<<(NTOT*Hd/4)/256, 256, 0, stream>>>(x_in, rm, xmb);

  for (int l = 0; l < 2; ++l) {
    const float* attW_l = attW + (size_t)l*16*Hd*Hd;
    qkvec_k<<<1, 512, 0, stream>>>(attW_l, att_q + (size_t)l*16*Hd, att_k + (size_t)l*16*Hd, qvec, kvec);
    sqk_k<<<NTOT/4, 256, 0, stream>>>(xmb, qvec, kvec, sq, sk);
    layer_init<<<NRSEG/256, 256, 0, stream>>>(den, bns);
    edge_ex<<<NEDGE/256, 256, 0, stream>>>(src, dst, edge_type, sq, sk, epos, exs, den);
    // fused: gather + (conv|att|root) GEMM + BN partial stats (conv_b/att_b cancel in BN)
    fused_gemm<<<NTOT/128, 512, 0, stream>>>(xmb, src_sorted, exs, offsets, invcnt, den,
                                             BtgL[l], hbuf, bns);
    bn_final<<<1, 128, 0, stream>>>(bns, bn_g + (size_t)l*Hd, bn_b + (size_t)l*Hd, bnscale, bnshift);
    if (l == 0)
      bn_apply<0><<<(NTOT*Hd/4)/256, 256, 0, stream>>>(hbuf, bnscale, bnshift, rm, x_in, xmb);
    else
      bn_apply<1><<<(NTOT*Hd/4)/256, 256, 0, stream>>>(hbuf, bnscale, bnshift, rm, x_in, xmb);
  }

  // out = (x + x_in) @ fc_W + fc_b, remapped rows
  wtrans<<<(128*128)/256, 256, 0, stream>>>(fc_W, Btw, 128, 128, 0);
  mgemm<2><<<512, 256, 0, stream>>>(xmb, Hd, Btw, 128, fc_b, nullptr, (float*)d_out, 128);
}

// Round 8
// 482.276 us; speedup vs baseline: 5.8130x; 1.2537x over previous
//
#include <hip/hip_runtime.h>

#define Hd 128
#define NTOT 65536
#define RREL 4
#define NRSEG (NTOT*RREL)
#define NEDGE 524288

typedef unsigned short u16;
typedef unsigned int u32;
typedef short bf16x8 __attribute__((ext_vector_type(8)));
typedef float f32x4 __attribute__((ext_vector_type(4)));

__device__ __forceinline__ u16 f2bf(float f) {   // RNE
  u32 u = __float_as_uint(f);
  return (u16)((u + 0x7fffu + ((u >> 16) & 1u)) >> 16);
}
__device__ __forceinline__ u32 pack2(float lo, float hi) {
  return ((u32)f2bf(hi) << 16) | f2bf(lo);
}

// swizzled byte offset within a [rows][256 B] LDS tile (involution on bits 7:4)
__device__ __forceinline__ int swzb(int row, int o) {
  return (row*256 + o) ^ ((row & 15) << 4);
}

// ======== mgemm: C[M,128] = A[M,K] @ Bt[128,K]^T (128-row tiles, 256 thr) ========
__device__ __forceinline__ void stage_tile(const u16* __restrict__ g, int ld,
                                           u16* lds, int wave, int lane) {
#pragma unroll
  for (int t = 0; t < 2; ++t) {
    int i = wave*2 + t;
    int row = i*16 + (lane >> 2);
    int col16 = (lane & 3) ^ ((lane >> 3) & 3);
    const u16* src = g + (size_t)row*ld + col16*8;
    __builtin_amdgcn_global_load_lds((const __attribute__((address_space(1))) void*)src,
                                     (__attribute__((address_space(3))) void*)(lds + i*512),
                                     16, 0, 0);
  }
}

// CMODE 2: remapped final-output write (+bias);
// CMODE 3: dual half-M (blocks >= gridDim/2 use A+32768 rows, Bt+128*128, bias2, C+32768 rows)
template<int CMODE>
__global__ __launch_bounds__(256) void mgemm(const u16* __restrict__ A, int lda,
                                             const u16* __restrict__ Bt, int ldb,
                                             const float* __restrict__ bias,
                                             const float* __restrict__ bias2,
                                             float* __restrict__ C, int kTot)
{
  __shared__ u16 As[4096], Bs[4096];
  const int tid = threadIdx.x, wave = tid >> 6, lane = tid & 63;
  const int wm = wave >> 1, wn = wave & 1;
  int bx = blockIdx.x;
  if (CMODE == 3) {
    if (bx >= (int)gridDim.x/2) {
      bx -= gridDim.x/2;
      A += (size_t)32768*lda; Bt += 128*128; bias = bias2; C += (size_t)32768*Hd;
    }
  }
  const int brow = bx * 128;
  const u16* Ab = A + (size_t)brow*lda;
  f32x4 acc[4][4];
#pragma unroll
  for (int i = 0; i < 4; ++i)
#pragma unroll
    for (int j = 0; j < 4; ++j) acc[i][j] = (f32x4){0.f, 0.f, 0.f, 0.f};

  const int ks = (lane >> 4) * 16;
  const int rl = lane & 15;
  for (int k0 = 0; k0 < kTot; k0 += 32) {
    stage_tile(Ab + k0, lda, As, wave, lane);
    stage_tile(Bt + k0, ldb, Bs, wave, lane);
    __syncthreads();
    bf16x8 af[4], bv[4];
    const char* Ac = (const char*)As;
    const char* Bc = (const char*)Bs;
#pragma unroll
    for (int i = 0; i < 4; ++i) {
      int r = wm*64 + i*16 + rl;
      int by = (r*64 + ks) ^ (((r >> 1) & 3) << 4);
      af[i] = *(const bf16x8*)(Ac + by);
    }
#pragma unroll
    for (int j = 0; j < 4; ++j) {
      int r = wn*64 + j*16 + rl;
      int by = (r*64 + ks) ^ (((r >> 1) & 3) << 4);
      bv[j] = *(const bf16x8*)(Bc + by);
    }
#pragma unroll
    for (int i = 0; i < 4; ++i)
#pragma unroll
      for (int j = 0; j < 4; ++j)
        acc[i][j] = __builtin_amdgcn_mfma_f32_16x16x32_bf16(af[i], bv[j], acc[i][j], 0, 0, 0);
    __syncthreads();
  }
  const int cl = lane & 15;
  const int rq = (lane >> 4) * 4;
#pragma unroll
  for (int i = 0; i < 4; ++i) {
#pragma unroll
    for (int q = 0; q < 4; ++q) {
      int row = brow + wm*64 + i*16 + rq + q;
      size_t ob;
      if (CMODE == 2) {
        int b = row >> 6, p = row & 63;
        ob = (p == 0) ? (size_t)b*Hd
                      : (size_t)(1024*Hd) + ((size_t)(b*63 + (p-1)))*Hd;
      } else {
        ob = (size_t)row * Hd;
      }
#pragma unroll
      for (int j = 0; j < 4; ++j) {
        int col = wn*64 + j*16 + cl;
        float v = acc[i][j][q];
        if (bias) v += bias[col];
        C[ob + col] = v;
      }
    }
  }
}

// ======== fused gather + K=1152 GEMM + BN-stats (64-row tile, 48 KB LDS) ========
// Btg: bf16 [128 out][1152], chunks: 0..3 conv_rel r, 4..7 attW r, 8 conv_root
// stage 128 rows x 256B (32 KB) with 8 waves
__device__ __forceinline__ void stageB(const u16* __restrict__ gbase, int ld,
                                       u16* lds, int wave, int lane) {
#pragma unroll
  for (int t = 0; t < 4; ++t) {
    int ti = wave*4 + t;
    int row = ti*4 + (lane >> 4);
    int lchunk = (lane & 15) ^ (row & 15);
    const u16* src = gbase + (size_t)row*ld + lchunk*8;
    __builtin_amdgcn_global_load_lds((const __attribute__((address_space(1))) void*)src,
                                     (__attribute__((address_space(3))) void*)(lds + ti*512),
                                     16, 0, 0);
  }
}
// stage 64 rows x 256B (16 KB) with 8 waves
__device__ __forceinline__ void stageY64(const u16* __restrict__ gbase, int ld,
                                         u16* lds, int wave, int lane) {
#pragma unroll
  for (int t = 0; t < 2; ++t) {
    int ti = wave*2 + t;
    int row = ti*4 + (lane >> 4);
    int lchunk = (lane & 15) ^ (row & 15);
    const u16* src = gbase + (size_t)row*ld + lchunk*8;
    __builtin_amdgcn_global_load_lds((const __attribute__((address_space(1))) void*)src,
                                     (__attribute__((address_space(3))) void*)(lds + ti*512),
                                     16, 0, 0);
  }
}

__device__ __forceinline__ void mfma64(const u16* Yt, const u16* Bt, f32x4 (&acc)[2][2],
                                       int wm, int wn, int lane) {
  const int rl = lane & 15;
  const int ko = (lane >> 4) * 16;
  const char* Yc_ = (const char*)Yt;
  const char* Bc_ = (const char*)Bt;
#pragma unroll
  for (int ks = 0; ks < 4; ++ks) {
    int o = ks*64 + ko;
    bf16x8 af[2], bv[2];
#pragma unroll
    for (int i = 0; i < 2; ++i)
      af[i] = *(const bf16x8*)(Yc_ + swzb(wm*32 + i*16 + rl, o));
#pragma unroll
    for (int j = 0; j < 2; ++j)
      bv[j] = *(const bf16x8*)(Bc_ + swzb(wn*32 + j*16 + rl, o));
#pragma unroll
    for (int i = 0; i < 2; ++i)
#pragma unroll
      for (int j = 0; j < 2; ++j)
        acc[i][j] = __builtin_amdgcn_mfma_f32_16x16x32_bf16(af[i], bv[j], acc[i][j], 0, 0, 0);
  }
}

__global__ __launch_bounds__(512, 2) void fused_gemm(
    const u16* __restrict__ xmb, const int* __restrict__ src_sorted,
    const float* __restrict__ exs, const int* __restrict__ offsets,
    const u16* __restrict__ Btg, float* __restrict__ hbuf, float* __restrict__ bns)
{
  __shared__ u16 Yt[8192];    // 16 KB: 64-row Y tile
  __shared__ u16 Bw[16384];   // 32 KB: 128-row weight tile
  const int tid = threadIdx.x, wave = tid >> 6, lane = tid & 63;
  const int wm = wave >> 2, wn = wave & 3;
  const int brow = blockIdx.x * 64;
  f32x4 acc[2][2];
#pragma unroll
  for (int i = 0; i < 2; ++i)
#pragma unroll
    for (int j = 0; j < 2; ++j) acc[i][j] = (f32x4){0.f, 0.f, 0.f, 0.f};

  u32 axp[8];                 // att sums, packed bf16 (alpha pre-normalized in exs)

  for (int r = 0; r < RREL; ++r) {
    __syncthreads();                        // Yt/Bw free (prev att-mfma done)
    stageB(Btg + r*128, 1152, Bw, wave, lane);   // conv weights in flight during gather
#pragma unroll
    for (int g = 0; g < 4; ++g) {           // 4 groups x 2 nodes per wave
      int ln0 = wave*8 + g*2;
      int e0[2], ct[2];
#pragma unroll
      for (int m = 0; m < 2; ++m) {
        int seg = (brow + ln0 + m)*RREL + r;
        e0[m] = offsets[seg];
        ct[m] = offsets[seg+1] - e0[m];
      }
      int   si[2][4];
      float ew[2][4];
#pragma unroll
      for (int m = 0; m < 2; ++m)
#pragma unroll
        for (int k = 0; k < 4; ++k) {
          si[m][k] = src_sorted[e0[m] + k];   // padded; discarded if k>=ct
          ew[m][k] = exs[e0[m] + k];
        }
      u32 uu[2][4];
#pragma unroll
      for (int m = 0; m < 2; ++m)
#pragma unroll
        for (int k = 0; k < 4; ++k) {
          int sx = (k < ct[m]) ? si[m][k] : 0;     // clamp to L1-hot row
          uu[m][k] = *(const u32*)(xmb + (size_t)sx*Hd + lane*2);
        }
      float cx[2], cy[2], ax[2], ay[2];
#pragma unroll
      for (int m = 0; m < 2; ++m) { cx[m] = cy[m] = ax[m] = ay[m] = 0.f; }
#pragma unroll
      for (int m = 0; m < 2; ++m) {
#pragma unroll
        for (int k = 0; k < 4; ++k) {
          float pr = (k < ct[m]) ? 1.f : 0.f;
          float al = pr * ew[m][k];
          float vx = __uint_as_float(uu[m][k] << 16);
          float vy = __uint_as_float(uu[m][k] & 0xffff0000u);
          cx[m] = fmaf(pr, vx, cx[m]);
          cy[m] = fmaf(pr, vy, cy[m]);
          ax[m] = fmaf(al, vx, ax[m]);
          ay[m] = fmaf(al, vy, ay[m]);
        }
        for (int e = e0[m] + 4; e < e0[m] + ct[m]; ++e) {   // rare tail
          int s = src_sorted[e];
          float al = exs[e];
          u32 u = *(const u32*)(xmb + (size_t)s*Hd + lane*2);
          float vx = __uint_as_float(u << 16);
          float vy = __uint_as_float(u & 0xffff0000u);
          cx[m] += vx; cy[m] += vy;
          ax[m] = fmaf(al, vx, ax[m]);
          ay[m] = fmaf(al, vy, ay[m]);
        }
      }
#pragma unroll
      for (int m = 0; m < 2; ++m) {
        int ln = ln0 + m;
        float ic = 1.f / (float)max(ct[m], 1);
        *(u32*)((char*)Yt + swzb(ln, lane*4)) = pack2(cx[m]*ic, cy[m]*ic);
        axp[g*2+m] = pack2(ax[m], ay[m]);
      }
    }
    __syncthreads();                        // Y conv written + conv B staged
    mfma64(Yt, Bw, acc, wm, wn, lane);      // conv contribution
    __syncthreads();                        // conv reads done
    stageB(Btg + (4+r)*128, 1152, Bw, wave, lane);   // att weights
#pragma unroll
    for (int g = 0; g < 4; ++g)
#pragma unroll
      for (int m = 0; m < 2; ++m) {
        int ln = wave*8 + g*2 + m;
        *(u32*)((char*)Yt + swzb(ln, lane*4)) = axp[g*2+m];
      }
    __syncthreads();                        // Y att written + att B staged
    mfma64(Yt, Bw, acc, wm, wn, lane);      // att contribution
  }
  // ---- root chunk: Y = xmb tile ----
  __syncthreads();
  stageY64(xmb + (size_t)brow*Hd, Hd, Yt, wave, lane);
  stageB(Btg + 8*128, 1152, Bw, wave, lane);
  __syncthreads();
  mfma64(Yt, Bw, acc, wm, wn, lane);

  // ---- epilogue: write hbuf + BN partial sums ----
  const int cl = lane & 15, rq = (lane >> 4) * 4;
#pragma unroll
  for (int j = 0; j < 2; ++j) {
    float s = 0.f, s2 = 0.f;
#pragma unroll
    for (int i = 0; i < 2; ++i) {
#pragma unroll
      for (int q = 0; q < 4; ++q) {
        float v = acc[i][j][q];
        int row = brow + wm*32 + i*16 + rq + q;
        hbuf[(size_t)row*Hd + wn*32 + j*16 + cl] = v;
        s += v; s2 = fmaf(v, v, s2);
      }
    }
    s  += __shfl_xor(s, 16);  s  += __shfl_xor(s, 32);
    s2 += __shfl_xor(s2, 16); s2 += __shfl_xor(s2, 32);
    if (lane < 16) {
      int col = wn*32 + j*16 + cl;
      unsafeAtomicAdd(&bns[col], s);
      unsafeAtomicAdd(&bns[128 + col], s2);
    }
  }
}

// ---------------- weight transpose+convert: Bt[o][koff+k] = bf16(B[k][o]) ----------------
__global__ void wtrans(const float* __restrict__ B, u16* __restrict__ Bt,
                       int K, int ldb, int koff) {
  int idx = blockIdx.x*256 + threadIdx.x;
  if (idx >= K*128) return;
  int k = idx >> 7, o = idx & 127;
  Bt[(size_t)o*ldb + koff + k] = f2bf(B[idx]);
}

// ---------------- small utility kernels ----------------
__global__ void fill_i32(int* p, int v, int n) {
  int i = blockIdx.x*blockDim.x + threadIdx.x;
  if (i < n) p[i] = v;
}
__global__ void rowmask_k(const float* __restrict__ mask, float* __restrict__ rm) {
  int n = blockIdx.x*blockDim.x + threadIdx.x;
  if (n < NTOT) rm[n] = mask[(size_t)n*Hd];
}
__global__ void edge_count(const int* __restrict__ dst, const int* __restrict__ et, int* __restrict__ cnt) {
  int e = blockIdx.x*blockDim.x + threadIdx.x;
  if (e < NEDGE) atomicAdd(&cnt[dst[e]*RREL + et[e]], 1);
}
// both node types in one dispatch
__global__ void cvt_bf16_2(const float* __restrict__ s0, const float* __restrict__ s1,
                           u16* __restrict__ dst) {
  int i = blockIdx.x*256 + threadIdx.x;
  const int half = 32768*Hd/4;
  const float* s = (i < half) ? s0 : s1;
  int ii = (i < half) ? i : i - half;
  float4 v = *reinterpret_cast<const float4*>(s + (size_t)ii*4);
  *reinterpret_cast<uint2*>(dst + (size_t)i*4) = make_uint2(pack2(v.x, v.y), pack2(v.z, v.w));
}
__global__ void mkxmb(const float* __restrict__ x, const float* __restrict__ rm,
                      u16* __restrict__ xmb) {
  int i = blockIdx.x*256 + threadIdx.x;
  float s = rm[i >> 5];
  float4 v = *reinterpret_cast<const float4*>(x + (size_t)i*4);
  *reinterpret_cast<uint2*>(xmb + (size_t)i*4) =
      make_uint2(pack2(v.x*s, v.y*s), pack2(v.z*s, v.w*s));
}

// ---------------- CSR build ----------------
__global__ void scan1_k(const int* __restrict__ cnt, int* __restrict__ partial, int* __restrict__ bsum) {
  __shared__ int sh[256];
  int t = threadIdx.x;
  int i = blockIdx.x*256 + t;
  int v = cnt[i];
  sh[t] = v; __syncthreads();
  for (int off = 1; off < 256; off <<= 1) {
    int u = (t >= off) ? sh[t-off] : 0;
    __syncthreads();
    sh[t] += u;
    __syncthreads();
  }
  partial[i] = sh[t] - v;
  if (t == 255) bsum[blockIdx.x] = sh[255];
}
__global__ void scan2_k(int* __restrict__ bsum) {
  __shared__ int sh[256];
  int t = threadIdx.x;
  int v0 = bsum[t*4+0], v1 = bsum[t*4+1], v2 = bsum[t*4+2], v3 = bsum[t*4+3];
  int tot = v0+v1+v2+v3;
  sh[t] = tot; __syncthreads();
  for (int off = 1; off < 256; off <<= 1) {
    int u = (t >= off) ? sh[t-off] : 0;
    __syncthreads();
    sh[t] += u;
    __syncthreads();
  }
  int base = sh[t] - tot;
  bsum[t*4+0] = base;
  bsum[t*4+1] = base + v0;
  bsum[t*4+2] = base + v0+v1;
  bsum[t*4+3] = base + v0+v1+v2;
}
__global__ void scan3_k(const int* __restrict__ partial, const int* __restrict__ bsum, int* __restrict__ offsets) {
  int i = blockIdx.x*256 + threadIdx.x;
  offsets[i] = partial[i] + bsum[i >> 8];
  if (i == 0) offsets[NRSEG] = NEDGE;
}
__global__ void csr_fill(const int* __restrict__ src, const int* __restrict__ dst,
                         const int* __restrict__ et, const int* __restrict__ offsets,
                         int* __restrict__ fillctr, int* __restrict__ src_sorted) {
  int e = blockIdx.x*blockDim.x + threadIdx.x;
  if (e >= NEDGE) return;
  int seg = dst[e]*RREL + et[e];
  int pos = offsets[seg] + atomicAdd(&fillctr[seg], 1);
  src_sorted[pos] = src[e];
}

// ---------------- attention scalar path ----------------
__global__ void qkvec_k(const float* __restrict__ attW, const float* __restrict__ att_q,
                        const float* __restrict__ att_k,
                        float* __restrict__ qvec, float* __restrict__ kvec,
                        float* __restrict__ bns) {
  int t = threadIdx.x;
  if (t < 256) bns[t] = 0.f;       // zero BN accumulators for this layer
  int r = t >> 7, h = t & 127;
  const float* wrow = attW + ((size_t)r*Hd + h)*Hd;
  const float* qv = att_q + (size_t)r*Hd;
  const float* kv = att_k + (size_t)r*Hd;
  float sq_ = 0.f, sk_ = 0.f;
  for (int o = 0; o < Hd; ++o) { float w = wrow[o]; sq_ = fmaf(w, qv[o], sq_); sk_ = fmaf(w, kv[o], sk_); }
  qvec[r*Hd + h] = sq_;
  kvec[r*Hd + h] = sk_;
}

__global__ void sqk_k(const u16* __restrict__ xmb, const float* __restrict__ qvec,
                      const float* __restrict__ kvec, float* __restrict__ sq, float* __restrict__ sk) {
  int w = blockIdx.x*4 + (threadIdx.x >> 6);
  if (w >= NTOT) return;
  int lane = threadIdx.x & 63;
  u32 u = *reinterpret_cast<const u32*>(xmb + (size_t)w*Hd + lane*2);
  float vx = __uint_as_float(u << 16);
  float vy = __uint_as_float(u & 0xffff0000u);
  float pq[RREL], pk[RREL];
#pragma unroll
  for (int r = 0; r < RREL; ++r) {
    float2 q = *reinterpret_cast<const float2*>(qvec + r*Hd + lane*2);
    float2 k = *reinterpret_cast<const float2*>(kvec + r*Hd + lane*2);
    pq[r] = vx*q.x + vy*q.y;
    pk[r] = vx*k.x + vy*k.y;
  }
#pragma unroll
  for (int off = 32; off > 0; off >>= 1) {
#pragma unroll
    for (int r = 0; r < RREL; ++r) {
      pq[r] += __shfl_xor(pq[r], off);
      pk[r] += __shfl_xor(pk[r], off);
    }
  }
  if (lane == 0) {
#pragma unroll
    for (int r = 0; r < RREL; ++r) {
      sq[(size_t)r*NTOT + w] = pq[r];
      sk[(size_t)r*NTOT + w] = pk[r];
    }
  }
}

// one thread per segment: exp(leaky(sq+sk)) over its CSR range, normalize in place.
// No atomics, no den array; exs ends up holding alpha directly (sorted order).
__global__ void seg_alpha(const int* __restrict__ src_sorted, const int* __restrict__ offsets,
                          const float* __restrict__ sq, const float* __restrict__ sk,
                          float* __restrict__ exs) {
  int seg = blockIdx.x*256 + threadIdx.x;
  if (seg >= NRSEG) return;
  int e0 = offsets[seg], e1 = offsets[seg+1];
  if (e0 == e1) return;
  int nd = seg >> 2, r = seg & 3;
  float sqv = sq[(size_t)r*NTOT + nd];
  float sum = 0.f;
  for (int e = e0; e < e1; ++e) {
    float lg = sqv + sk[(size_t)r*NTOT + src_sorted[e]];
    lg = lg >= 0.f ? lg : 0.2f*lg;
    float ex = __expf(lg);
    exs[e] = ex;
    sum += ex;
  }
  float inv = 1.f / fmaxf(sum, 1e-16f);
  for (int e = e0; e < e1; ++e) exs[e] *= inv;
}

// ---------------- batchnorm finalize/apply ----------------
__global__ void bn_final(const float* __restrict__ bns, const float* __restrict__ g,
                         const float* __restrict__ b, float* __restrict__ scale,
                         float* __restrict__ shift) {
  int c = threadIdx.x;
  float mu = bns[c] * (1.f/NTOT);
  float var = bns[128 + c] * (1.f/NTOT) - mu*mu;
  float sc = g[c] / sqrtf(var + 1e-5f);
  scale[c] = sc;
  shift[c] = b[c] - mu*sc;
}

// LAST=0: xmb = bf16(rm * leaky(bn(h)))   LAST=1: xmb = bf16(leaky(bn(h)) + x_in)
template<int LAST>
__global__ void bn_apply(const float* __restrict__ h, const float* __restrict__ scale,
                         const float* __restrict__ shift, const float* __restrict__ rm,
                         const float* __restrict__ x_in, u16* __restrict__ xmb) {
  int i = blockIdx.x*256 + threadIdx.x;
  size_t i4 = (size_t)i*4;
  int c = (int)(i4 & 127);
  float4 v = *reinterpret_cast<const float4*>(h + i4);
  float4 sc = *reinterpret_cast<const float4*>(scale + c);
  float4 sh = *reinterpret_cast<const float4*>(shift + c);
  v.x = fmaf(v.x, sc.x, sh.x); v.y = fmaf(v.y, sc.y, sh.y);
  v.z = fmaf(v.z, sc.z, sh.z); v.w = fmaf(v.w, sc.w, sh.w);
  v.x = v.x >= 0.f ? v.x : 0.01f*v.x;
  v.y = v.y >= 0.f ? v.y : 0.01f*v.y;
  v.z = v.z >= 0.f ? v.z : 0.01f*v.z;
  v.w = v.w >= 0.f ? v.w : 0.01f*v.w;
  float4 xb;
  if (LAST) {
    float4 rsd = *reinterpret_cast<const float4*>(x_in + i4);
    xb.x = v.x + rsd.x; xb.y = v.y + rsd.y; xb.z = v.z + rsd.z; xb.w = v.w + rsd.w;
  } else {
    float s = rm[i >> 5];
    xb.x = v.x*s; xb.y = v.y*s; xb.z = v.z*s; xb.w = v.w*s;
  }
  *reinterpret_cast<uint2*>(xmb + i4) = make_uint2(pack2(xb.x, xb.y), pack2(xb.z, xb.w));
}

extern "C" void kernel_launch(void* const* d_in, const int* in_sizes, int n_in,
                              void* d_out, int out_size, void* d_ws, size_t ws_size,
                              hipStream_t stream) {
  const float* x0       = (const float*)d_in[0];
  const float* x1       = (const float*)d_in[1];
  const float* W0       = (const float*)d_in[2];
  const float* b0       = (const float*)d_in[3];
  const float* W1       = (const float*)d_in[4];
  const float* b1       = (const float*)d_in[5];
  const float* mask     = (const float*)d_in[6];
  const float* conv_root= (const float*)d_in[7];
  const float* conv_rel = (const float*)d_in[8];
  const float* attW     = (const float*)d_in[10];
  const float* att_q    = (const float*)d_in[11];
  const float* att_k    = (const float*)d_in[12];
  const float* bn_g     = (const float*)d_in[14];
  const float* bn_b     = (const float*)d_in[15];
  const float* fc_W     = (const float*)d_in[16];
  const float* fc_b     = (const float*)d_in[17];
  const int* edge_index = (const int*)d_in[18];
  const int* edge_type  = (const int*)d_in[19];
  const int* src = edge_index;
  const int* dst = edge_index + NEDGE;
  (void)in_sizes; (void)n_in; (void)out_size; (void)ws_size;

  char* ws = (char*)d_ws;
  size_t off = 0;
  auto alloc = [&](size_t bytes) { void* p = ws + off; off = (off + bytes + 255) & ~(size_t)255; return p; };
  float* x_in  = (float*)alloc((size_t)NTOT*Hd*4);
  float* hbuf  = (float*)alloc((size_t)NTOT*Hd*4);
  u16*   xmb   = (u16*)  alloc((size_t)NTOT*Hd*2);
  float* sq    = (float*)alloc((size_t)RREL*NTOT*4);
  float* sk    = (float*)alloc((size_t)RREL*NTOT*4);
  float* exs   = (float*)alloc((size_t)(NEDGE+16)*4);   // +16 pad for head over-read
  float* rm    = (float*)alloc((size_t)NTOT*4);
  int* cnt        = (int*)alloc((size_t)NRSEG*4);
  int* fillctr    = (int*)alloc((size_t)NRSEG*4);
  int* partial    = (int*)alloc((size_t)NRSEG*4);
  int* offsets    = (int*)alloc((size_t)(NRSEG+4)*4);
  int* bsum       = (int*)alloc(4096);
  int* src_sorted = (int*)alloc((size_t)(NEDGE+16)*4);  // +16 pad
  float* qvec   = (float*)alloc(512*4);
  float* kvec   = (float*)alloc(512*4);
  float* bns    = (float*)alloc(1024);
  float* bnscale= (float*)alloc(512);
  float* bnshift= (float*)alloc(512);
  u16* Btw  = (u16*)alloc((size_t)2*128*128*2);   // W0^T | W1^T (then reused for fc)
  u16* Btg0 = (u16*)alloc((size_t)128*1152*2);
  u16* Btg1 = (u16*)alloc((size_t)128*1152*2);
  u16* BtgL[2] = {Btg0, Btg1};

  // ---- static CSR over (dst, rel) segments ----
  rowmask_k<<<NTOT/256, 256, 0, stream>>>(mask, rm);
  fill_i32<<<NRSEG/256, 256, 0, stream>>>(cnt, 0, NRSEG);
  edge_count<<<NEDGE/256, 256, 0, stream>>>(dst, edge_type, cnt);
  scan1_k<<<NRSEG/256, 256, 0, stream>>>(cnt, partial, bsum);
  scan2_k<<<1, 256, 0, stream>>>(bsum);
  scan3_k<<<NRSEG/256, 256, 0, stream>>>(partial, bsum, offsets);
  fill_i32<<<NRSEG/256, 256, 0, stream>>>(fillctr, 0, NRSEG);
  csr_fill<<<NEDGE/256, 256, 0, stream>>>(src, dst, edge_type, offsets, fillctr, src_sorted);

  // ---- per-layer stacked weights: [conv_rel r | attW r | conv_root], bf16 [128][1152] ----
  for (int l = 0; l < 2; ++l) {
    wtrans<<<(512*128)/256, 256, 0, stream>>>(conv_rel + (size_t)l*RREL*Hd*Hd, BtgL[l], 512, 1152, 0);
    wtrans<<<(512*128)/256, 256, 0, stream>>>(attW + (size_t)l*16*Hd*Hd, BtgL[l], 512, 1152, 512);
    wtrans<<<(128*128)/256, 256, 0, stream>>>(conv_root + (size_t)l*Hd*Hd, BtgL[l], 128, 1152, 1024);
  }

  // ---- x_in = [x0@W0+b0 ; x1@W1+b1]  (bf16 MFMA, single dual dispatch) ----
  cvt_bf16_2<<<(NTOT*Hd/4)/256, 256, 0, stream>>>(x0, x1, xmb);
  wtrans<<<(128*128)/256, 256, 0, stream>>>(W0, Btw, 128, 128, 0);
  wtrans<<<(128*128)/256, 256, 0, stream>>>(W1, Btw + 128*128, 128, 128, 0);
  mgemm<3><<<512, 256, 0, stream>>>(xmb, Hd, Btw, 128, b0, b1, x_in, 128);
  mkxmb<<<(NTOT*Hd/4)/256, 256, 0, stream>>>(x_in, rm, xmb);

  for (int l = 0; l < 2; ++l) {
    const float* attW_l = attW + (size_t)l*16*Hd*Hd;
    qkvec_k<<<1, 512, 0, stream>>>(attW_l, att_q + (size_t)l*16*Hd, att_k + (size_t)l*16*Hd,
                                   qvec, kvec, bns);
    sqk_k<<<NTOT/4, 256, 0, stream>>>(xmb, qvec, kvec, sq, sk);
    seg_alpha<<<NRSEG/256, 256, 0, stream>>>(src_sorted, offsets, sq, sk, exs);
    // fused: gather + (conv|att|root) GEMM + BN partial stats (conv_b/att_b cancel in BN)
    fused_gemm<<<NTOT/64, 512, 0, stream>>>(xmb, src_sorted, exs, offsets,
                                            BtgL[l], hbuf, bns);
    bn_final<<<1, 128, 0, stream>>>(bns, bn_g + (size_t)l*Hd, bn_b + (size_t)l*Hd, bnscale, bnshift);
    if (l == 0)
      bn_apply<0><<<(NTOT*Hd/4)/256, 256, 0, stream>>>(hbuf, bnscale, bnshift, rm, x_in, xmb);
    else
      bn_apply<1><<<(NTOT*Hd/4)/256, 256, 0, stream>>>(hbuf, bnscale, bnshift, rm, x_in, xmb);
  }

  // out = (x + x_in) @ fc_W + fc_b, remapped rows
  wtrans<<<(128*128)/256, 256, 0, stream>>>(fc_W, Btw, 128, 128, 0);
  mgemm<2><<<512, 256, 0, stream>>>(xmb, Hd, Btw, 128, fc_b, nullptr, (float*)d_out, 128);
}